// Round 1
// baseline (4233.916 us; speedup 1.0000x reference)
//
#include <hip/hip_runtime.h>
#include <math.h>

#define H 128
#define NG 8

// ---------------- adjacency build ----------------
__global__ void k_build_adj(const int* __restrict__ ei, int E, float* __restrict__ A, int n) {
  int e = blockIdx.x * blockDim.x + threadIdx.x;
  if (e >= E) return;
  int s = ei[e];
  int d = ei[E + e];
  atomicAdd(&A[(size_t)d * n + s], 1.0f);
}

// d[i] = rsqrt(rowsum(A)+2)   (A_hat = A + 2I, improved GCN)
__global__ void k_deg(const float* __restrict__ A, int n, float* __restrict__ dv) {
  int row = blockIdx.x * (blockDim.x >> 6) + (threadIdx.x >> 6);
  int lane = threadIdx.x & 63;
  if (row >= n) return;
  float s = 0.f;
  const float* arow = A + (size_t)row * n;
  for (int j = lane; j < n; j += 64) s += arow[j];
#pragma unroll
  for (int o = 32; o > 0; o >>= 1) s += __shfl_down(s, o);
  if (lane == 0) dv[row] = rsqrtf(s + 2.0f);
}

// Y[r,c] = dv[r] * sum_k X[r,k] W[k,c]   (feature transform + left degree scale)
__global__ void k_xw(const float* __restrict__ X, const float* __restrict__ W,
                     const float* __restrict__ dv, float* __restrict__ Y,
                     int n, int F) {
  int col = threadIdx.x;                       // 0..127
  int row = blockIdx.x * blockDim.y + threadIdx.y;
  if (row >= n) return;
  float acc = 0.f;
  const float* xr = X + (size_t)row * F;
  for (int k = 0; k < F; ++k) acc += xr[k] * W[k * H + col];
  Y[(size_t)row * H + col] = dv[row] * acc;
}

// Out = act( dv .* (A@Y + 2*Y) + bias )
template <int RELU>
__global__ __launch_bounds__(256) void k_gcn(const float* __restrict__ A,
                                             const float* __restrict__ Y,
                                             const float* __restrict__ dv,
                                             const float* __restrict__ bias,
                                             float* __restrict__ Out, int n) {
  __shared__ float As[64][36];
  __shared__ float Ys[32][132];
  int tid = threadIdx.x;
  int r0 = (tid >> 5) << 3;   // 8 rows per thread
  int c0 = (tid & 31) << 2;   // 4 cols per thread
  size_t rowBase = (size_t)blockIdx.x * 64;
  float acc[8][4] = {};
  for (int k0 = 0; k0 < n; k0 += 32) {
#pragma unroll
    for (int it = 0, e = tid; it < 8; ++it, e += 256) {
      int ii = e >> 5, kk = e & 31;
      As[ii][kk] = A[(rowBase + ii) * (size_t)n + k0 + kk];
    }
#pragma unroll
    for (int it = 0, e = tid; it < 16; ++it, e += 256) {
      int kk = e >> 7, cc = e & 127;
      Ys[kk][cc] = Y[(size_t)(k0 + kk) * H + cc];
    }
    __syncthreads();
#pragma unroll
    for (int kk = 0; kk < 32; kk += 4) {
      float4 a4[8], y4[4];
#pragma unroll
      for (int i = 0; i < 8; ++i) a4[i] = *(const float4*)&As[r0 + i][kk];
#pragma unroll
      for (int s = 0; s < 4; ++s) y4[s] = *(const float4*)&Ys[kk + s][c0];
#pragma unroll
      for (int i = 0; i < 8; ++i) {
        float av[4] = {a4[i].x, a4[i].y, a4[i].z, a4[i].w};
#pragma unroll
        for (int s = 0; s < 4; ++s) {
          float yv[4] = {y4[s].x, y4[s].y, y4[s].z, y4[s].w};
#pragma unroll
          for (int j = 0; j < 4; ++j) acc[i][j] = fmaf(av[s], yv[j], acc[i][j]);
        }
      }
    }
    __syncthreads();
  }
#pragma unroll
  for (int i = 0; i < 8; ++i) {
    size_t row = rowBase + r0 + i;
    float dd = dv[row];
#pragma unroll
    for (int j = 0; j < 4; ++j) {
      int col = c0 + j;
      float v = acc[i][j] + 2.0f * Y[row * H + col];
      v = dd * v + bias[col];
      if (RELU) v = fmaxf(v, 0.0f);
      Out[row * H + col] = v;
    }
  }
}

// C[i,j] = (pi==pj ? 0 : sum_k (A[pi,k]+(pi==k)) * (A[pj,k]+(pj==k)))
// A symmetric -> S[:,perm] rows == S[perm,:] rows.  Upper-tri blocks only; mirror.
__global__ __launch_bounds__(256) void k_ata(const float* __restrict__ A,
                                             const int* __restrict__ perm,
                                             float* __restrict__ C, int n, int k) {
  int bc = blockIdx.x, br = blockIdx.y;
  if (br > bc) return;
  __shared__ float As[64][40];
  __shared__ float Bs[64][40];
  __shared__ int pr[64], pc[64];
  int tid = threadIdx.x;
  if (tid < 64) pr[tid] = perm[br * 64 + tid];
  else if (tid < 128) pc[tid - 64] = perm[bc * 64 + (tid - 64)];
  __syncthreads();
  int r0 = (tid >> 4) << 2;
  int c0 = (tid & 15) << 2;
  float acc[4][4] = {};
  for (int k0 = 0; k0 < n; k0 += 32) {
#pragma unroll
    for (int it = 0, e = tid; it < 8; ++it, e += 256) {
      int ii = e >> 5, kk = e & 31;
      int gk = k0 + kk;
      int p = pr[ii];
      As[ii][kk] = A[(size_t)p * n + gk] + ((p == gk) ? 1.0f : 0.0f);
      p = pc[ii];
      Bs[ii][kk] = A[(size_t)p * n + gk] + ((p == gk) ? 1.0f : 0.0f);
    }
    __syncthreads();
#pragma unroll
    for (int kk = 0; kk < 32; kk += 4) {
      float4 a4[4], b4[4];
#pragma unroll
      for (int i = 0; i < 4; ++i) a4[i] = *(const float4*)&As[r0 + i][kk];
#pragma unroll
      for (int j = 0; j < 4; ++j) b4[j] = *(const float4*)&Bs[c0 + j][kk];
#pragma unroll
      for (int i = 0; i < 4; ++i) {
        float av[4] = {a4[i].x, a4[i].y, a4[i].z, a4[i].w};
#pragma unroll
        for (int j = 0; j < 4; ++j) {
          float bv[4] = {b4[j].x, b4[j].y, b4[j].z, b4[j].w};
#pragma unroll
          for (int s = 0; s < 4; ++s) acc[i][j] = fmaf(av[s], bv[s], acc[i][j]);
        }
      }
    }
    __syncthreads();
  }
#pragma unroll
  for (int i = 0; i < 4; ++i) {
    int gi = br * 64 + r0 + i;
#pragma unroll
    for (int j = 0; j < 4; ++j) {
      int gj = bc * 64 + c0 + j;
      float v = (gi == gj) ? 0.0f : acc[i][j];
      C[(size_t)gi * k + gj] = v;
      C[(size_t)gj * k + gi] = v;
    }
  }
}

__global__ void k_wnorm(const float* __restrict__ w, float* __restrict__ wn) {
  int lane = threadIdx.x;  // 64
  float s = w[lane] * w[lane] + w[lane + 64] * w[lane + 64];
#pragma unroll
  for (int o = 32; o > 0; o >>= 1) s += __shfl_down(s, o);
  if (lane == 0) *wn = sqrtf(s);
}

__global__ void k_score(const float* __restrict__ h, const float* __restrict__ w,
                        const float* __restrict__ wn, float* __restrict__ score, int n) {
  int row = blockIdx.x * (blockDim.x >> 6) + (threadIdx.x >> 6);
  int lane = threadIdx.x & 63;
  if (row >= n) return;
  float s = h[(size_t)row * H + lane] * w[lane] + h[(size_t)row * H + lane + 64] * w[lane + 64];
#pragma unroll
  for (int o = 32; o > 0; o >>= 1) s += __shfl_down(s, o);
  if (lane == 0) score[row] = tanhf(s / *wn);
}

// descending score, ascending index ties -> matches jax.lax.top_k
__global__ __launch_bounds__(1024) void k_topk(const float* __restrict__ score, int n,
                                               int* __restrict__ perm) {
  __shared__ unsigned long long keys[4096];
  int tid = threadIdx.x;
  for (int i = tid; i < n; i += 1024) {
    unsigned u = __float_as_uint(score[i]);
    u = (u & 0x80000000u) ? ~u : (u | 0x80000000u);  // orderable ascending
    u = ~u;                                          // descending score
    keys[i] = ((unsigned long long)u << 32) | (unsigned)i;
  }
  __syncthreads();
  for (int size = 2; size <= n; size <<= 1) {
    for (int stride = size >> 1; stride > 0; stride >>= 1) {
      for (int t = tid; t < (n >> 1); t += 1024) {
        int i = ((t & ~(stride - 1)) << 1) | (t & (stride - 1));
        int j = i + stride;
        bool asc = ((i & size) == 0);
        unsigned long long a = keys[i], b = keys[j];
        if ((a > b) == asc) { keys[i] = b; keys[j] = a; }
      }
      __syncthreads();
    }
  }
  int k = n >> 1;
  for (int i = tid; i < k; i += 1024) perm[i] = (int)(keys[i] & 0xffffffffu);
}

__global__ void k_pool(const float* __restrict__ h, const float* __restrict__ score,
                       const int* __restrict__ perm, float* __restrict__ hp, int k) {
  int idx = blockIdx.x * 256 + threadIdx.x;
  if (idx >= k * H) return;
  int r = idx >> 7, c = idx & 127;
  int p = perm[r];
  hp[idx] = h[(size_t)p * H + c] * score[p];
}

__global__ void k_scatter(const float* __restrict__ hprev, const int* __restrict__ perm,
                          float* __restrict__ u, int k) {
  int idx = blockIdx.x * 256 + threadIdx.x;
  if (idx >= k * H) return;
  int r = idx >> 7, c = idx & 127;
  u[(size_t)perm[r] * H + c] += hprev[idx];
}

__global__ void k_segsum(const float* __restrict__ h, const int* __restrict__ batch,
                         float* __restrict__ g, int n) {
  int c = threadIdx.x;  // 128
  int r0 = blockIdx.x * 32;
  int rend = min(r0 + 32, n);
  float acc = 0.f;
  int cur = batch[r0];
  for (int r = r0; r < rend; ++r) {
    int b = batch[r];
    if (b != cur) { atomicAdd(&g[cur * H + c], acc); acc = 0.f; cur = b; }
    acc += h[(size_t)r * H + c];
  }
  atomicAdd(&g[cur * H + c], acc);
}

__global__ __launch_bounds__(256) void k_head(const float* __restrict__ g,
    const float* __restrict__ lins_w, const float* __restrict__ lins_b,
    const float* __restrict__ bn_g, const float* __restrict__ bn_b,
    const float* __restrict__ out_w, const float* __restrict__ out_b,
    float* __restrict__ out) {
  __shared__ float a[NG * H], b[NG * H];
  int tid = threadIdx.x;
  const float inv = 1.0f / sqrtf(1.0f + 1e-5f);
  for (int i = tid; i < NG * H; i += 256) a[i] = g[i];
  __syncthreads();
  for (int L = 0; L < 3; ++L) {
    for (int i = tid; i < NG * H; i += 256) {
      int c = i & 127;
      b[i] = a[i] * (bn_g[L * H + c] * inv) + bn_b[L * H + c];
    }
    __syncthreads();
    for (int i = tid; i < NG * H; i += 256) {
      int r = i >> 7, c = i & 127;
      float s = lins_b[L * H + c];
      for (int k2 = 0; k2 < H; ++k2) s += b[r * H + k2] * lins_w[(size_t)L * H * H + k2 * H + c];
      a[i] = tanhf(s);
    }
    __syncthreads();
  }
  for (int i = tid; i < NG * H; i += 256) {
    int c = i & 127;
    b[i] = a[i] * (bn_g[3 * H + c] * inv) + bn_b[3 * H + c];
  }
  __syncthreads();
  for (int i = tid; i < NG * 32; i += 256) {
    int r = i >> 5, o = i & 31;
    float s = out_b[o];
    for (int k2 = 0; k2 < H; ++k2) s += b[r * H + k2] * out_w[k2 * 32 + o];
    out[i] = s;
  }
}

extern "C" void kernel_launch(void* const* d_in, const int* in_sizes, int n_in,
                              void* d_out, int out_size, void* d_ws, size_t ws_size,
                              hipStream_t stream) {
  const float* x       = (const float*)d_in[0];
  const int*   ei      = (const int*)d_in[1];
  const int*   batch   = (const int*)d_in[2];
  const float* conv0_w = (const float*)d_in[3];
  const float* conv0_b = (const float*)d_in[4];
  const float* down_w  = (const float*)d_in[5];
  const float* down_b  = (const float*)d_in[6];
  const float* pool_w  = (const float*)d_in[7];
  const float* up_w    = (const float*)d_in[8];
  const float* up_b    = (const float*)d_in[9];
  const float* lins_w  = (const float*)d_in[10];
  const float* lins_b  = (const float*)d_in[11];
  const float* bn_g    = (const float*)d_in[12];
  const float* bn_b    = (const float*)d_in[13];
  const float* out_w   = (const float*)d_in[14];
  const float* out_b   = (const float*)d_in[15];
  int E = in_sizes[1] / 2;

  char* p = (char*)d_ws;
  auto alloc = [&](size_t bytes) {
    char* r = p;
    p += (bytes + 255) & ~(size_t)255;
    return r;
  };
  float* A0   = (float*)alloc((size_t)4096 * 4096 * 4);
  float* A1   = (float*)alloc((size_t)2048 * 2048 * 4);
  float* A2m  = (float*)alloc((size_t)1024 * 1024 * 4);
  float* A3   = (float*)alloc((size_t)512 * 512 * 4);
  float* dv0  = (float*)alloc(4096 * 4);
  float* dv1  = (float*)alloc(2048 * 4);
  float* dv2  = (float*)alloc(1024 * 4);
  float* dv3  = (float*)alloc(512 * 4);
  int*   perm0 = (int*)alloc(2048 * 4);
  int*   perm1 = (int*)alloc(1024 * 4);
  int*   perm2 = (int*)alloc(512 * 4);
  float* score = (float*)alloc(4096 * 4);
  float* wn    = (float*)alloc(4 * 4);
  float* h0 = (float*)alloc((size_t)4096 * H * 4);
  float* h1 = (float*)alloc((size_t)2048 * H * 4);
  float* h2 = (float*)alloc((size_t)1024 * H * 4);
  float* h3 = (float*)alloc((size_t)512 * H * 4);
  float* t  = (float*)alloc((size_t)4096 * H * 4);
  float* t2 = (float*)alloc((size_t)4096 * H * 4);
  float* hu = (float*)alloc((size_t)4096 * H * 4);
  float* g  = (float*)alloc(NG * H * 4);

  // ---- adjacency + conv0 ----
  hipMemsetAsync(A0, 0, (size_t)4096 * 4096 * 4, stream);
  k_build_adj<<<(E + 255) / 256, 256, 0, stream>>>(ei, E, A0, 4096);
  k_deg<<<4096 / 4, 256, 0, stream>>>(A0, 4096, dv0);
  k_xw<<<dim3(2048), dim3(128, 2), 0, stream>>>(x, conv0_w, dv0, t2, 4096, 64);
  k_gcn<1><<<4096 / 64, 256, 0, stream>>>(A0, t2, dv0, conv0_b, h0, 4096);

  // ---- down path ----
  const int ns[3] = {4096, 2048, 1024};
  float* Ain[3]   = {A0, A1, A2m};
  float* Aout[3]  = {A1, A2m, A3};
  float* dnext[3] = {dv1, dv2, dv3};
  float* hin[3]   = {h0, h1, h2};
  float* hout[3]  = {h1, h2, h3};
  int*   perms[3] = {perm0, perm1, perm2};
  for (int i = 0; i < 3; ++i) {
    int n = ns[i], kk = n >> 1;
    k_wnorm<<<1, 64, 0, stream>>>(pool_w + i * H, wn + i);
    k_score<<<n / 4, 256, 0, stream>>>(hin[i], pool_w + i * H, wn + i, score, n);
    k_topk<<<1, 1024, 0, stream>>>(score, n, perms[i]);
    k_pool<<<(kk * H) / 256, 256, 0, stream>>>(hin[i], score, perms[i], t, kk);
    k_ata<<<dim3(kk / 64, kk / 64), 256, 0, stream>>>(Ain[i], perms[i], Aout[i], n, kk);
    k_deg<<<kk / 4, 256, 0, stream>>>(Aout[i], kk, dnext[i]);
    k_xw<<<dim3(kk / 2), dim3(128, 2), 0, stream>>>(t, down_w + (size_t)i * H * H, dnext[i], t2, kk, H);
    k_gcn<1><<<kk / 64, 256, 0, stream>>>(Aout[i], t2, dnext[i], down_b + i * H, hout[i], kk);
  }

  // ---- up path ----
  // i=0 (j=2): res=h2 (1024), A=A2m, perm2, prev=h3 (512)
  hipMemcpyAsync(t, h2, (size_t)1024 * H * 4, hipMemcpyDeviceToDevice, stream);
  k_scatter<<<(512 * H) / 256, 256, 0, stream>>>(h3, perm2, t, 512);
  k_xw<<<dim3(1024 / 2), dim3(128, 2), 0, stream>>>(t, up_w, dv2, t2, 1024, H);
  k_gcn<1><<<1024 / 64, 256, 0, stream>>>(A2m, t2, dv2, up_b, hu, 1024);
  // i=1 (j=1): res=h1 (2048), A=A1, perm1, prev=hu (1024)
  hipMemcpyAsync(t, h1, (size_t)2048 * H * 4, hipMemcpyDeviceToDevice, stream);
  k_scatter<<<(1024 * H) / 256, 256, 0, stream>>>(hu, perm1, t, 1024);
  k_xw<<<dim3(2048 / 2), dim3(128, 2), 0, stream>>>(t, up_w + H * H, dv1, t2, 2048, H);
  k_gcn<1><<<2048 / 64, 256, 0, stream>>>(A1, t2, dv1, up_b + H, hu, 2048);
  // i=2 (j=0): res=h0 (4096), A=A0, perm0, prev=hu (2048), NO relu
  hipMemcpyAsync(t, h0, (size_t)4096 * H * 4, hipMemcpyDeviceToDevice, stream);
  k_scatter<<<(2048 * H) / 256, 256, 0, stream>>>(hu, perm0, t, 2048);
  k_xw<<<dim3(4096 / 2), dim3(128, 2), 0, stream>>>(t, up_w + 2 * H * H, dv0, t2, 4096, H);
  k_gcn<0><<<4096 / 64, 256, 0, stream>>>(A0, t2, dv0, up_b + 2 * H, hu, 4096);

  // ---- pool + head ----
  hipMemsetAsync(g, 0, NG * H * 4, stream);
  k_segsum<<<4096 / 32, 128, 0, stream>>>(hu, batch, g, 4096);
  k_head<<<1, 256, 0, stream>>>(g, lins_w, lins_b, bn_g, bn_b, out_w, out_b, (float*)d_out);
}

// Round 2
// 1815.470 us; speedup vs baseline: 2.3321x; 2.3321x over previous
//
#include <hip/hip_runtime.h>
#include <math.h>

#define H 128
#define NG 8

// ---------------- adjacency build ----------------
__global__ void k_build_adj(const int* __restrict__ ei, int E, float* __restrict__ A, int n) {
  int e = blockIdx.x * blockDim.x + threadIdx.x;
  if (e >= E) return;
  int s = ei[e];
  int d = ei[E + e];
  atomicAdd(&A[(size_t)d * n + s], 1.0f);
}

// d[i] = rsqrt(rowsum(A)+2)   (A_hat = A + 2I, improved GCN)
__global__ void k_deg(const float* __restrict__ A, int n, float* __restrict__ dv) {
  int row = blockIdx.x * (blockDim.x >> 6) + (threadIdx.x >> 6);
  int lane = threadIdx.x & 63;
  if (row >= n) return;
  float s = 0.f;
  const float* arow = A + (size_t)row * n;
  for (int j = lane; j < n; j += 64) s += arow[j];
#pragma unroll
  for (int o = 32; o > 0; o >>= 1) s += __shfl_down(s, o);
  if (lane == 0) dv[row] = rsqrtf(s + 2.0f);
}

// Y[r,c] = dv[r] * sum_k X[r,k] W[k,c]
__global__ void k_xw(const float* __restrict__ X, const float* __restrict__ W,
                     const float* __restrict__ dv, float* __restrict__ Y,
                     int n, int F) {
  int col = threadIdx.x;                       // 0..127
  int row = blockIdx.x * blockDim.y + threadIdx.y;
  if (row >= n) return;
  float acc = 0.f;
  const float* xr = X + (size_t)row * F;
  for (int k = 0; k < F; ++k) acc += xr[k] * W[k * H + col];
  Y[(size_t)row * H + col] = dv[row] * acc;
}

// Partial A@Y over k-chunk [by*KC, by*KC+KC): atomicAdd into Acc
__global__ __launch_bounds__(256) void k_gcn_part(const float* __restrict__ A,
                                                  const float* __restrict__ Y,
                                                  float* __restrict__ Acc,
                                                  int n, int KC) {
  __shared__ float As[64][36];
  __shared__ float Ys[32][132];
  int tid = threadIdx.x;
  int r0 = (tid >> 5) << 3;   // 8 rows per thread
  int c0 = (tid & 31) << 2;   // 4 cols per thread
  size_t rowBase = (size_t)blockIdx.x * 64;
  int k0s = blockIdx.y * KC;
  float acc[8][4] = {};
  for (int k0 = k0s; k0 < k0s + KC; k0 += 32) {
#pragma unroll
    for (int it = 0, e = tid; it < 8; ++it, e += 256) {
      int ii = e >> 5, kk = e & 31;
      As[ii][kk] = A[(rowBase + ii) * (size_t)n + k0 + kk];
    }
#pragma unroll
    for (int it = 0, e = tid; it < 4; ++it, e += 256) {
      int kk = e >> 5, cc4 = e & 31;
      *(float4*)&Ys[kk][cc4 << 2] = *(const float4*)&Y[(size_t)(k0 + kk) * H + (cc4 << 2)];
    }
    __syncthreads();
#pragma unroll
    for (int kk = 0; kk < 32; kk += 4) {
      float4 a4[8], y4[4];
#pragma unroll
      for (int i = 0; i < 8; ++i) a4[i] = *(const float4*)&As[r0 + i][kk];
#pragma unroll
      for (int s = 0; s < 4; ++s) y4[s] = *(const float4*)&Ys[kk + s][c0];
#pragma unroll
      for (int i = 0; i < 8; ++i) {
        float av[4] = {a4[i].x, a4[i].y, a4[i].z, a4[i].w};
#pragma unroll
        for (int s = 0; s < 4; ++s) {
          float yv[4] = {y4[s].x, y4[s].y, y4[s].z, y4[s].w};
#pragma unroll
          for (int j = 0; j < 4; ++j) acc[i][j] = fmaf(av[s], yv[j], acc[i][j]);
        }
      }
    }
    __syncthreads();
  }
#pragma unroll
  for (int i = 0; i < 8; ++i) {
    size_t row = rowBase + r0 + i;
#pragma unroll
    for (int j = 0; j < 4; ++j) atomicAdd(&Acc[row * H + c0 + j], acc[i][j]);
  }
}

// Out = act( dv .* (Acc + 2*Y) + bias )
__global__ void k_gcn_fin(const float* __restrict__ Acc, const float* __restrict__ Y,
                          const float* __restrict__ dv, const float* __restrict__ bias,
                          float* __restrict__ Out, int n, int relu) {
  int idx = blockIdx.x * 256 + threadIdx.x;
  if (idx >= n * H) return;
  int row = idx >> 7, col = idx & 127;
  float v = Acc[idx] + 2.0f * Y[idx];
  v = dv[row] * v + bias[col];
  if (relu) v = fmaxf(v, 0.0f);
  Out[idx] = v;
}

// C[i,j] = (pi==pj ? 0 : sum_k (A[pi,k]+(pi==k)) * (A[pj,k]+(pj==k)))
// A symmetric; upper-tri blocks only, mirrored.
// Thread (ty,tx): rows ty+16i, cols tx+16j -> per-16-lane-phase consecutive rows,
// stride 36 floats (144B): bank base 4*row mod 32 -> 2 lanes/bank = conflict-free.
__global__ __launch_bounds__(256) void k_ata(const float* __restrict__ A,
                                             const int* __restrict__ perm,
                                             float* __restrict__ C, int n, int k) {
  int bc = blockIdx.x, br = blockIdx.y;
  if (br > bc) return;
  __shared__ float As[64][36];
  __shared__ float Bs[64][36];
  __shared__ int pr[64], pc[64];
  int tid = threadIdx.x;
  if (tid < 64) pr[tid] = perm[br * 64 + tid];
  else if (tid < 128) pc[tid - 64] = perm[bc * 64 + (tid - 64)];
  __syncthreads();
  int ty = tid >> 4;   // 0..15
  int tx = tid & 15;   // 0..15
  float acc[4][4] = {};
  for (int k0 = 0; k0 < n; k0 += 32) {
#pragma unroll
    for (int it = 0, e = tid; it < 8; ++it, e += 256) {
      int ii = e >> 5, kk = e & 31;
      int gk = k0 + kk;
      int p = pr[ii];
      As[ii][kk] = A[(size_t)p * n + gk] + ((p == gk) ? 1.0f : 0.0f);
      p = pc[ii];
      Bs[ii][kk] = A[(size_t)p * n + gk] + ((p == gk) ? 1.0f : 0.0f);
    }
    __syncthreads();
#pragma unroll
    for (int kk = 0; kk < 32; kk += 4) {
      float4 a4[4], b4[4];
#pragma unroll
      for (int i = 0; i < 4; ++i) a4[i] = *(const float4*)&As[ty + 16 * i][kk];
#pragma unroll
      for (int j = 0; j < 4; ++j) b4[j] = *(const float4*)&Bs[tx + 16 * j][kk];
#pragma unroll
      for (int i = 0; i < 4; ++i) {
        float av[4] = {a4[i].x, a4[i].y, a4[i].z, a4[i].w};
#pragma unroll
        for (int j = 0; j < 4; ++j) {
          float bv[4] = {b4[j].x, b4[j].y, b4[j].z, b4[j].w};
#pragma unroll
          for (int s = 0; s < 4; ++s) acc[i][j] = fmaf(av[s], bv[s], acc[i][j]);
        }
      }
    }
    __syncthreads();
  }
#pragma unroll
  for (int i = 0; i < 4; ++i) {
    int gi = br * 64 + ty + 16 * i;
#pragma unroll
    for (int j = 0; j < 4; ++j) {
      int gj = bc * 64 + tx + 16 * j;
      float v = (gi == gj) ? 0.0f : acc[i][j];
      C[(size_t)gi * k + gj] = v;
      C[(size_t)gj * k + gi] = v;
    }
  }
}

__global__ void k_wnorm(const float* __restrict__ w, float* __restrict__ wn) {
  int lane = threadIdx.x;  // 64
  float s = w[lane] * w[lane] + w[lane + 64] * w[lane + 64];
#pragma unroll
  for (int o = 32; o > 0; o >>= 1) s += __shfl_down(s, o);
  if (lane == 0) *wn = sqrtf(s);
}

__global__ void k_score(const float* __restrict__ h, const float* __restrict__ w,
                        const float* __restrict__ wn, float* __restrict__ score, int n) {
  int row = blockIdx.x * (blockDim.x >> 6) + (threadIdx.x >> 6);
  int lane = threadIdx.x & 63;
  if (row >= n) return;
  float s = h[(size_t)row * H + lane] * w[lane] + h[(size_t)row * H + lane + 64] * w[lane + 64];
#pragma unroll
  for (int o = 32; o > 0; o >>= 1) s += __shfl_down(s, o);
  if (lane == 0) score[row] = tanhf(s / *wn);
}

// descending score, ascending index ties -> matches jax.lax.top_k
__global__ __launch_bounds__(1024) void k_topk(const float* __restrict__ score, int n,
                                               int* __restrict__ perm) {
  __shared__ unsigned long long keys[4096];
  int tid = threadIdx.x;
  for (int i = tid; i < n; i += 1024) {
    unsigned u = __float_as_uint(score[i]);
    u = (u & 0x80000000u) ? ~u : (u | 0x80000000u);
    u = ~u;
    keys[i] = ((unsigned long long)u << 32) | (unsigned)i;
  }
  __syncthreads();
  for (int size = 2; size <= n; size <<= 1) {
    for (int stride = size >> 1; stride > 0; stride >>= 1) {
      for (int t = tid; t < (n >> 1); t += 1024) {
        int i = ((t & ~(stride - 1)) << 1) | (t & (stride - 1));
        int j = i + stride;
        bool asc = ((i & size) == 0);
        unsigned long long a = keys[i], b = keys[j];
        if ((a > b) == asc) { keys[i] = b; keys[j] = a; }
      }
      __syncthreads();
    }
  }
  int k = n >> 1;
  for (int i = tid; i < k; i += 1024) perm[i] = (int)(keys[i] & 0xffffffffu);
}

__global__ void k_pool(const float* __restrict__ h, const float* __restrict__ score,
                       const int* __restrict__ perm, float* __restrict__ hp, int k) {
  int idx = blockIdx.x * 256 + threadIdx.x;
  if (idx >= k * H) return;
  int r = idx >> 7, c = idx & 127;
  int p = perm[r];
  hp[idx] = h[(size_t)p * H + c] * score[p];
}

__global__ void k_scatter(const float* __restrict__ hprev, const int* __restrict__ perm,
                          float* __restrict__ u, int k) {
  int idx = blockIdx.x * 256 + threadIdx.x;
  if (idx >= k * H) return;
  int r = idx >> 7, c = idx & 127;
  u[(size_t)perm[r] * H + c] += hprev[idx];
}

__global__ void k_segsum(const float* __restrict__ h, const int* __restrict__ batch,
                         float* __restrict__ g, int n) {
  int c = threadIdx.x;  // 128
  int r0 = blockIdx.x * 32;
  int rend = min(r0 + 32, n);
  float acc = 0.f;
  int cur = batch[r0];
  for (int r = r0; r < rend; ++r) {
    int b = batch[r];
    if (b != cur) { atomicAdd(&g[cur * H + c], acc); acc = 0.f; cur = b; }
    acc += h[(size_t)r * H + c];
  }
  atomicAdd(&g[cur * H + c], acc);
}

__global__ __launch_bounds__(256) void k_head(const float* __restrict__ g,
    const float* __restrict__ lins_w, const float* __restrict__ lins_b,
    const float* __restrict__ bn_g, const float* __restrict__ bn_b,
    const float* __restrict__ out_w, const float* __restrict__ out_b,
    float* __restrict__ out) {
  __shared__ float a[NG * H], b[NG * H];
  int tid = threadIdx.x;
  const float inv = 1.0f / sqrtf(1.0f + 1e-5f);
  for (int i = tid; i < NG * H; i += 256) a[i] = g[i];
  __syncthreads();
  for (int L = 0; L < 3; ++L) {
    for (int i = tid; i < NG * H; i += 256) {
      int c = i & 127;
      b[i] = a[i] * (bn_g[L * H + c] * inv) + bn_b[L * H + c];
    }
    __syncthreads();
    for (int i = tid; i < NG * H; i += 256) {
      int r = i >> 7, c = i & 127;
      float s = lins_b[L * H + c];
      for (int k2 = 0; k2 < H; ++k2) s += b[r * H + k2] * lins_w[(size_t)L * H * H + k2 * H + c];
      a[i] = tanhf(s);
    }
    __syncthreads();
  }
  for (int i = tid; i < NG * H; i += 256) {
    int c = i & 127;
    b[i] = a[i] * (bn_g[3 * H + c] * inv) + bn_b[3 * H + c];
  }
  __syncthreads();
  for (int i = tid; i < NG * 32; i += 256) {
    int r = i >> 5, o = i & 31;
    float s = out_b[o];
    for (int k2 = 0; k2 < H; ++k2) s += b[r * H + k2] * out_w[k2 * 32 + o];
    out[i] = s;
  }
}

extern "C" void kernel_launch(void* const* d_in, const int* in_sizes, int n_in,
                              void* d_out, int out_size, void* d_ws, size_t ws_size,
                              hipStream_t stream) {
  const float* x       = (const float*)d_in[0];
  const int*   ei      = (const int*)d_in[1];
  const int*   batch   = (const int*)d_in[2];
  const float* conv0_w = (const float*)d_in[3];
  const float* conv0_b = (const float*)d_in[4];
  const float* down_w  = (const float*)d_in[5];
  const float* down_b  = (const float*)d_in[6];
  const float* pool_w  = (const float*)d_in[7];
  const float* up_w    = (const float*)d_in[8];
  const float* up_b    = (const float*)d_in[9];
  const float* lins_w  = (const float*)d_in[10];
  const float* lins_b  = (const float*)d_in[11];
  const float* bn_g    = (const float*)d_in[12];
  const float* bn_b    = (const float*)d_in[13];
  const float* out_w   = (const float*)d_in[14];
  const float* out_b   = (const float*)d_in[15];
  int E = in_sizes[1] / 2;

  char* p = (char*)d_ws;
  auto alloc = [&](size_t bytes) {
    char* r = p;
    p += (bytes + 255) & ~(size_t)255;
    return r;
  };
  float* A0   = (float*)alloc((size_t)4096 * 4096 * 4);
  float* A1   = (float*)alloc((size_t)2048 * 2048 * 4);
  float* A2m  = (float*)alloc((size_t)1024 * 1024 * 4);
  float* A3   = (float*)alloc((size_t)512 * 512 * 4);
  float* dv0  = (float*)alloc(4096 * 4);
  float* dv1  = (float*)alloc(2048 * 4);
  float* dv2  = (float*)alloc(1024 * 4);
  float* dv3  = (float*)alloc(512 * 4);
  int*   perm0 = (int*)alloc(2048 * 4);
  int*   perm1 = (int*)alloc(1024 * 4);
  int*   perm2 = (int*)alloc(512 * 4);
  float* score = (float*)alloc(4096 * 4);
  float* wn    = (float*)alloc(4 * 4);
  float* h0 = (float*)alloc((size_t)4096 * H * 4);
  float* h1 = (float*)alloc((size_t)2048 * H * 4);
  float* h2 = (float*)alloc((size_t)1024 * H * 4);
  float* h3 = (float*)alloc((size_t)512 * H * 4);
  float* t  = (float*)alloc((size_t)4096 * H * 4);
  float* t2 = (float*)alloc((size_t)4096 * H * 4);
  float* hu = (float*)alloc((size_t)4096 * H * 4);
  float* acc = (float*)alloc((size_t)4096 * H * 4);
  float* g  = (float*)alloc(NG * H * 4);

  // gcn: Out = act(dv .* (A@Y + 2Y) + bias), split-K
  auto gcn = [&](const float* A, const float* Y, const float* dv, const float* bias,
                 float* Out, int n, int relu) {
    int kc = (n >= 4096) ? 256 : 256;
    int nch = n / kc;
    hipMemsetAsync(acc, 0, (size_t)n * H * 4, stream);
    k_gcn_part<<<dim3(n / 64, nch), 256, 0, stream>>>(A, Y, acc, n, kc);
    k_gcn_fin<<<(n * H) / 256, 256, 0, stream>>>(acc, Y, dv, bias, Out, n, relu);
  };

  // ---- adjacency + conv0 ----
  hipMemsetAsync(A0, 0, (size_t)4096 * 4096 * 4, stream);
  k_build_adj<<<(E + 255) / 256, 256, 0, stream>>>(ei, E, A0, 4096);
  k_deg<<<4096 / 4, 256, 0, stream>>>(A0, 4096, dv0);
  k_xw<<<dim3(2048), dim3(128, 2), 0, stream>>>(x, conv0_w, dv0, t2, 4096, 64);
  gcn(A0, t2, dv0, conv0_b, h0, 4096, 1);

  // ---- down path ----
  const int ns[3] = {4096, 2048, 1024};
  float* Ain[3]   = {A0, A1, A2m};
  float* Aout[3]  = {A1, A2m, A3};
  float* dnext[3] = {dv1, dv2, dv3};
  float* hin[3]   = {h0, h1, h2};
  float* hout[3]  = {h1, h2, h3};
  int*   permsA[3] = {perm0, perm1, perm2};
  for (int i = 0; i < 3; ++i) {
    int n = ns[i], kk = n >> 1;
    k_wnorm<<<1, 64, 0, stream>>>(pool_w + i * H, wn + i);
    k_score<<<n / 4, 256, 0, stream>>>(hin[i], pool_w + i * H, wn + i, score, n);
    k_topk<<<1, 1024, 0, stream>>>(score, n, permsA[i]);
    k_pool<<<(kk * H) / 256, 256, 0, stream>>>(hin[i], score, permsA[i], t, kk);
    k_ata<<<dim3(kk / 64, kk / 64), 256, 0, stream>>>(Ain[i], permsA[i], Aout[i], n, kk);
    k_deg<<<kk / 4, 256, 0, stream>>>(Aout[i], kk, dnext[i]);
    k_xw<<<dim3(kk / 2), dim3(128, 2), 0, stream>>>(t, down_w + (size_t)i * H * H, dnext[i], t2, kk, H);
    gcn(Aout[i], t2, dnext[i], down_b + i * H, hout[i], kk, 1);
  }

  // ---- up path ----
  hipMemcpyAsync(t, h2, (size_t)1024 * H * 4, hipMemcpyDeviceToDevice, stream);
  k_scatter<<<(512 * H) / 256, 256, 0, stream>>>(h3, perm2, t, 512);
  k_xw<<<dim3(1024 / 2), dim3(128, 2), 0, stream>>>(t, up_w, dv2, t2, 1024, H);
  gcn(A2m, t2, dv2, up_b, hu, 1024, 1);

  hipMemcpyAsync(t, h1, (size_t)2048 * H * 4, hipMemcpyDeviceToDevice, stream);
  k_scatter<<<(1024 * H) / 256, 256, 0, stream>>>(hu, perm1, t, 1024);
  k_xw<<<dim3(2048 / 2), dim3(128, 2), 0, stream>>>(t, up_w + H * H, dv1, t2, 2048, H);
  gcn(A1, t2, dv1, up_b + H, hu, 2048, 1);

  hipMemcpyAsync(t, h0, (size_t)4096 * H * 4, hipMemcpyDeviceToDevice, stream);
  k_scatter<<<(2048 * H) / 256, 256, 0, stream>>>(hu, perm0, t, 2048);
  k_xw<<<dim3(4096 / 2), dim3(128, 2), 0, stream>>>(t, up_w + 2 * H * H, dv0, t2, 4096, H);
  gcn(A0, t2, dv0, up_b + 2 * H, hu, 4096, 0);

  // ---- pool + head ----
  hipMemsetAsync(g, 0, NG * H * 4, stream);
  k_segsum<<<4096 / 32, 128, 0, stream>>>(hu, batch, g, 4096);
  k_head<<<1, 256, 0, stream>>>(g, lins_w, lins_b, bn_g, bn_b, out_w, out_b, (float*)d_out);
}

// Round 3
// 942.716 us; speedup vs baseline: 4.4912x; 1.9258x over previous
//
#include <hip/hip_runtime.h>
#include <math.h>

#define H 128
#define NG 8
#define MAXL 512

// ---------------- CSR build from edge list ----------------
__global__ void k_hist(const int* __restrict__ ei, int E, int* __restrict__ cnt) {
  int e = blockIdx.x * 256 + threadIdx.x;
  if (e >= E) return;
  atomicAdd(&cnt[ei[E + e]], 1);   // row = edge_index[1]
}

__global__ __launch_bounds__(1024) void k_scan(const int* __restrict__ cnt,
                                               int* __restrict__ rowptr, int n) {
  __shared__ int sums[1024];
  int tid = threadIdx.x;
  int base = tid * 4;
  int v0 = 0, v1 = 0, v2 = 0, v3 = 0;
  if (base < n) { v0 = cnt[base]; v1 = cnt[base + 1]; v2 = cnt[base + 2]; v3 = cnt[base + 3]; }
  int s = v0 + v1 + v2 + v3;
  sums[tid] = s;
  __syncthreads();
  for (int off = 1; off < 1024; off <<= 1) {
    int t = (tid >= off) ? sums[tid - off] : 0;
    __syncthreads();
    sums[tid] += t;
    __syncthreads();
  }
  int excl = sums[tid] - s;
  if (base < n) {
    rowptr[base] = excl;
    rowptr[base + 1] = excl + v0;
    rowptr[base + 2] = excl + v0 + v1;
    rowptr[base + 3] = excl + v0 + v1 + v2;
  }
  if (tid == 1023) rowptr[n] = sums[1023];
}

__global__ void k_fill(const int* __restrict__ ei, int E, const int* __restrict__ rowptr,
                       int* __restrict__ cursor, int* __restrict__ colidx) {
  int e = blockIdx.x * 256 + threadIdx.x;
  if (e >= E) return;
  int r = ei[E + e], c = ei[e];
  int p = atomicAdd(&cursor[r], 1);
  colidx[rowptr[r] + p] = c;
}

__global__ void k_dvcnt(const int* __restrict__ cnt, float* __restrict__ dv, int n) {
  int i = blockIdx.x * 256 + threadIdx.x;
  if (i < n) dv[i] = rsqrtf((float)cnt[i] + 2.0f);
}

__global__ void k_inv(const int* __restrict__ perm, int* __restrict__ inv, int k) {
  int i = blockIdx.x * 256 + threadIdx.x;
  if (i < k) inv[perm[i]] = i;
}

// d[i] = rsqrt(rowsum(A)+2) for dense A
__global__ void k_deg(const float* __restrict__ A, int n, float* __restrict__ dv) {
  int row = blockIdx.x * (blockDim.x >> 6) + (threadIdx.x >> 6);
  int lane = threadIdx.x & 63;
  if (row >= n) return;
  float s = 0.f;
  const float* arow = A + (size_t)row * n;
  for (int j = lane; j < n; j += 64) s += arow[j];
#pragma unroll
  for (int o = 32; o > 0; o >>= 1) s += __shfl_down(s, o);
  if (lane == 0) dv[row] = rsqrtf(s + 2.0f);
}

// Y[r,c] = dv[r] * sum_k X[r,k] W[k,c]
__global__ void k_xw(const float* __restrict__ X, const float* __restrict__ W,
                     const float* __restrict__ dv, float* __restrict__ Y,
                     int n, int F) {
  int col = threadIdx.x;
  int row = blockIdx.x * blockDim.y + threadIdx.y;
  if (row >= n) return;
  float acc = 0.f;
  const float* xr = X + (size_t)row * F;
  for (int k = 0; k < F; ++k) acc += xr[k] * W[k * H + col];
  Y[(size_t)row * H + col] = dv[row] * acc;
}

// sparse GCN: Out[r,:] = act(dv[r]*(sum_{e in row r} Y[col_e,:] + 2*Y[r,:]) + bias)
__global__ void k_spmm_fin(const int* __restrict__ rowptr, const int* __restrict__ colidx,
                           const float* __restrict__ Y, const float* __restrict__ dv,
                           const float* __restrict__ bias, float* __restrict__ Out,
                           int n, int relu) {
  int row = blockIdx.x * 4 + (threadIdx.x >> 6);
  int lane = threadIdx.x & 63;
  if (row >= n) return;
  int s = rowptr[row], e = rowptr[row + 1];
  float a0 = 0.f, a1 = 0.f;
  int i = s;
  for (; i + 1 < e; i += 2) {
    int c0 = colidx[i], c1 = colidx[i + 1];
    float y00 = Y[(size_t)c0 * H + lane], y01 = Y[(size_t)c0 * H + 64 + lane];
    float y10 = Y[(size_t)c1 * H + lane], y11 = Y[(size_t)c1 * H + 64 + lane];
    a0 += y00 + y10;
    a1 += y01 + y11;
  }
  if (i < e) {
    int c = colidx[i];
    a0 += Y[(size_t)c * H + lane];
    a1 += Y[(size_t)c * H + 64 + lane];
  }
  float d = dv[row];
  float v0 = d * (a0 + 2.0f * Y[(size_t)row * H + lane]) + bias[lane];
  float v1 = d * (a1 + 2.0f * Y[(size_t)row * H + 64 + lane]) + bias[64 + lane];
  if (relu) { v0 = fmaxf(v0, 0.f); v1 = fmaxf(v1, 0.f); }
  Out[(size_t)row * H + lane] = v0;
  Out[(size_t)row * H + 64 + lane] = v1;
}

// sparse ATA (level 0): column k's selected entries (val 1 each, duplicates separate,
// +I self entry) -> all pairs +1 into C. Exact integers; diagonal skipped.
__global__ __launch_bounds__(256) void k_ata_sparse(const int* __restrict__ rowptr,
                                                    const int* __restrict__ colidx,
                                                    const int* __restrict__ inv,
                                                    float* __restrict__ C, int k) {
  __shared__ int lidx[MAXL];
  __shared__ int cnt;
  int kcol = blockIdx.x;
  int tid = threadIdx.x;
  if (tid == 0) cnt = 0;
  __syncthreads();
  int s = rowptr[kcol], e = rowptr[kcol + 1];
  for (int i = s + tid; i < e; i += 256) {
    int ii = inv[colidx[i]];
    if (ii >= 0) { int p = atomicAdd(&cnt, 1); if (p < MAXL) lidx[p] = ii; }
  }
  if (tid == 0) {
    int ii = inv[kcol];
    if (ii >= 0) { int p = atomicAdd(&cnt, 1); if (p < MAXL) lidx[p] = ii; }
  }
  __syncthreads();
  int c = min(cnt, MAXL);
  int tot = c * c;
  for (int t = tid; t < tot; t += 256) {
    int a = t / c, b = t - a * c;
    int ia = lidx[a], ib = lidx[b];
    if (ia != ib) atomicAdd(&C[(size_t)ia * k + ib], 1.0f);
  }
}

// dense ATA with split-K (levels 1,2): C pre-zeroed, atomicAdd partials, diag stays 0.
__global__ __launch_bounds__(256) void k_ata_sk(const float* __restrict__ A,
                                                const int* __restrict__ perm,
                                                float* __restrict__ C, int n, int k, int CK) {
  int bc = blockIdx.x, br = blockIdx.y;
  if (br > bc) return;
  __shared__ float As[64][36];
  __shared__ float Bs[64][36];
  __shared__ int pr[64], pc[64];
  int tid = threadIdx.x;
  if (tid < 64) pr[tid] = perm[br * 64 + tid];
  else if (tid < 128) pc[tid - 64] = perm[bc * 64 + (tid - 64)];
  __syncthreads();
  int ty = tid >> 4;
  int tx = tid & 15;
  float acc[4][4] = {};
  int k0s = blockIdx.z * CK;
  for (int k0 = k0s; k0 < k0s + CK; k0 += 32) {
#pragma unroll
    for (int it = 0, e = tid; it < 8; ++it, e += 256) {
      int ii = e >> 5, kk = e & 31;
      int gk = k0 + kk;
      int p = pr[ii];
      As[ii][kk] = A[(size_t)p * n + gk] + ((p == gk) ? 1.0f : 0.0f);
      p = pc[ii];
      Bs[ii][kk] = A[(size_t)p * n + gk] + ((p == gk) ? 1.0f : 0.0f);
    }
    __syncthreads();
#pragma unroll
    for (int kk = 0; kk < 32; kk += 4) {
      float4 a4[4], b4[4];
#pragma unroll
      for (int i = 0; i < 4; ++i) a4[i] = *(const float4*)&As[ty + 16 * i][kk];
#pragma unroll
      for (int j = 0; j < 4; ++j) b4[j] = *(const float4*)&Bs[tx + 16 * j][kk];
#pragma unroll
      for (int i = 0; i < 4; ++i) {
        float av[4] = {a4[i].x, a4[i].y, a4[i].z, a4[i].w};
#pragma unroll
        for (int j = 0; j < 4; ++j) {
          float bv[4] = {b4[j].x, b4[j].y, b4[j].z, b4[j].w};
#pragma unroll
          for (int s = 0; s < 4; ++s) acc[i][j] = fmaf(av[s], bv[s], acc[i][j]);
        }
      }
    }
    __syncthreads();
  }
  bool diag = (br == bc);
#pragma unroll
  for (int i = 0; i < 4; ++i) {
    int gi = br * 64 + ty + 16 * i;
#pragma unroll
    for (int j = 0; j < 4; ++j) {
      int gj = bc * 64 + tx + 16 * j;
      if (gi == gj) continue;
      float v = acc[i][j];
      atomicAdd(&C[(size_t)gi * k + gj], v);
      if (!diag) atomicAdd(&C[(size_t)gj * k + gi], v);
    }
  }
}

// Partial A@Y over k-chunk: atomicAdd into Acc
__global__ __launch_bounds__(256) void k_gcn_part(const float* __restrict__ A,
                                                  const float* __restrict__ Y,
                                                  float* __restrict__ Acc,
                                                  int n, int KC) {
  __shared__ float As[64][36];
  __shared__ float Ys[32][132];
  int tid = threadIdx.x;
  int r0 = (tid >> 5) << 3;
  int c0 = (tid & 31) << 2;
  size_t rowBase = (size_t)blockIdx.x * 64;
  int k0s = blockIdx.y * KC;
  float acc[8][4] = {};
  for (int k0 = k0s; k0 < k0s + KC; k0 += 32) {
#pragma unroll
    for (int it = 0, e = tid; it < 8; ++it, e += 256) {
      int ii = e >> 5, kk = e & 31;
      As[ii][kk] = A[(rowBase + ii) * (size_t)n + k0 + kk];
    }
#pragma unroll
    for (int it = 0, e = tid; it < 4; ++it, e += 256) {
      int kk = e >> 5, cc4 = e & 31;
      *(float4*)&Ys[kk][cc4 << 2] = *(const float4*)&Y[(size_t)(k0 + kk) * H + (cc4 << 2)];
    }
    __syncthreads();
#pragma unroll
    for (int kk = 0; kk < 32; kk += 4) {
      float4 a4[8], y4[4];
#pragma unroll
      for (int i = 0; i < 8; ++i) a4[i] = *(const float4*)&As[r0 + i][kk];
#pragma unroll
      for (int s = 0; s < 4; ++s) y4[s] = *(const float4*)&Ys[kk + s][c0];
#pragma unroll
      for (int i = 0; i < 8; ++i) {
        float av[4] = {a4[i].x, a4[i].y, a4[i].z, a4[i].w};
#pragma unroll
        for (int s = 0; s < 4; ++s) {
          float yv[4] = {y4[s].x, y4[s].y, y4[s].z, y4[s].w};
#pragma unroll
          for (int j = 0; j < 4; ++j) acc[i][j] = fmaf(av[s], yv[j], acc[i][j]);
        }
      }
    }
    __syncthreads();
  }
#pragma unroll
  for (int i = 0; i < 8; ++i) {
    size_t row = rowBase + r0 + i;
#pragma unroll
    for (int j = 0; j < 4; ++j) atomicAdd(&Acc[row * H + c0 + j], acc[i][j]);
  }
}

__global__ void k_gcn_fin(const float* __restrict__ Acc, const float* __restrict__ Y,
                          const float* __restrict__ dv, const float* __restrict__ bias,
                          float* __restrict__ Out, int n, int relu) {
  int idx = blockIdx.x * 256 + threadIdx.x;
  if (idx >= n * H) return;
  int row = idx >> 7, col = idx & 127;
  float v = Acc[idx] + 2.0f * Y[idx];
  v = dv[row] * v + bias[col];
  if (relu) v = fmaxf(v, 0.0f);
  Out[idx] = v;
}

__global__ void k_wnorm(const float* __restrict__ w, float* __restrict__ wn) {
  int lane = threadIdx.x;
  float s = w[lane] * w[lane] + w[lane + 64] * w[lane + 64];
#pragma unroll
  for (int o = 32; o > 0; o >>= 1) s += __shfl_down(s, o);
  if (lane == 0) *wn = sqrtf(s);
}

__global__ void k_score(const float* __restrict__ h, const float* __restrict__ w,
                        const float* __restrict__ wn, float* __restrict__ score, int n) {
  int row = blockIdx.x * (blockDim.x >> 6) + (threadIdx.x >> 6);
  int lane = threadIdx.x & 63;
  if (row >= n) return;
  float s = h[(size_t)row * H + lane] * w[lane] + h[(size_t)row * H + lane + 64] * w[lane + 64];
#pragma unroll
  for (int o = 32; o > 0; o >>= 1) s += __shfl_down(s, o);
  if (lane == 0) score[row] = tanhf(s / *wn);
}

// descending score, ascending index ties -> matches jax.lax.top_k
__global__ __launch_bounds__(1024) void k_topk(const float* __restrict__ score, int n,
                                               int* __restrict__ perm) {
  __shared__ unsigned long long keys[4096];
  int tid = threadIdx.x;
  for (int i = tid; i < n; i += 1024) {
    unsigned u = __float_as_uint(score[i]);
    u = (u & 0x80000000u) ? ~u : (u | 0x80000000u);
    u = ~u;
    keys[i] = ((unsigned long long)u << 32) | (unsigned)i;
  }
  __syncthreads();
  for (int size = 2; size <= n; size <<= 1) {
    for (int stride = size >> 1; stride > 0; stride >>= 1) {
      for (int t = tid; t < (n >> 1); t += 1024) {
        int i = ((t & ~(stride - 1)) << 1) | (t & (stride - 1));
        int j = i + stride;
        bool asc = ((i & size) == 0);
        unsigned long long a = keys[i], b = keys[j];
        if ((a > b) == asc) { keys[i] = b; keys[j] = a; }
      }
      __syncthreads();
    }
  }
  int k = n >> 1;
  for (int i = tid; i < k; i += 1024) perm[i] = (int)(keys[i] & 0xffffffffu);
}

__global__ void k_pool(const float* __restrict__ h, const float* __restrict__ score,
                       const int* __restrict__ perm, float* __restrict__ hp, int k) {
  int idx = blockIdx.x * 256 + threadIdx.x;
  if (idx >= k * H) return;
  int r = idx >> 7, c = idx & 127;
  int p = perm[r];
  hp[idx] = h[(size_t)p * H + c] * score[p];
}

__global__ void k_scatter(const float* __restrict__ hprev, const int* __restrict__ perm,
                          float* __restrict__ u, int k) {
  int idx = blockIdx.x * 256 + threadIdx.x;
  if (idx >= k * H) return;
  int r = idx >> 7, c = idx & 127;
  u[(size_t)perm[r] * H + c] += hprev[idx];
}

__global__ void k_segsum(const float* __restrict__ h, const int* __restrict__ batch,
                         float* __restrict__ g, int n) {
  int c = threadIdx.x;
  int r0 = blockIdx.x * 32;
  int rend = min(r0 + 32, n);
  float acc = 0.f;
  int cur = batch[r0];
  for (int r = r0; r < rend; ++r) {
    int b = batch[r];
    if (b != cur) { atomicAdd(&g[cur * H + c], acc); acc = 0.f; cur = b; }
    acc += h[(size_t)r * H + c];
  }
  atomicAdd(&g[cur * H + c], acc);
}

__global__ __launch_bounds__(256) void k_head(const float* __restrict__ g,
    const float* __restrict__ lins_w, const float* __restrict__ lins_b,
    const float* __restrict__ bn_g, const float* __restrict__ bn_b,
    const float* __restrict__ out_w, const float* __restrict__ out_b,
    float* __restrict__ out) {
  __shared__ float a[NG * H], b[NG * H];
  int tid = threadIdx.x;
  const float inv = 1.0f / sqrtf(1.0f + 1e-5f);
  for (int i = tid; i < NG * H; i += 256) a[i] = g[i];
  __syncthreads();
  for (int L = 0; L < 3; ++L) {
    for (int i = tid; i < NG * H; i += 256) {
      int c = i & 127;
      b[i] = a[i] * (bn_g[L * H + c] * inv) + bn_b[L * H + c];
    }
    __syncthreads();
    for (int i = tid; i < NG * H; i += 256) {
      int r = i >> 7, c = i & 127;
      float s = lins_b[L * H + c];
      for (int k2 = 0; k2 < H; ++k2) s += b[r * H + k2] * lins_w[(size_t)L * H * H + k2 * H + c];
      a[i] = tanhf(s);
    }
    __syncthreads();
  }
  for (int i = tid; i < NG * H; i += 256) {
    int c = i & 127;
    b[i] = a[i] * (bn_g[3 * H + c] * inv) + bn_b[3 * H + c];
  }
  __syncthreads();
  for (int i = tid; i < NG * 32; i += 256) {
    int r = i >> 5, o = i & 31;
    float s = out_b[o];
    for (int k2 = 0; k2 < H; ++k2) s += b[r * H + k2] * out_w[k2 * 32 + o];
    out[i] = s;
  }
}

extern "C" void kernel_launch(void* const* d_in, const int* in_sizes, int n_in,
                              void* d_out, int out_size, void* d_ws, size_t ws_size,
                              hipStream_t stream) {
  const float* x       = (const float*)d_in[0];
  const int*   ei      = (const int*)d_in[1];
  const int*   batch   = (const int*)d_in[2];
  const float* conv0_w = (const float*)d_in[3];
  const float* conv0_b = (const float*)d_in[4];
  const float* down_w  = (const float*)d_in[5];
  const float* down_b  = (const float*)d_in[6];
  const float* pool_w  = (const float*)d_in[7];
  const float* up_w    = (const float*)d_in[8];
  const float* up_b    = (const float*)d_in[9];
  const float* lins_w  = (const float*)d_in[10];
  const float* lins_b  = (const float*)d_in[11];
  const float* bn_g    = (const float*)d_in[12];
  const float* bn_b    = (const float*)d_in[13];
  const float* out_w   = (const float*)d_in[14];
  const float* out_b   = (const float*)d_in[15];
  int E = in_sizes[1] / 2;   // 131072 directed entries

  char* p = (char*)d_ws;
  auto alloc = [&](size_t bytes) {
    char* r = p;
    p += (bytes + 255) & ~(size_t)255;
    return r;
  };
  float* A1   = (float*)alloc((size_t)2048 * 2048 * 4);
  float* A2m  = (float*)alloc((size_t)1024 * 1024 * 4);
  float* A3   = (float*)alloc((size_t)512 * 512 * 4);
  int* cnt    = (int*)alloc(4096 * 4);
  int* cursor = (int*)alloc(4096 * 4);
  int* rowptr = (int*)alloc(4100 * 4);
  int* colidx = (int*)alloc((size_t)E * 4);
  int* invm   = (int*)alloc(4096 * 4);
  float* dv0  = (float*)alloc(4096 * 4);
  float* dv1  = (float*)alloc(2048 * 4);
  float* dv2  = (float*)alloc(1024 * 4);
  float* dv3  = (float*)alloc(512 * 4);
  int* perm0  = (int*)alloc(2048 * 4);
  int* perm1  = (int*)alloc(1024 * 4);
  int* perm2  = (int*)alloc(512 * 4);
  float* score = (float*)alloc(4096 * 4);
  float* wn    = (float*)alloc(4 * 4);
  float* h0 = (float*)alloc((size_t)4096 * H * 4);
  float* h1 = (float*)alloc((size_t)2048 * H * 4);
  float* h2 = (float*)alloc((size_t)1024 * H * 4);
  float* h3 = (float*)alloc((size_t)512 * H * 4);
  float* t  = (float*)alloc((size_t)4096 * H * 4);
  float* t2 = (float*)alloc((size_t)4096 * H * 4);
  float* hu = (float*)alloc((size_t)4096 * H * 4);
  float* acc = (float*)alloc((size_t)2048 * H * 4);
  float* g  = (float*)alloc(NG * H * 4);

  // dense gcn (levels <= 2048): Out = act(dv .* (A@Y + 2Y) + bias), split-K
  auto gcn = [&](const float* A, const float* Y, const float* dv, const float* bias,
                 float* Out, int n, int relu) {
    int KC = (n >= 2048) ? 128 : 64;
    int nch = n / KC;
    hipMemsetAsync(acc, 0, (size_t)n * H * 4, stream);
    k_gcn_part<<<dim3(n / 64, nch), 256, 0, stream>>>(A, Y, acc, n, KC);
    k_gcn_fin<<<(n * H) / 256, 256, 0, stream>>>(acc, Y, dv, bias, Out, n, relu);
  };

  // ---- CSR build (replaces dense A0 entirely) ----
  hipMemsetAsync(cnt, 0, 4096 * 4, stream);
  hipMemsetAsync(cursor, 0, 4096 * 4, stream);
  k_hist<<<(E + 255) / 256, 256, 0, stream>>>(ei, E, cnt);
  k_scan<<<1, 1024, 0, stream>>>(cnt, rowptr, 4096);
  k_fill<<<(E + 255) / 256, 256, 0, stream>>>(ei, E, rowptr, cursor, colidx);
  k_dvcnt<<<4096 / 256, 256, 0, stream>>>(cnt, dv0, 4096);

  // ---- conv0 (sparse) ----
  k_xw<<<dim3(2048), dim3(128, 2), 0, stream>>>(x, conv0_w, dv0, t2, 4096, 64);
  k_spmm_fin<<<1024, 256, 0, stream>>>(rowptr, colidx, t2, dv0, conv0_b, h0, 4096, 1);

  // ---- down path ----
  // level 0 (n=4096 -> 2048): sparse ATA
  {
    int n = 4096, kk = 2048;
    k_wnorm<<<1, 64, 0, stream>>>(pool_w, wn);
    k_score<<<n / 4, 256, 0, stream>>>(h0, pool_w, wn, score, n);
    k_topk<<<1, 1024, 0, stream>>>(score, n, perm0);
    k_pool<<<(kk * H) / 256, 256, 0, stream>>>(h0, score, perm0, t, kk);
    hipMemsetAsync(invm, 0xFF, 4096 * 4, stream);
    k_inv<<<(kk + 255) / 256, 256, 0, stream>>>(perm0, invm, kk);
    hipMemsetAsync(A1, 0, (size_t)kk * kk * 4, stream);
    k_ata_sparse<<<n, 256, 0, stream>>>(rowptr, colidx, invm, A1, kk);
    k_deg<<<kk / 4, 256, 0, stream>>>(A1, kk, dv1);
    k_xw<<<dim3(kk / 2), dim3(128, 2), 0, stream>>>(t, down_w, dv1, t2, kk, H);
    gcn(A1, t2, dv1, down_b, h1, kk, 1);
  }
  // levels 1,2: dense split-K ATA
  {
    int n = 2048, kk = 1024;
    k_wnorm<<<1, 64, 0, stream>>>(pool_w + H, wn + 1);
    k_score<<<n / 4, 256, 0, stream>>>(h1, pool_w + H, wn + 1, score, n);
    k_topk<<<1, 1024, 0, stream>>>(score, n, perm1);
    k_pool<<<(kk * H) / 256, 256, 0, stream>>>(h1, score, perm1, t, kk);
    hipMemsetAsync(A2m, 0, (size_t)kk * kk * 4, stream);
    k_ata_sk<<<dim3(kk / 64, kk / 64, 4), 256, 0, stream>>>(A1, perm1, A2m, n, kk, 512);
    k_deg<<<kk / 4, 256, 0, stream>>>(A2m, kk, dv2);
    k_xw<<<dim3(kk / 2), dim3(128, 2), 0, stream>>>(t, down_w + (size_t)H * H, dv2, t2, kk, H);
    gcn(A2m, t2, dv2, down_b + H, h2, kk, 1);
  }
  {
    int n = 1024, kk = 512;
    k_wnorm<<<1, 64, 0, stream>>>(pool_w + 2 * H, wn + 2);
    k_score<<<n / 4, 256, 0, stream>>>(h2, pool_w + 2 * H, wn + 2, score, n);
    k_topk<<<1, 1024, 0, stream>>>(score, n, perm2);
    k_pool<<<(kk * H) / 256, 256, 0, stream>>>(h2, score, perm2, t, kk);
    hipMemsetAsync(A3, 0, (size_t)kk * kk * 4, stream);
    k_ata_sk<<<dim3(kk / 64, kk / 64, 8), 256, 0, stream>>>(A2m, perm2, A3, n, kk, 128);
    k_deg<<<kk / 4, 256, 0, stream>>>(A3, kk, dv3);
    k_xw<<<dim3(kk / 2), dim3(128, 2), 0, stream>>>(t, down_w + (size_t)2 * H * H, dv3, t2, kk, H);
    gcn(A3, t2, dv3, down_b + 2 * H, h3, kk, 1);
  }

  // ---- up path ----
  hipMemcpyAsync(t, h2, (size_t)1024 * H * 4, hipMemcpyDeviceToDevice, stream);
  k_scatter<<<(512 * H) / 256, 256, 0, stream>>>(h3, perm2, t, 512);
  k_xw<<<dim3(1024 / 2), dim3(128, 2), 0, stream>>>(t, up_w, dv2, t2, 1024, H);
  gcn(A2m, t2, dv2, up_b, hu, 1024, 1);

  hipMemcpyAsync(t, h1, (size_t)2048 * H * 4, hipMemcpyDeviceToDevice, stream);
  k_scatter<<<(1024 * H) / 256, 256, 0, stream>>>(hu, perm1, t, 1024);
  k_xw<<<dim3(2048 / 2), dim3(128, 2), 0, stream>>>(t, up_w + (size_t)H * H, dv1, t2, 2048, H);
  gcn(A1, t2, dv1, up_b + H, hu, 2048, 1);

  hipMemcpyAsync(t, h0, (size_t)4096 * H * 4, hipMemcpyDeviceToDevice, stream);
  k_scatter<<<(2048 * H) / 256, 256, 0, stream>>>(hu, perm0, t, 2048);
  k_xw<<<dim3(4096 / 2), dim3(128, 2), 0, stream>>>(t, up_w + (size_t)2 * H * H, dv0, t2, 4096, H);
  k_spmm_fin<<<1024, 256, 0, stream>>>(rowptr, colidx, t2, dv0, up_b + 2 * H, hu, 4096, 0);

  // ---- pool + head ----
  hipMemsetAsync(g, 0, NG * H * 4, stream);
  k_segsum<<<4096 / 32, 128, 0, stream>>>(hu, batch, g, 4096);
  k_head<<<1, 256, 0, stream>>>(g, lins_w, lins_b, bn_g, bn_b, out_w, out_b, (float*)d_out);
}

// Round 4
// 863.965 us; speedup vs baseline: 4.9006x; 1.0912x over previous
//
#include <hip/hip_runtime.h>
#include <math.h>

#define H 128
#define NG 8
#define MAXL 512

typedef __attribute__((ext_vector_type(8))) short bf16x8;
typedef __attribute__((ext_vector_type(8))) unsigned short ushort8;
typedef __attribute__((ext_vector_type(4))) float f32x4;

static __device__ __forceinline__ float b2f(unsigned short u) {
  union { unsigned int i; float f; } v;
  v.i = ((unsigned int)u) << 16;
  return v.f;
}
static __device__ __forceinline__ unsigned short f2b(float f) {
  // exact for our small-integer values (all <= 2^8)
  return (unsigned short)(__float_as_uint(f) >> 16);
}

// ---------------- CSR build from edge list ----------------
__global__ void k_hist(const int* __restrict__ ei, int E, int* __restrict__ cnt) {
  int e = blockIdx.x * 256 + threadIdx.x;
  if (e >= E) return;
  atomicAdd(&cnt[ei[E + e]], 1);
}

__global__ __launch_bounds__(1024) void k_scan(const int* __restrict__ cnt,
                                               int* __restrict__ rowptr, int n) {
  __shared__ int sums[1024];
  int tid = threadIdx.x;
  int base = tid * 4;
  int v0 = 0, v1 = 0, v2 = 0, v3 = 0;
  if (base < n) { v0 = cnt[base]; v1 = cnt[base + 1]; v2 = cnt[base + 2]; v3 = cnt[base + 3]; }
  int s = v0 + v1 + v2 + v3;
  sums[tid] = s;
  __syncthreads();
  for (int off = 1; off < 1024; off <<= 1) {
    int t = (tid >= off) ? sums[tid - off] : 0;
    __syncthreads();
    sums[tid] += t;
    __syncthreads();
  }
  int excl = sums[tid] - s;
  if (base < n) {
    rowptr[base] = excl;
    rowptr[base + 1] = excl + v0;
    rowptr[base + 2] = excl + v0 + v1;
    rowptr[base + 3] = excl + v0 + v1 + v2;
  }
  if (tid == 1023) rowptr[n] = sums[1023];
}

__global__ void k_fill(const int* __restrict__ ei, int E, const int* __restrict__ rowptr,
                       int* __restrict__ cursor, int* __restrict__ colidx) {
  int e = blockIdx.x * 256 + threadIdx.x;
  if (e >= E) return;
  int r = ei[E + e], c = ei[e];
  int p = atomicAdd(&cursor[r], 1);
  colidx[rowptr[r] + p] = c;
}

__global__ void k_dvcnt(const int* __restrict__ cnt, float* __restrict__ dv, int n) {
  int i = blockIdx.x * 256 + threadIdx.x;
  if (i < n) dv[i] = rsqrtf((float)cnt[i] + 2.0f);
}

// fp32 -> bf16 (exact for small ints)
__global__ void k_cvt_b16(const float* __restrict__ A, unsigned short* __restrict__ Ab, int total) {
  int i = blockIdx.x * 256 + threadIdx.x;
  if (i * 4 >= total) return;
  float4 v = *(const float4*)&A[i * 4];
  unsigned long long w = ((unsigned long long)(__float_as_uint(v.x) >> 16))
                       | ((unsigned long long)(__float_as_uint(v.y) >> 16) << 16)
                       | ((unsigned long long)(__float_as_uint(v.z) >> 16) << 32)
                       | ((unsigned long long)(__float_as_uint(v.w) >> 16) << 48);
  *(unsigned long long*)&Ab[i * 4] = w;
}

// d[i] = rsqrt(rowsum(A)+2) for dense fp32 A
__global__ void k_deg(const float* __restrict__ A, int n, float* __restrict__ dv) {
  int row = blockIdx.x * (blockDim.x >> 6) + (threadIdx.x >> 6);
  int lane = threadIdx.x & 63;
  if (row >= n) return;
  float s = 0.f;
  const float* arow = A + (size_t)row * n;
  for (int j = lane; j < n; j += 64) s += arow[j];
#pragma unroll
  for (int o = 32; o > 0; o >>= 1) s += __shfl_down(s, o);
  if (lane == 0) dv[row] = rsqrtf(s + 2.0f);
}

__global__ void k_deg_b16(const unsigned short* __restrict__ Ab, int n, float* __restrict__ dv) {
  int row = blockIdx.x * 4 + (threadIdx.x >> 6);
  int lane = threadIdx.x & 63;
  const unsigned short* ar = Ab + (size_t)row * n;
  float s = 0.f;
  for (int j = lane * 4; j < n; j += 256) {
    unsigned long long w = *(const unsigned long long*)&ar[j];
    s += b2f((unsigned short)w) + b2f((unsigned short)(w >> 16)) +
         b2f((unsigned short)(w >> 32)) + b2f((unsigned short)(w >> 48));
  }
#pragma unroll
  for (int o = 32; o > 0; o >>= 1) s += __shfl_down(s, o);
  if (lane == 0) dv[row] = rsqrtf(s + 2.0f);
}

// Y[r,c] = dv[r] * sum_k X[r,k] W[k,c]
__global__ void k_xw(const float* __restrict__ X, const float* __restrict__ W,
                     const float* __restrict__ dv, float* __restrict__ Y,
                     int n, int F) {
  int col = threadIdx.x;
  int row = blockIdx.x * blockDim.y + threadIdx.y;
  if (row >= n) return;
  float acc = 0.f;
  const float* xr = X + (size_t)row * F;
  for (int k = 0; k < F; ++k) acc += xr[k] * W[k * H + col];
  Y[(size_t)row * H + col] = dv[row] * acc;
}

// sparse GCN epilogue
__global__ void k_spmm_fin(const int* __restrict__ rowptr, const int* __restrict__ colidx,
                           const float* __restrict__ Y, const float* __restrict__ dv,
                           const float* __restrict__ bias, float* __restrict__ Out,
                           int n, int relu) {
  int row = blockIdx.x * 4 + (threadIdx.x >> 6);
  int lane = threadIdx.x & 63;
  if (row >= n) return;
  int s = rowptr[row], e = rowptr[row + 1];
  float a0 = 0.f, a1 = 0.f;
  int i = s;
  for (; i + 1 < e; i += 2) {
    int c0 = colidx[i], c1 = colidx[i + 1];
    a0 += Y[(size_t)c0 * H + lane] + Y[(size_t)c1 * H + lane];
    a1 += Y[(size_t)c0 * H + 64 + lane] + Y[(size_t)c1 * H + 64 + lane];
  }
  if (i < e) {
    int c = colidx[i];
    a0 += Y[(size_t)c * H + lane];
    a1 += Y[(size_t)c * H + 64 + lane];
  }
  float d = dv[row];
  float v0 = d * (a0 + 2.0f * Y[(size_t)row * H + lane]) + bias[lane];
  float v1 = d * (a1 + 2.0f * Y[(size_t)row * H + 64 + lane]) + bias[64 + lane];
  if (relu) { v0 = fmaxf(v0, 0.f); v1 = fmaxf(v1, 0.f); }
  Out[(size_t)row * H + lane] = v0;
  Out[(size_t)row * H + 64 + lane] = v1;
}

// sparse ATA (level 0)
__global__ __launch_bounds__(256) void k_ata_sparse(const int* __restrict__ rowptr,
                                                    const int* __restrict__ colidx,
                                                    const int* __restrict__ inv,
                                                    float* __restrict__ C, int k) {
  __shared__ int lidx[MAXL];
  __shared__ int cnt;
  int kcol = blockIdx.x;
  int tid = threadIdx.x;
  if (tid == 0) cnt = 0;
  __syncthreads();
  int s = rowptr[kcol], e = rowptr[kcol + 1];
  for (int i = s + tid; i < e; i += 256) {
    int ii = inv[colidx[i]];
    if (ii >= 0) { int p = atomicAdd(&cnt, 1); if (p < MAXL) lidx[p] = ii; }
  }
  if (tid == 0) {
    int ii = inv[kcol];
    if (ii >= 0) { int p = atomicAdd(&cnt, 1); if (p < MAXL) lidx[p] = ii; }
  }
  __syncthreads();
  int c = min(cnt, MAXL);
  int tot = c * c;
  for (int t = tid; t < tot; t += 256) {
    int a = t / c, b = t - a * c;
    int ia = lidx[a], ib = lidx[b];
    if (ia != ib) atomicAdd(&C[(size_t)ia * k + ib], 1.0f);
  }
}

// gather permuted S-rows into bf16 P (with +I), exact
__global__ void k_gather(const unsigned short* __restrict__ Ab, const int* __restrict__ perm,
                         unsigned short* __restrict__ P, int n, int k) {
  int row = blockIdx.x;
  int p = perm[row];
  const unsigned short* src = Ab + (size_t)p * n;
  unsigned short* dst = P + (size_t)row * n;
  for (int c = threadIdx.x * 8; c < n; c += 256 * 8) {
    *(ushort8*)&dst[c] = *(const ushort8*)&src[c];
  }
  __syncthreads();
  if (threadIdx.x == 0) dst[p] = f2b(b2f(src[p]) + 1.0f);  // +I on the diagonal column
}

// C = P @ P^T via bf16 MFMA (exact: small-integer entries). Diagonal zeroed.
__global__ __launch_bounds__(256) void k_ata_mfma(const unsigned short* __restrict__ P,
                                                  float* __restrict__ C, int n, int k) {
  __shared__ __align__(16) unsigned short As[64][64];
  __shared__ __align__(16) unsigned short Bs[64][64];
  int tid = threadIdx.x;
  int w = tid >> 6, ln = tid & 63;
  int l15 = ln & 15, l4 = ln >> 4;
  int br = blockIdx.y, bc = blockIdx.x;
  f32x4 acc[4] = {};
  for (int k0 = 0; k0 < n; k0 += 64) {
#pragma unroll
    for (int it = 0; it < 2; ++it) {
      int e = tid + it * 256;        // 0..511: 64 rows x 8 chunks of 8 bf16
      int row = e >> 3, ch = e & 7;
      int sch = (ch ^ (row & 7)) * 8;   // XOR swizzle: conflict-free frag reads
      *(ushort8*)&As[row][sch] = *(const ushort8*)&P[(size_t)(br * 64 + row) * n + k0 + ch * 8];
      *(ushort8*)&Bs[row][sch] = *(const ushort8*)&P[(size_t)(bc * 64 + row) * n + k0 + ch * 8];
    }
    __syncthreads();
#pragma unroll
    for (int s = 0; s < 2; ++s) {
      int arow = w * 16 + l15;
      bf16x8 af = *(const bf16x8*)&As[arow][((s * 4 + l4) ^ (arow & 7)) * 8];
#pragma unroll
      for (int f = 0; f < 4; ++f) {
        int brow = f * 16 + l15;
        bf16x8 bfr = *(const bf16x8*)&Bs[brow][((s * 4 + l4) ^ (brow & 7)) * 8];
        acc[f] = __builtin_amdgcn_mfma_f32_16x16x32_bf16(af, bfr, acc[f], 0, 0, 0);
      }
    }
    __syncthreads();
  }
#pragma unroll
  for (int f = 0; f < 4; ++f) {
#pragma unroll
    for (int r = 0; r < 4; ++r) {
      int gi = br * 64 + w * 16 + l4 * 4 + r;   // C/D layout: col=lane&15, row=(lane>>4)*4+reg
      int gj = bc * 64 + f * 16 + l15;
      C[(size_t)gi * k + gj] = (gi == gj) ? 0.0f : acc[f][r];
    }
  }
}

// dense fp32 ATA split-K (level 2 only; A2 entries may exceed bf16-exact range)
__global__ __launch_bounds__(256) void k_ata_sk(const float* __restrict__ A,
                                                const int* __restrict__ perm,
                                                float* __restrict__ C, int n, int k, int CK) {
  int bc = blockIdx.x, br = blockIdx.y;
  if (br > bc) return;
  __shared__ float As[64][36];
  __shared__ float Bs[64][36];
  __shared__ int pr[64], pc[64];
  int tid = threadIdx.x;
  if (tid < 64) pr[tid] = perm[br * 64 + tid];
  else if (tid < 128) pc[tid - 64] = perm[bc * 64 + (tid - 64)];
  __syncthreads();
  int ty = tid >> 4;
  int tx = tid & 15;
  float acc[4][4] = {};
  int k0s = blockIdx.z * CK;
  for (int k0 = k0s; k0 < k0s + CK; k0 += 32) {
#pragma unroll
    for (int it = 0, e = tid; it < 8; ++it, e += 256) {
      int ii = e >> 5, kk = e & 31;
      int gk = k0 + kk;
      int p = pr[ii];
      As[ii][kk] = A[(size_t)p * n + gk] + ((p == gk) ? 1.0f : 0.0f);
      p = pc[ii];
      Bs[ii][kk] = A[(size_t)p * n + gk] + ((p == gk) ? 1.0f : 0.0f);
    }
    __syncthreads();
#pragma unroll
    for (int kk = 0; kk < 32; kk += 4) {
      float4 a4[4], b4[4];
#pragma unroll
      for (int i = 0; i < 4; ++i) a4[i] = *(const float4*)&As[ty + 16 * i][kk];
#pragma unroll
      for (int j = 0; j < 4; ++j) b4[j] = *(const float4*)&Bs[tx + 16 * j][kk];
#pragma unroll
      for (int i = 0; i < 4; ++i) {
        float av[4] = {a4[i].x, a4[i].y, a4[i].z, a4[i].w};
#pragma unroll
        for (int j = 0; j < 4; ++j) {
          float bv[4] = {b4[j].x, b4[j].y, b4[j].z, b4[j].w};
#pragma unroll
          for (int s = 0; s < 4; ++s) acc[i][j] = fmaf(av[s], bv[s], acc[i][j]);
        }
      }
    }
    __syncthreads();
  }
  bool diag = (br == bc);
#pragma unroll
  for (int i = 0; i < 4; ++i) {
    int gi = br * 64 + ty + 16 * i;
#pragma unroll
    for (int j = 0; j < 4; ++j) {
      int gj = bc * 64 + tx + 16 * j;
      if (gi == gj) continue;
      float v = acc[i][j];
      atomicAdd(&C[(size_t)gi * k + gj], v);
      if (!diag) atomicAdd(&C[(size_t)gj * k + gi], v);
    }
  }
}

// fp32 dense GCN partial (split-K)
__global__ __launch_bounds__(256) void k_gcn_part(const float* __restrict__ A,
                                                  const float* __restrict__ Y,
                                                  float* __restrict__ Acc,
                                                  int n, int KC) {
  __shared__ float As[64][36];
  __shared__ float Ys[32][132];
  int tid = threadIdx.x;
  int r0 = (tid >> 5) << 3;
  int c0 = (tid & 31) << 2;
  size_t rowBase = (size_t)blockIdx.x * 64;
  int k0s = blockIdx.y * KC;
  float acc[8][4] = {};
  for (int k0 = k0s; k0 < k0s + KC; k0 += 32) {
#pragma unroll
    for (int it = 0, e = tid; it < 8; ++it, e += 256) {
      int ii = e >> 5, kk = e & 31;
      As[ii][kk] = A[(rowBase + ii) * (size_t)n + k0 + kk];
    }
#pragma unroll
    for (int it = 0, e = tid; it < 4; ++it, e += 256) {
      int kk = e >> 5, cc4 = e & 31;
      *(float4*)&Ys[kk][cc4 << 2] = *(const float4*)&Y[(size_t)(k0 + kk) * H + (cc4 << 2)];
    }
    __syncthreads();
#pragma unroll
    for (int kk = 0; kk < 32; kk += 4) {
      float4 a4[8], y4[4];
#pragma unroll
      for (int i = 0; i < 8; ++i) a4[i] = *(const float4*)&As[r0 + i][kk];
#pragma unroll
      for (int s = 0; s < 4; ++s) y4[s] = *(const float4*)&Ys[kk + s][c0];
#pragma unroll
      for (int i = 0; i < 8; ++i) {
        float av[4] = {a4[i].x, a4[i].y, a4[i].z, a4[i].w};
#pragma unroll
        for (int s = 0; s < 4; ++s) {
          float yv[4] = {y4[s].x, y4[s].y, y4[s].z, y4[s].w};
#pragma unroll
          for (int j = 0; j < 4; ++j) acc[i][j] = fmaf(av[s], yv[j], acc[i][j]);
        }
      }
    }
    __syncthreads();
  }
#pragma unroll
  for (int i = 0; i < 8; ++i) {
    size_t row = rowBase + r0 + i;
#pragma unroll
    for (int j = 0; j < 4; ++j) atomicAdd(&Acc[row * H + c0 + j], acc[i][j]);
  }
}

// same but A stored as bf16 (exact small ints) -> half the HBM traffic
__global__ __launch_bounds__(256) void k_gcn_part_b16(const unsigned short* __restrict__ A,
                                                      const float* __restrict__ Y,
                                                      float* __restrict__ Acc,
                                                      int n, int KC) {
  __shared__ float As[64][36];
  __shared__ float Ys[32][132];
  int tid = threadIdx.x;
  int r0 = (tid >> 5) << 3;
  int c0 = (tid & 31) << 2;
  size_t rowBase = (size_t)blockIdx.x * 64;
  int k0s = blockIdx.y * KC;
  float acc[8][4] = {};
  for (int k0 = k0s; k0 < k0s + KC; k0 += 32) {
    {
      int row = tid >> 2, ch = (tid & 3) * 8;
      ushort8 v = *(const ushort8*)&A[(rowBase + row) * (size_t)n + k0 + ch];
#pragma unroll
      for (int q = 0; q < 8; ++q) As[row][ch + q] = b2f(v[q]);
    }
#pragma unroll
    for (int it = 0, e = tid; it < 4; ++it, e += 256) {
      int kk = e >> 5, cc4 = e & 31;
      *(float4*)&Ys[kk][cc4 << 2] = *(const float4*)&Y[(size_t)(k0 + kk) * H + (cc4 << 2)];
    }
    __syncthreads();
#pragma unroll
    for (int kk = 0; kk < 32; kk += 4) {
      float4 a4[8], y4[4];
#pragma unroll
      for (int i = 0; i < 8; ++i) a4[i] = *(const float4*)&As[r0 + i][kk];
#pragma unroll
      for (int s = 0; s < 4; ++s) y4[s] = *(const float4*)&Ys[kk + s][c0];
#pragma unroll
      for (int i = 0; i < 8; ++i) {
        float av[4] = {a4[i].x, a4[i].y, a4[i].z, a4[i].w};
#pragma unroll
        for (int s = 0; s < 4; ++s) {
          float yv[4] = {y4[s].x, y4[s].y, y4[s].z, y4[s].w};
#pragma unroll
          for (int j = 0; j < 4; ++j) acc[i][j] = fmaf(av[s], yv[j], acc[i][j]);
        }
      }
    }
    __syncthreads();
  }
#pragma unroll
  for (int i = 0; i < 8; ++i) {
    size_t row = rowBase + r0 + i;
#pragma unroll
    for (int j = 0; j < 4; ++j) atomicAdd(&Acc[row * H + c0 + j], acc[i][j]);
  }
}

__global__ void k_gcn_fin(const float* __restrict__ Acc, const float* __restrict__ Y,
                          const float* __restrict__ dv, const float* __restrict__ bias,
                          float* __restrict__ Out, int n, int relu) {
  int idx = blockIdx.x * 256 + threadIdx.x;
  if (idx >= n * H) return;
  int row = idx >> 7, col = idx & 127;
  float v = Acc[idx] + 2.0f * Y[idx];
  v = dv[row] * v + bias[col];
  if (relu) v = fmaxf(v, 0.0f);
  Out[idx] = v;
}

// score = tanh((h@w)/||w||); ||w|| computed in-block (fuses old k_wnorm)
__global__ void k_score(const float* __restrict__ h, const float* __restrict__ w,
                        float* __restrict__ score, int n) {
  __shared__ float wn;
  int tid = threadIdx.x;
  if (tid < 64) {
    float s = w[tid] * w[tid] + w[tid + 64] * w[tid + 64];
#pragma unroll
    for (int o = 32; o > 0; o >>= 1) s += __shfl_down(s, o);
    if (tid == 0) wn = sqrtf(s);
  }
  __syncthreads();
  int row = blockIdx.x * 4 + (tid >> 6);
  int lane = tid & 63;
  if (row >= n) return;
  float s = h[(size_t)row * H + lane] * w[lane] + h[(size_t)row * H + lane + 64] * w[lane + 64];
#pragma unroll
  for (int o = 32; o > 0; o >>= 1) s += __shfl_down(s, o);
  if (lane == 0) score[row] = tanhf(s / wn);
}

// ---- hybrid bitonic top-k: 4 elems/thread in regs; shfl for strides 4..128; LDS >=256 ----
static __device__ __forceinline__ void ce_(unsigned long long& x, unsigned long long& y, bool asc) {
  if ((x < y) != asc) { unsigned long long t = x; x = y; y = t; }
}
static __device__ __forceinline__ unsigned long long pick_(unsigned long long a,
                                                           unsigned long long b,
                                                           bool lower, bool asc) {
  unsigned long long lo = (a < b) ? a : b;
  unsigned long long hi = (a < b) ? b : a;
  return (lower == asc) ? lo : hi;
}

template <int LOGN>
__global__ __launch_bounds__(1024) void k_topk(const float* __restrict__ score,
                                               int* __restrict__ perm,
                                               int* __restrict__ inv) {
  const int n = 1 << LOGN;
  __shared__ unsigned long long lds[1 << LOGN];
  int t = threadIdx.x;
  int e0 = t * 4;
  unsigned long long key[4];
#pragma unroll
  for (int j = 0; j < 4; ++j) {
    unsigned u = __float_as_uint(score[e0 + j]);
    u = (u & 0x80000000u) ? ~u : (u | 0x80000000u);  // orderable ascending
    u = ~u;                                          // descending score
    key[j] = (((unsigned long long)u) << 32) | (unsigned)(e0 + j);
  }
  ce_(key[0], key[1], true);
  ce_(key[2], key[3], false);
  for (int size = 4; size <= n; size <<= 1) {
    bool asc = ((e0 & size) == 0);
    for (int stride = size >> 1; stride >= 256; stride >>= 1) {
#pragma unroll
      for (int j = 0; j < 4; ++j) lds[e0 + j] = key[j];
      __syncthreads();
      bool lower = ((e0 & stride) == 0);
#pragma unroll
      for (int j = 0; j < 4; ++j)
        key[j] = pick_(key[j], lds[(e0 + j) ^ stride], lower, asc);
      __syncthreads();
    }
    int s0 = ((size >> 1) < 256) ? (size >> 1) : 128;
    for (int stride = s0; stride >= 4; stride >>= 1) {
      int m = stride >> 2;
      bool lower = ((t & m) == 0);
#pragma unroll
      for (int j = 0; j < 4; ++j) {
        unsigned long long o = __shfl_xor(key[j], m, 64);
        key[j] = pick_(key[j], o, lower, asc);
      }
    }
    ce_(key[0], key[2], asc);
    ce_(key[1], key[3], asc);
    ce_(key[0], key[1], asc);
    ce_(key[2], key[3], asc);
  }
  int kk = n >> 1;
#pragma unroll
  for (int j = 0; j < 4; ++j) {
    int e = e0 + j;
    int idx = (int)(key[j] & 0xffffffffu);
    if (e < kk) perm[e] = idx;
    if (inv) inv[idx] = (e < kk) ? e : -1;
  }
}

__global__ void k_pool(const float* __restrict__ h, const float* __restrict__ score,
                       const int* __restrict__ perm, float* __restrict__ hp, int k) {
  int idx = blockIdx.x * 256 + threadIdx.x;
  if (idx >= k * H) return;
  int r = idx >> 7, c = idx & 127;
  int p = perm[r];
  hp[idx] = h[(size_t)p * H + c] * score[p];
}

__global__ void k_scatter(const float* __restrict__ hprev, const int* __restrict__ perm,
                          float* __restrict__ u, int k) {
  int idx = blockIdx.x * 256 + threadIdx.x;
  if (idx >= k * H) return;
  int r = idx >> 7, c = idx & 127;
  u[(size_t)perm[r] * H + c] += hprev[idx];
}

__global__ void k_segsum(const float* __restrict__ h, const int* __restrict__ batch,
                         float* __restrict__ g, int n) {
  int c = threadIdx.x;
  int r0 = blockIdx.x * 32;
  int rend = min(r0 + 32, n);
  float acc = 0.f;
  int cur = batch[r0];
  for (int r = r0; r < rend; ++r) {
    int b = batch[r];
    if (b != cur) { atomicAdd(&g[cur * H + c], acc); acc = 0.f; cur = b; }
    acc += h[(size_t)r * H + c];
  }
  atomicAdd(&g[cur * H + c], acc);
}

__global__ __launch_bounds__(256) void k_head(const float* __restrict__ g,
    const float* __restrict__ lins_w, const float* __restrict__ lins_b,
    const float* __restrict__ bn_g, const float* __restrict__ bn_b,
    const float* __restrict__ out_w, const float* __restrict__ out_b,
    float* __restrict__ out) {
  __shared__ float a[NG * H], b[NG * H];
  int tid = threadIdx.x;
  const float inv = 1.0f / sqrtf(1.0f + 1e-5f);
  for (int i = tid; i < NG * H; i += 256) a[i] = g[i];
  __syncthreads();
  for (int L = 0; L < 3; ++L) {
    for (int i = tid; i < NG * H; i += 256) {
      int c = i & 127;
      b[i] = a[i] * (bn_g[L * H + c] * inv) + bn_b[L * H + c];
    }
    __syncthreads();
    for (int i = tid; i < NG * H; i += 256) {
      int r = i >> 7, c = i & 127;
      float s = lins_b[L * H + c];
      for (int k2 = 0; k2 < H; ++k2) s += b[r * H + k2] * lins_w[(size_t)L * H * H + k2 * H + c];
      a[i] = tanhf(s);
    }
    __syncthreads();
  }
  for (int i = tid; i < NG * H; i += 256) {
    int c = i & 127;
    b[i] = a[i] * (bn_g[3 * H + c] * inv) + bn_b[3 * H + c];
  }
  __syncthreads();
  for (int i = tid; i < NG * 32; i += 256) {
    int r = i >> 5, o = i & 31;
    float s = out_b[o];
    for (int k2 = 0; k2 < H; ++k2) s += b[r * H + k2] * out_w[k2 * 32 + o];
    out[i] = s;
  }
}

extern "C" void kernel_launch(void* const* d_in, const int* in_sizes, int n_in,
                              void* d_out, int out_size, void* d_ws, size_t ws_size,
                              hipStream_t stream) {
  const float* x       = (const float*)d_in[0];
  const int*   ei      = (const int*)d_in[1];
  const int*   batch   = (const int*)d_in[2];
  const float* conv0_w = (const float*)d_in[3];
  const float* conv0_b = (const float*)d_in[4];
  const float* down_w  = (const float*)d_in[5];
  const float* down_b  = (const float*)d_in[6];
  const float* pool_w  = (const float*)d_in[7];
  const float* up_w    = (const float*)d_in[8];
  const float* up_b    = (const float*)d_in[9];
  const float* lins_w  = (const float*)d_in[10];
  const float* lins_b  = (const float*)d_in[11];
  const float* bn_g    = (const float*)d_in[12];
  const float* bn_b    = (const float*)d_in[13];
  const float* out_w   = (const float*)d_in[14];
  const float* out_b   = (const float*)d_in[15];
  int E = in_sizes[1] / 2;

  char* p = (char*)d_ws;
  auto alloc = [&](size_t bytes) {
    char* r = p;
    p += (bytes + 255) & ~(size_t)255;
    return r;
  };
  float*          A1   = (float*)alloc((size_t)2048 * 2048 * 4);
  unsigned short* A1b  = (unsigned short*)alloc((size_t)2048 * 2048 * 2);
  unsigned short* P    = (unsigned short*)alloc((size_t)1024 * 2048 * 2);
  float*          A2m  = (float*)alloc((size_t)1024 * 1024 * 4);
  float*          A3   = (float*)alloc((size_t)512 * 512 * 4);
  int* cnt    = (int*)alloc(4096 * 4);
  int* cursor = (int*)alloc(4096 * 4);
  int* rowptr = (int*)alloc(4100 * 4);
  int* colidx = (int*)alloc((size_t)E * 4);
  int* invm   = (int*)alloc(4096 * 4);
  float* dv0  = (float*)alloc(4096 * 4);
  float* dv1  = (float*)alloc(2048 * 4);
  float* dv2  = (float*)alloc(1024 * 4);
  float* dv3  = (float*)alloc(512 * 4);
  int* perm0  = (int*)alloc(2048 * 4);
  int* perm1  = (int*)alloc(1024 * 4);
  int* perm2  = (int*)alloc(512 * 4);
  float* score = (float*)alloc(4096 * 4);
  float* h0 = (float*)alloc((size_t)4096 * H * 4);
  float* h1 = (float*)alloc((size_t)2048 * H * 4);
  float* h2 = (float*)alloc((size_t)1024 * H * 4);
  float* h3 = (float*)alloc((size_t)512 * H * 4);
  float* t  = (float*)alloc((size_t)4096 * H * 4);
  float* t2 = (float*)alloc((size_t)4096 * H * 4);
  float* hu = (float*)alloc((size_t)4096 * H * 4);
  float* acc = (float*)alloc((size_t)2048 * H * 4);
  float* g  = (float*)alloc(NG * H * 4);

  // dense gcn: Out = act(dv .* (A@Y + 2Y) + bias), split-K; Ab!=null -> bf16 A path
  auto gcn = [&](const float* A, const unsigned short* Ab, const float* Y, const float* dvv,
                 const float* bias, float* Out, int nn, int relu) {
    int KC = (nn >= 2048) ? 128 : (nn >= 1024 ? 64 : 32);
    hipMemsetAsync(acc, 0, (size_t)nn * H * 4, stream);
    if (Ab)
      k_gcn_part_b16<<<dim3(nn / 64, nn / KC), 256, 0, stream>>>(Ab, Y, acc, nn, KC);
    else
      k_gcn_part<<<dim3(nn / 64, nn / KC), 256, 0, stream>>>(A, Y, acc, nn, KC);
    k_gcn_fin<<<(nn * H) / 256, 256, 0, stream>>>(acc, Y, dvv, bias, Out, nn, relu);
  };

  // ---- CSR build ----
  hipMemsetAsync(cnt, 0, 4096 * 4, stream);
  hipMemsetAsync(cursor, 0, 4096 * 4, stream);
  k_hist<<<(E + 255) / 256, 256, 0, stream>>>(ei, E, cnt);
  k_scan<<<1, 1024, 0, stream>>>(cnt, rowptr, 4096);
  k_fill<<<(E + 255) / 256, 256, 0, stream>>>(ei, E, rowptr, cursor, colidx);
  k_dvcnt<<<4096 / 256, 256, 0, stream>>>(cnt, dv0, 4096);

  // ---- conv0 (sparse) ----
  k_xw<<<dim3(2048), dim3(128, 2), 0, stream>>>(x, conv0_w, dv0, t2, 4096, 64);
  k_spmm_fin<<<1024, 256, 0, stream>>>(rowptr, colidx, t2, dv0, conv0_b, h0, 4096, 1);

  // ---- level 0 pooling (4096 -> 2048): sparse ATA ----
  k_score<<<1024, 256, 0, stream>>>(h0, pool_w, score, 4096);
  k_topk<12><<<1, 1024, 0, stream>>>(score, perm0, invm);
  k_pool<<<(2048 * H) / 256, 256, 0, stream>>>(h0, score, perm0, t, 2048);
  hipMemsetAsync(A1, 0, (size_t)2048 * 2048 * 4, stream);
  k_ata_sparse<<<4096, 256, 0, stream>>>(rowptr, colidx, invm, A1, 2048);
  k_cvt_b16<<<(2048 * 2048 / 4 + 255) / 256, 256, 0, stream>>>(A1, A1b, 2048 * 2048);
  k_deg_b16<<<2048 / 4, 256, 0, stream>>>(A1b, 2048, dv1);
  k_xw<<<dim3(1024), dim3(128, 2), 0, stream>>>(t, down_w, dv1, t2, 2048, H);
  gcn(nullptr, A1b, t2, dv1, down_b, h1, 2048, 1);

  // ---- level 1 pooling (2048 -> 1024): bf16 MFMA ATA (exact small ints) ----
  k_score<<<512, 256, 0, stream>>>(h1, pool_w + H, score, 2048);
  k_topk<11><<<1, 512, 0, stream>>>(score, perm1, nullptr);
  k_pool<<<(1024 * H) / 256, 256, 0, stream>>>(h1, score, perm1, t, 1024);
  k_gather<<<1024, 256, 0, stream>>>(A1b, perm1, P, 2048, 1024);
  k_ata_mfma<<<dim3(16, 16), 256, 0, stream>>>(P, A2m, 2048, 1024);
  k_deg<<<1024 / 4, 256, 0, stream>>>(A2m, 1024, dv2);
  k_xw<<<dim3(512), dim3(128, 2), 0, stream>>>(t, down_w + (size_t)H * H, dv2, t2, 1024, H);
  gcn(A2m, nullptr, t2, dv2, down_b + H, h2, 1024, 1);

  // ---- level 2 pooling (1024 -> 512): fp32 split-K ATA ----
  k_score<<<256, 256, 0, stream>>>(h2, pool_w + 2 * H, score, 1024);
  k_topk<10><<<1, 256, 0, stream>>>(score, perm2, nullptr);
  k_pool<<<(512 * H) / 256, 256, 0, stream>>>(h2, score, perm2, t, 512);
  hipMemsetAsync(A3, 0, (size_t)512 * 512 * 4, stream);
  k_ata_sk<<<dim3(8, 8, 8), 256, 0, stream>>>(A2m, perm2, A3, 1024, 512, 128);
  k_deg<<<512 / 4, 256, 0, stream>>>(A3, 512, dv3);
  k_xw<<<dim3(256), dim3(128, 2), 0, stream>>>(t, down_w + (size_t)2 * H * H, dv3, t2, 512, H);
  gcn(A3, nullptr, t2, dv3, down_b + 2 * H, h3, 512, 1);

  // ---- up path ----
  hipMemcpyAsync(t, h2, (size_t)1024 * H * 4, hipMemcpyDeviceToDevice, stream);
  k_scatter<<<(512 * H) / 256, 256, 0, stream>>>(h3, perm2, t, 512);
  k_xw<<<dim3(512), dim3(128, 2), 0, stream>>>(t, up_w, dv2, t2, 1024, H);
  gcn(A2m, nullptr, t2, dv2, up_b, hu, 1024, 1);

  hipMemcpyAsync(t, h1, (size_t)2048 * H * 4, hipMemcpyDeviceToDevice, stream);
  k_scatter<<<(1024 * H) / 256, 256, 0, stream>>>(hu, perm1, t, 1024);
  k_xw<<<dim3(1024), dim3(128, 2), 0, stream>>>(t, up_w + (size_t)H * H, dv1, t2, 2048, H);
  gcn(nullptr, A1b, t2, dv1, up_b + H, hu, 2048, 1);

  hipMemcpyAsync(t, h0, (size_t)4096 * H * 4, hipMemcpyDeviceToDevice, stream);
  k_scatter<<<(2048 * H) / 256, 256, 0, stream>>>(hu, perm0, t, 2048);
  k_xw<<<dim3(2048), dim3(128, 2), 0, stream>>>(t, up_w + (size_t)2 * H * H, dv0, t2, 4096, H);
  k_spmm_fin<<<1024, 256, 0, stream>>>(rowptr, colidx, t2, dv0, up_b + 2 * H, hu, 4096, 0);

  // ---- pool + head ----
  hipMemsetAsync(g, 0, NG * H * 4, stream);
  k_segsum<<<4096 / 32, 128, 0, stream>>>(hu, batch, g, 4096);
  k_head<<<1, 256, 0, stream>>>(g, lins_w, lins_b, bn_g, bn_b, out_w, out_b, (float*)d_out);
}

// Round 5
// 715.880 us; speedup vs baseline: 5.9143x; 1.2069x over previous
//
#include <hip/hip_runtime.h>
#include <math.h>

#define H 128
#define NG 8
#define MAXL 512

typedef __attribute__((ext_vector_type(8))) short bf16x8;
typedef __attribute__((ext_vector_type(8))) unsigned short ushort8;
typedef __attribute__((ext_vector_type(4))) float f32x4;

static __device__ __forceinline__ float b2f(unsigned short u) {
  union { unsigned int i; float f; } v;
  v.i = ((unsigned int)u) << 16;
  return v.f;
}
static __device__ __forceinline__ unsigned short f2b(float f) {
  return (unsigned short)(__float_as_uint(f) >> 16);  // exact for small ints
}

// ---------------- CSR build from edge list ----------------
__global__ void k_hist(const int* __restrict__ ei, int E, int* __restrict__ cnt) {
  int e = blockIdx.x * 256 + threadIdx.x;
  if (e >= E) return;
  atomicAdd(&cnt[ei[E + e]], 1);
}

__global__ __launch_bounds__(1024) void k_scan(const int* __restrict__ cnt,
                                               int* __restrict__ rowptr, int n) {
  __shared__ int sums[1024];
  int tid = threadIdx.x;
  int base = tid * 4;
  int v0 = 0, v1 = 0, v2 = 0, v3 = 0;
  if (base < n) { v0 = cnt[base]; v1 = cnt[base + 1]; v2 = cnt[base + 2]; v3 = cnt[base + 3]; }
  int s = v0 + v1 + v2 + v3;
  sums[tid] = s;
  __syncthreads();
  for (int off = 1; off < 1024; off <<= 1) {
    int t = (tid >= off) ? sums[tid - off] : 0;
    __syncthreads();
    sums[tid] += t;
    __syncthreads();
  }
  int excl = sums[tid] - s;
  if (base < n) {
    rowptr[base] = excl;
    rowptr[base + 1] = excl + v0;
    rowptr[base + 2] = excl + v0 + v1;
    rowptr[base + 3] = excl + v0 + v1 + v2;
  }
  if (tid == 1023) rowptr[n] = sums[1023];
}

__global__ void k_fill(const int* __restrict__ ei, int E, const int* __restrict__ rowptr,
                       int* __restrict__ cursor, int* __restrict__ colidx) {
  int e = blockIdx.x * 256 + threadIdx.x;
  if (e >= E) return;
  int r = ei[E + e], c = ei[e];
  int p = atomicAdd(&cursor[r], 1);
  colidx[rowptr[r] + p] = c;
}

__global__ void k_dvcnt(const int* __restrict__ cnt, float* __restrict__ dv, int n) {
  int i = blockIdx.x * 256 + threadIdx.x;
  if (i < n) dv[i] = rsqrtf((float)cnt[i] + 2.0f);
}

// fp32 -> bf16 (exact for small ints)
__global__ void k_cvt_b16(const float* __restrict__ A, unsigned short* __restrict__ Ab, int total) {
  int i = blockIdx.x * 256 + threadIdx.x;
  if (i * 4 >= total) return;
  float4 v = *(const float4*)&A[i * 4];
  unsigned long long w = ((unsigned long long)(__float_as_uint(v.x) >> 16))
                       | ((unsigned long long)(__float_as_uint(v.y) >> 16) << 16)
                       | ((unsigned long long)(__float_as_uint(v.z) >> 16) << 32)
                       | ((unsigned long long)(__float_as_uint(v.w) >> 16) << 48);
  *(unsigned long long*)&Ab[i * 4] = w;
}

// d[i] = rsqrt(rowsum(A)+2) for dense fp32 A
__global__ void k_deg(const float* __restrict__ A, int n, float* __restrict__ dv) {
  int row = blockIdx.x * (blockDim.x >> 6) + (threadIdx.x >> 6);
  int lane = threadIdx.x & 63;
  if (row >= n) return;
  float s = 0.f;
  const float* arow = A + (size_t)row * n;
  for (int j = lane; j < n; j += 64) s += arow[j];
#pragma unroll
  for (int o = 32; o > 0; o >>= 1) s += __shfl_down(s, o);
  if (lane == 0) dv[row] = rsqrtf(s + 2.0f);
}

__global__ void k_deg_b16(const unsigned short* __restrict__ Ab, int n, float* __restrict__ dv) {
  int row = blockIdx.x * 4 + (threadIdx.x >> 6);
  int lane = threadIdx.x & 63;
  const unsigned short* ar = Ab + (size_t)row * n;
  float s = 0.f;
  for (int j = lane * 4; j < n; j += 256) {
    unsigned long long w = *(const unsigned long long*)&ar[j];
    s += b2f((unsigned short)w) + b2f((unsigned short)(w >> 16)) +
         b2f((unsigned short)(w >> 32)) + b2f((unsigned short)(w >> 48));
  }
#pragma unroll
  for (int o = 32; o > 0; o >>= 1) s += __shfl_down(s, o);
  if (lane == 0) dv[row] = rsqrtf(s + 2.0f);
}

// Y[r,c] = dv[r] * sum_k X[r,k] W[k,c]
__global__ void k_xw(const float* __restrict__ X, const float* __restrict__ W,
                     const float* __restrict__ dv, float* __restrict__ Y,
                     int n, int F) {
  int col = threadIdx.x;
  int row = blockIdx.x * blockDim.y + threadIdx.y;
  if (row >= n) return;
  float acc = 0.f;
  const float* xr = X + (size_t)row * F;
  for (int k = 0; k < F; ++k) acc += xr[k] * W[k * H + col];
  Y[(size_t)row * H + col] = dv[row] * acc;
}

// sparse GCN epilogue
__global__ void k_spmm_fin(const int* __restrict__ rowptr, const int* __restrict__ colidx,
                           const float* __restrict__ Y, const float* __restrict__ dv,
                           const float* __restrict__ bias, float* __restrict__ Out,
                           int n, int relu) {
  int row = blockIdx.x * 4 + (threadIdx.x >> 6);
  int lane = threadIdx.x & 63;
  if (row >= n) return;
  int s = rowptr[row], e = rowptr[row + 1];
  float a0 = 0.f, a1 = 0.f;
  int i = s;
  for (; i + 1 < e; i += 2) {
    int c0 = colidx[i], c1 = colidx[i + 1];
    a0 += Y[(size_t)c0 * H + lane] + Y[(size_t)c1 * H + lane];
    a1 += Y[(size_t)c0 * H + 64 + lane] + Y[(size_t)c1 * H + 64 + lane];
  }
  if (i < e) {
    int c = colidx[i];
    a0 += Y[(size_t)c * H + lane];
    a1 += Y[(size_t)c * H + 64 + lane];
  }
  float d = dv[row];
  float v0 = d * (a0 + 2.0f * Y[(size_t)row * H + lane]) + bias[lane];
  float v1 = d * (a1 + 2.0f * Y[(size_t)row * H + 64 + lane]) + bias[64 + lane];
  if (relu) { v0 = fmaxf(v0, 0.f); v1 = fmaxf(v1, 0.f); }
  Out[(size_t)row * H + lane] = v0;
  Out[(size_t)row * H + 64 + lane] = v1;
}

// sparse ATA (level 0)
__global__ __launch_bounds__(256) void k_ata_sparse(const int* __restrict__ rowptr,
                                                    const int* __restrict__ colidx,
                                                    const int* __restrict__ inv,
                                                    float* __restrict__ C, int k) {
  __shared__ int lidx[MAXL];
  __shared__ int cnt;
  int kcol = blockIdx.x;
  int tid = threadIdx.x;
  if (tid == 0) cnt = 0;
  __syncthreads();
  int s = rowptr[kcol], e = rowptr[kcol + 1];
  for (int i = s + tid; i < e; i += 256) {
    int ii = inv[colidx[i]];
    if (ii >= 0) { int p = atomicAdd(&cnt, 1); if (p < MAXL) lidx[p] = ii; }
  }
  if (tid == 0) {
    int ii = inv[kcol];
    if (ii >= 0) { int p = atomicAdd(&cnt, 1); if (p < MAXL) lidx[p] = ii; }
  }
  __syncthreads();
  int c = min(cnt, MAXL);
  int tot = c * c;
  for (int t = tid; t < tot; t += 256) {
    int a = t / c, b = t - a * c;
    int ia = lidx[a], ib = lidx[b];
    if (ia != ib) atomicAdd(&C[(size_t)ia * k + ib], 1.0f);
  }
}

// gather permuted S-rows into bf16 P (with +I), exact
__global__ void k_gather(const unsigned short* __restrict__ Ab, const int* __restrict__ perm,
                         unsigned short* __restrict__ P, int n, int k) {
  int row = blockIdx.x;
  int p = perm[row];
  const unsigned short* src = Ab + (size_t)p * n;
  unsigned short* dst = P + (size_t)row * n;
  for (int c = threadIdx.x * 8; c < n; c += 256 * 8) {
    *(ushort8*)&dst[c] = *(const ushort8*)&src[c];
  }
  __syncthreads();
  if (threadIdx.x == 0) dst[p] = f2b(b2f(src[p]) + 1.0f);
}

// C = P @ P^T via bf16 MFMA (exact: small-integer entries). Diagonal zeroed.
__global__ __launch_bounds__(256) void k_ata_mfma(const unsigned short* __restrict__ P,
                                                  float* __restrict__ C, int n, int k) {
  __shared__ __align__(16) unsigned short As[64][64];
  __shared__ __align__(16) unsigned short Bs[64][64];
  int tid = threadIdx.x;
  int w = tid >> 6, ln = tid & 63;
  int l15 = ln & 15, l4 = ln >> 4;
  int br = blockIdx.y, bc = blockIdx.x;
  f32x4 acc[4] = {};
  for (int k0 = 0; k0 < n; k0 += 64) {
#pragma unroll
    for (int it = 0; it < 2; ++it) {
      int e = tid + it * 256;
      int row = e >> 3, ch = e & 7;
      int sch = (ch ^ (row & 7)) * 8;
      *(ushort8*)&As[row][sch] = *(const ushort8*)&P[(size_t)(br * 64 + row) * n + k0 + ch * 8];
      *(ushort8*)&Bs[row][sch] = *(const ushort8*)&P[(size_t)(bc * 64 + row) * n + k0 + ch * 8];
    }
    __syncthreads();
#pragma unroll
    for (int s = 0; s < 2; ++s) {
      int arow = w * 16 + l15;
      bf16x8 af = *(const bf16x8*)&As[arow][((s * 4 + l4) ^ (arow & 7)) * 8];
#pragma unroll
      for (int f = 0; f < 4; ++f) {
        int brow = f * 16 + l15;
        bf16x8 bfr = *(const bf16x8*)&Bs[brow][((s * 4 + l4) ^ (brow & 7)) * 8];
        acc[f] = __builtin_amdgcn_mfma_f32_16x16x32_bf16(af, bfr, acc[f], 0, 0, 0);
      }
    }
    __syncthreads();
  }
#pragma unroll
  for (int f = 0; f < 4; ++f) {
#pragma unroll
    for (int r = 0; r < 4; ++r) {
      int gi = br * 64 + w * 16 + l4 * 4 + r;
      int gj = bc * 64 + f * 16 + l15;
      C[(size_t)gi * k + gj] = (gi == gj) ? 0.0f : acc[f][r];
    }
  }
}

// dense fp32 ATA split-K (level 2 only)
__global__ __launch_bounds__(256) void k_ata_sk(const float* __restrict__ A,
                                                const int* __restrict__ perm,
                                                float* __restrict__ C, int n, int k, int CK) {
  int bc = blockIdx.x, br = blockIdx.y;
  if (br > bc) return;
  __shared__ float As[64][36];
  __shared__ float Bs[64][36];
  __shared__ int pr[64], pc[64];
  int tid = threadIdx.x;
  if (tid < 64) pr[tid] = perm[br * 64 + tid];
  else if (tid < 128) pc[tid - 64] = perm[bc * 64 + (tid - 64)];
  __syncthreads();
  int ty = tid >> 4;
  int tx = tid & 15;
  float acc[4][4] = {};
  int k0s = blockIdx.z * CK;
  for (int k0 = k0s; k0 < k0s + CK; k0 += 32) {
#pragma unroll
    for (int it = 0, e = tid; it < 8; ++it, e += 256) {
      int ii = e >> 5, kk = e & 31;
      int gk = k0 + kk;
      int p = pr[ii];
      As[ii][kk] = A[(size_t)p * n + gk] + ((p == gk) ? 1.0f : 0.0f);
      p = pc[ii];
      Bs[ii][kk] = A[(size_t)p * n + gk] + ((p == gk) ? 1.0f : 0.0f);
    }
    __syncthreads();
#pragma unroll
    for (int kk = 0; kk < 32; kk += 4) {
      float4 a4[4], b4[4];
#pragma unroll
      for (int i = 0; i < 4; ++i) a4[i] = *(const float4*)&As[ty + 16 * i][kk];
#pragma unroll
      for (int j = 0; j < 4; ++j) b4[j] = *(const float4*)&Bs[tx + 16 * j][kk];
#pragma unroll
      for (int i = 0; i < 4; ++i) {
        float av[4] = {a4[i].x, a4[i].y, a4[i].z, a4[i].w};
#pragma unroll
        for (int j = 0; j < 4; ++j) {
          float bv[4] = {b4[j].x, b4[j].y, b4[j].z, b4[j].w};
#pragma unroll
          for (int s = 0; s < 4; ++s) acc[i][j] = fmaf(av[s], bv[s], acc[i][j]);
        }
      }
    }
    __syncthreads();
  }
  bool diag = (br == bc);
#pragma unroll
  for (int i = 0; i < 4; ++i) {
    int gi = br * 64 + ty + 16 * i;
#pragma unroll
    for (int j = 0; j < 4; ++j) {
      int gj = bc * 64 + tx + 16 * j;
      if (gi == gj) continue;
      float v = acc[i][j];
      atomicAdd(&C[(size_t)gi * k + gj], v);
      if (!diag) atomicAdd(&C[(size_t)gj * k + gi], v);
    }
  }
}

// fp32 dense GCN partial (split-K, private partial buffer per chunk - no atomics)
__global__ __launch_bounds__(256) void k_gcn_part(const float* __restrict__ A,
                                                  const float* __restrict__ Y,
                                                  float* __restrict__ Part,
                                                  int n, int KC) {
  __shared__ float As[64][36];
  __shared__ float Ys[32][132];
  int tid = threadIdx.x;
  int r0 = (tid >> 5) << 3;
  int c0 = (tid & 31) << 2;
  size_t rowBase = (size_t)blockIdx.x * 64;
  int k0s = blockIdx.y * KC;
  float* out = Part + (size_t)blockIdx.y * n * H;
  float acc[8][4] = {};
  for (int k0 = k0s; k0 < k0s + KC; k0 += 32) {
#pragma unroll
    for (int it = 0, e = tid; it < 8; ++it, e += 256) {
      int ii = e >> 5, kk = e & 31;
      As[ii][kk] = A[(rowBase + ii) * (size_t)n + k0 + kk];
    }
#pragma unroll
    for (int it = 0, e = tid; it < 4; ++it, e += 256) {
      int kk = e >> 5, cc4 = e & 31;
      *(float4*)&Ys[kk][cc4 << 2] = *(const float4*)&Y[(size_t)(k0 + kk) * H + (cc4 << 2)];
    }
    __syncthreads();
#pragma unroll
    for (int kk = 0; kk < 32; kk += 4) {
      float4 a4[8], y4[4];
#pragma unroll
      for (int i = 0; i < 8; ++i) a4[i] = *(const float4*)&As[r0 + i][kk];
#pragma unroll
      for (int s = 0; s < 4; ++s) y4[s] = *(const float4*)&Ys[kk + s][c0];
#pragma unroll
      for (int i = 0; i < 8; ++i) {
        float av[4] = {a4[i].x, a4[i].y, a4[i].z, a4[i].w};
#pragma unroll
        for (int s = 0; s < 4; ++s) {
          float yv[4] = {y4[s].x, y4[s].y, y4[s].z, y4[s].w};
#pragma unroll
          for (int j = 0; j < 4; ++j) acc[i][j] = fmaf(av[s], yv[j], acc[i][j]);
        }
      }
    }
    __syncthreads();
  }
#pragma unroll
  for (int i = 0; i < 8; ++i) {
    size_t row = rowBase + r0 + i;
    *(float4*)&out[row * H + c0] = make_float4(acc[i][0], acc[i][1], acc[i][2], acc[i][3]);
  }
}

// same but A stored as bf16 (exact small ints) -> half the HBM traffic
__global__ __launch_bounds__(256) void k_gcn_part_b16(const unsigned short* __restrict__ A,
                                                      const float* __restrict__ Y,
                                                      float* __restrict__ Part,
                                                      int n, int KC) {
  __shared__ float As[64][36];
  __shared__ float Ys[32][132];
  int tid = threadIdx.x;
  int r0 = (tid >> 5) << 3;
  int c0 = (tid & 31) << 2;
  size_t rowBase = (size_t)blockIdx.x * 64;
  int k0s = blockIdx.y * KC;
  float* out = Part + (size_t)blockIdx.y * n * H;
  float acc[8][4] = {};
  for (int k0 = k0s; k0 < k0s + KC; k0 += 32) {
    {
      int row = tid >> 2, ch = (tid & 3) * 8;
      ushort8 v = *(const ushort8*)&A[(rowBase + row) * (size_t)n + k0 + ch];
#pragma unroll
      for (int q = 0; q < 8; ++q) As[row][ch + q] = b2f(v[q]);
    }
#pragma unroll
    for (int it = 0, e = tid; it < 4; ++it, e += 256) {
      int kk = e >> 5, cc4 = e & 31;
      *(float4*)&Ys[kk][cc4 << 2] = *(const float4*)&Y[(size_t)(k0 + kk) * H + (cc4 << 2)];
    }
    __syncthreads();
#pragma unroll
    for (int kk = 0; kk < 32; kk += 4) {
      float4 a4[8], y4[4];
#pragma unroll
      for (int i = 0; i < 8; ++i) a4[i] = *(const float4*)&As[r0 + i][kk];
#pragma unroll
      for (int s = 0; s < 4; ++s) y4[s] = *(const float4*)&Ys[kk + s][c0];
#pragma unroll
      for (int i = 0; i < 8; ++i) {
        float av[4] = {a4[i].x, a4[i].y, a4[i].z, a4[i].w};
#pragma unroll
        for (int s = 0; s < 4; ++s) {
          float yv[4] = {y4[s].x, y4[s].y, y4[s].z, y4[s].w};
#pragma unroll
          for (int j = 0; j < 4; ++j) acc[i][j] = fmaf(av[s], yv[j], acc[i][j]);
        }
      }
    }
    __syncthreads();
  }
#pragma unroll
  for (int i = 0; i < 8; ++i) {
    size_t row = rowBase + r0 + i;
    *(float4*)&out[row * H + c0] = make_float4(acc[i][0], acc[i][1], acc[i][2], acc[i][3]);
  }
}

// Out = act(dv .* (sum_c Part[c] + 2Y) + bias), float4 per thread
__global__ void k_gcn_fin(const float* __restrict__ Part, const float* __restrict__ Y,
                          const float* __restrict__ dv, const float* __restrict__ bias,
                          float* __restrict__ Out, int n, int nch, int relu) {
  int i4 = blockIdx.x * 256 + threadIdx.x;
  if (i4 * 4 >= n * H) return;
  int row = i4 >> 5, c4 = (i4 & 31) * 4;
  size_t stride = (size_t)n * H;
  float4 s = *(const float4*)&Part[i4 * 4];
  for (int c = 1; c < nch; ++c) {
    float4 p = *(const float4*)&Part[c * stride + i4 * 4];
    s.x += p.x; s.y += p.y; s.z += p.z; s.w += p.w;
  }
  float4 y = *(const float4*)&Y[i4 * 4];
  float d = dv[row];
  float4 v;
  v.x = d * (s.x + 2.0f * y.x) + bias[c4];
  v.y = d * (s.y + 2.0f * y.y) + bias[c4 + 1];
  v.z = d * (s.z + 2.0f * y.z) + bias[c4 + 2];
  v.w = d * (s.w + 2.0f * y.w) + bias[c4 + 3];
  if (relu) {
    v.x = fmaxf(v.x, 0.f); v.y = fmaxf(v.y, 0.f);
    v.z = fmaxf(v.z, 0.f); v.w = fmaxf(v.w, 0.f);
  }
  *(float4*)&Out[i4 * 4] = v;
}

// score = tanh((h@w)/||w||)
__global__ void k_score(const float* __restrict__ h, const float* __restrict__ w,
                        float* __restrict__ score, int n) {
  __shared__ float wn;
  int tid = threadIdx.x;
  if (tid < 64) {
    float s = w[tid] * w[tid] + w[tid + 64] * w[tid + 64];
#pragma unroll
    for (int o = 32; o > 0; o >>= 1) s += __shfl_down(s, o);
    if (tid == 0) wn = sqrtf(s);
  }
  __syncthreads();
  int row = blockIdx.x * 4 + (tid >> 6);
  int lane = tid & 63;
  if (row >= n) return;
  float s = h[(size_t)row * H + lane] * w[lane] + h[(size_t)row * H + lane + 64] * w[lane + 64];
#pragma unroll
  for (int o = 32; o > 0; o >>= 1) s += __shfl_down(s, o);
  if (lane == 0) score[row] = tanhf(s / wn);
}

// ---- hybrid bitonic top-k ----
static __device__ __forceinline__ void ce_(unsigned long long& x, unsigned long long& y, bool asc) {
  if ((x < y) != asc) { unsigned long long t = x; x = y; y = t; }
}
static __device__ __forceinline__ unsigned long long pick_(unsigned long long a,
                                                           unsigned long long b,
                                                           bool lower, bool asc) {
  unsigned long long lo = (a < b) ? a : b;
  unsigned long long hi = (a < b) ? b : a;
  return (lower == asc) ? lo : hi;
}

template <int LOGN>
__global__ __launch_bounds__(1024) void k_topk(const float* __restrict__ score,
                                               int* __restrict__ perm,
                                               int* __restrict__ inv) {
  const int n = 1 << LOGN;
  __shared__ unsigned long long lds[1 << LOGN];
  int t = threadIdx.x;
  int e0 = t * 4;
  unsigned long long key[4];
#pragma unroll
  for (int j = 0; j < 4; ++j) {
    unsigned u = __float_as_uint(score[e0 + j]);
    u = (u & 0x80000000u) ? ~u : (u | 0x80000000u);
    u = ~u;
    key[j] = (((unsigned long long)u) << 32) | (unsigned)(e0 + j);
  }
  ce_(key[0], key[1], true);
  ce_(key[2], key[3], false);
  for (int size = 4; size <= n; size <<= 1) {
    bool asc = ((e0 & size) == 0);
    for (int stride = size >> 1; stride >= 256; stride >>= 1) {
#pragma unroll
      for (int j = 0; j < 4; ++j) lds[e0 + j] = key[j];
      __syncthreads();
      bool lower = ((e0 & stride) == 0);
#pragma unroll
      for (int j = 0; j < 4; ++j)
        key[j] = pick_(key[j], lds[(e0 + j) ^ stride], lower, asc);
      __syncthreads();
    }
    int s0 = ((size >> 1) < 256) ? (size >> 1) : 128;
    for (int stride = s0; stride >= 4; stride >>= 1) {
      int m = stride >> 2;
      bool lower = ((t & m) == 0);
#pragma unroll
      for (int j = 0; j < 4; ++j) {
        unsigned long long o = __shfl_xor(key[j], m, 64);
        key[j] = pick_(key[j], o, lower, asc);
      }
    }
    ce_(key[0], key[2], asc);
    ce_(key[1], key[3], asc);
    ce_(key[0], key[1], asc);
    ce_(key[2], key[3], asc);
  }
  int kk = n >> 1;
#pragma unroll
  for (int j = 0; j < 4; ++j) {
    int e = e0 + j;
    int idx = (int)(key[j] & 0xffffffffu);
    if (e < kk) perm[e] = idx;
    if (inv) inv[idx] = (e < kk) ? e : -1;
  }
}

__global__ void k_pool(const float* __restrict__ h, const float* __restrict__ score,
                       const int* __restrict__ perm, float* __restrict__ hp, int k) {
  int idx = blockIdx.x * 256 + threadIdx.x;
  if (idx >= k * H) return;
  int r = idx >> 7, c = idx & 127;
  int p = perm[r];
  hp[idx] = h[(size_t)p * H + c] * score[p];
}

// skip connection: out[r,:] = res[r,:] + (inv[r]>=0 ? prev[inv[r],:] : 0)
__global__ void k_skip(const float* __restrict__ res, const float* __restrict__ prev,
                       const int* __restrict__ inv, float* __restrict__ out, int n) {
  int i4 = blockIdx.x * 256 + threadIdx.x;
  if (i4 * 4 >= n * H) return;
  int row = i4 >> 5, c4 = (i4 & 31) * 4;
  float4 v = *(const float4*)&res[i4 * 4];
  int iv = inv[row];
  if (iv >= 0) {
    float4 pv = *(const float4*)&prev[(size_t)iv * H + c4];
    v.x += pv.x; v.y += pv.y; v.z += pv.z; v.w += pv.w;
  }
  *(float4*)&out[i4 * 4] = v;
}

__global__ void k_segsum(const float* __restrict__ h, const int* __restrict__ batch,
                         float* __restrict__ g, int n) {
  int c = threadIdx.x;
  int r0 = blockIdx.x * 32;
  int rend = min(r0 + 32, n);
  float acc = 0.f;
  int cur = batch[r0];
  for (int r = r0; r < rend; ++r) {
    int b = batch[r];
    if (b != cur) { atomicAdd(&g[cur * H + c], acc); acc = 0.f; cur = b; }
    acc += h[(size_t)r * H + c];
  }
  atomicAdd(&g[cur * H + c], acc);
}

__global__ __launch_bounds__(256) void k_head(const float* __restrict__ g,
    const float* __restrict__ lins_w, const float* __restrict__ lins_b,
    const float* __restrict__ bn_g, const float* __restrict__ bn_b,
    const float* __restrict__ out_w, const float* __restrict__ out_b,
    float* __restrict__ out) {
  __shared__ float a[NG * H], b[NG * H];
  int tid = threadIdx.x;
  const float inv = 1.0f / sqrtf(1.0f + 1e-5f);
  for (int i = tid; i < NG * H; i += 256) a[i] = g[i];
  __syncthreads();
  for (int L = 0; L < 3; ++L) {
    for (int i = tid; i < NG * H; i += 256) {
      int c = i & 127;
      b[i] = a[i] * (bn_g[L * H + c] * inv) + bn_b[L * H + c];
    }
    __syncthreads();
    for (int i = tid; i < NG * H; i += 256) {
      int r = i >> 7, c = i & 127;
      float s = lins_b[L * H + c];
      for (int k2 = 0; k2 < H; ++k2) s += b[r * H + k2] * lins_w[(size_t)L * H * H + k2 * H + c];
      a[i] = tanhf(s);
    }
    __syncthreads();
  }
  for (int i = tid; i < NG * H; i += 256) {
    int c = i & 127;
    b[i] = a[i] * (bn_g[3 * H + c] * inv) + bn_b[3 * H + c];
  }
  __syncthreads();
  for (int i = tid; i < NG * 32; i += 256) {
    int r = i >> 5, o = i & 31;
    float s = out_b[o];
    for (int k2 = 0; k2 < H; ++k2) s += b[r * H + k2] * out_w[k2 * 32 + o];
    out[i] = s;
  }
}

extern "C" void kernel_launch(void* const* d_in, const int* in_sizes, int n_in,
                              void* d_out, int out_size, void* d_ws, size_t ws_size,
                              hipStream_t stream) {
  const float* x       = (const float*)d_in[0];
  const int*   ei      = (const int*)d_in[1];
  const int*   batch   = (const int*)d_in[2];
  const float* conv0_w = (const float*)d_in[3];
  const float* conv0_b = (const float*)d_in[4];
  const float* down_w  = (const float*)d_in[5];
  const float* down_b  = (const float*)d_in[6];
  const float* pool_w  = (const float*)d_in[7];
  const float* up_w    = (const float*)d_in[8];
  const float* up_b    = (const float*)d_in[9];
  const float* lins_w  = (const float*)d_in[10];
  const float* lins_b  = (const float*)d_in[11];
  const float* bn_g    = (const float*)d_in[12];
  const float* bn_b    = (const float*)d_in[13];
  const float* out_w   = (const float*)d_in[14];
  const float* out_b   = (const float*)d_in[15];
  int E = in_sizes[1] / 2;

  char* p = (char*)d_ws;
  auto alloc = [&](size_t bytes) {
    char* r = p;
    p += (bytes + 255) & ~(size_t)255;
    return r;
  };
  float*          A1   = (float*)alloc((size_t)2048 * 2048 * 4);
  unsigned short* A1b  = (unsigned short*)alloc((size_t)2048 * 2048 * 2);
  unsigned short* P    = (unsigned short*)alloc((size_t)1024 * 2048 * 2);
  float*          A2m  = (float*)alloc((size_t)1024 * 1024 * 4);
  float*          A3   = (float*)alloc((size_t)512 * 512 * 4);
  float*          part = (float*)alloc((size_t)8 * 2048 * H * 4);
  int* cnt    = (int*)alloc(4096 * 4);
  int* cursor = (int*)alloc(4096 * 4);
  int* rowptr = (int*)alloc(4100 * 4);
  int* colidx = (int*)alloc((size_t)E * 4);
  int* inv0   = (int*)alloc(4096 * 4);
  int* inv1   = (int*)alloc(2048 * 4);
  int* inv2   = (int*)alloc(1024 * 4);
  float* dv0  = (float*)alloc(4096 * 4);
  float* dv1  = (float*)alloc(2048 * 4);
  float* dv2  = (float*)alloc(1024 * 4);
  float* dv3  = (float*)alloc(512 * 4);
  int* perm0  = (int*)alloc(2048 * 4);
  int* perm1  = (int*)alloc(1024 * 4);
  int* perm2  = (int*)alloc(512 * 4);
  float* score = (float*)alloc(4096 * 4);
  float* h0 = (float*)alloc((size_t)4096 * H * 4);
  float* h1 = (float*)alloc((size_t)2048 * H * 4);
  float* h2 = (float*)alloc((size_t)1024 * H * 4);
  float* h3 = (float*)alloc((size_t)512 * H * 4);
  float* t  = (float*)alloc((size_t)4096 * H * 4);
  float* t2 = (float*)alloc((size_t)4096 * H * 4);
  float* hu = (float*)alloc((size_t)4096 * H * 4);
  float* g  = (float*)alloc(NG * H * 4);

  // dense gcn: Out = act(dv .* (A@Y + 2Y) + bias); split-K into private partials
  auto gcn = [&](const float* A, const unsigned short* Ab, const float* Y, const float* dvv,
                 const float* bias, float* Out, int nn, int relu) {
    const int nch = 8;
    int KC = nn / nch;
    if (Ab)
      k_gcn_part_b16<<<dim3(nn / 64, nch), 256, 0, stream>>>(Ab, Y, part, nn, KC);
    else
      k_gcn_part<<<dim3(nn / 64, nch), 256, 0, stream>>>(A, Y, part, nn, KC);
    k_gcn_fin<<<nn / 8, 256, 0, stream>>>(part, Y, dvv, bias, Out, nn, nch, relu);
  };

  // ---- CSR build ----
  hipMemsetAsync(cnt, 0, 4096 * 4, stream);
  hipMemsetAsync(cursor, 0, 4096 * 4, stream);
  k_hist<<<(E + 255) / 256, 256, 0, stream>>>(ei, E, cnt);
  k_scan<<<1, 1024, 0, stream>>>(cnt, rowptr, 4096);
  k_fill<<<(E + 255) / 256, 256, 0, stream>>>(ei, E, rowptr, cursor, colidx);
  k_dvcnt<<<4096 / 256, 256, 0, stream>>>(cnt, dv0, 4096);

  // ---- conv0 (sparse) ----
  k_xw<<<dim3(2048), dim3(128, 2), 0, stream>>>(x, conv0_w, dv0, t2, 4096, 64);
  k_spmm_fin<<<1024, 256, 0, stream>>>(rowptr, colidx, t2, dv0, conv0_b, h0, 4096, 1);

  // ---- level 0 pooling (4096 -> 2048): sparse ATA ----
  k_score<<<1024, 256, 0, stream>>>(h0, pool_w, score, 4096);
  k_topk<12><<<1, 1024, 0, stream>>>(score, perm0, inv0);
  k_pool<<<(2048 * H) / 256, 256, 0, stream>>>(h0, score, perm0, t, 2048);
  hipMemsetAsync(A1, 0, (size_t)2048 * 2048 * 4, stream);
  k_ata_sparse<<<4096, 256, 0, stream>>>(rowptr, colidx, inv0, A1, 2048);
  k_cvt_b16<<<(2048 * 2048 / 4 + 255) / 256, 256, 0, stream>>>(A1, A1b, 2048 * 2048);
  k_deg_b16<<<2048 / 4, 256, 0, stream>>>(A1b, 2048, dv1);
  k_xw<<<dim3(1024), dim3(128, 2), 0, stream>>>(t, down_w, dv1, t2, 2048, H);
  gcn(nullptr, A1b, t2, dv1, down_b, h1, 2048, 1);

  // ---- level 1 pooling (2048 -> 1024): bf16 MFMA ATA ----
  k_score<<<512, 256, 0, stream>>>(h1, pool_w + H, score, 2048);
  k_topk<11><<<1, 512, 0, stream>>>(score, perm1, inv1);
  k_pool<<<(1024 * H) / 256, 256, 0, stream>>>(h1, score, perm1, t, 1024);
  k_gather<<<1024, 256, 0, stream>>>(A1b, perm1, P, 2048, 1024);
  k_ata_mfma<<<dim3(16, 16), 256, 0, stream>>>(P, A2m, 2048, 1024);
  k_deg<<<1024 / 4, 256, 0, stream>>>(A2m, 1024, dv2);
  k_xw<<<dim3(512), dim3(128, 2), 0, stream>>>(t, down_w + (size_t)H * H, dv2, t2, 1024, H);
  gcn(A2m, nullptr, t2, dv2, down_b + H, h2, 1024, 1);

  // ---- level 2 pooling (1024 -> 512): fp32 split-K ATA ----
  k_score<<<256, 256, 0, stream>>>(h2, pool_w + 2 * H, score, 1024);
  k_topk<10><<<1, 256, 0, stream>>>(score, perm2, inv2);
  k_pool<<<(512 * H) / 256, 256, 0, stream>>>(h2, score, perm2, t, 512);
  hipMemsetAsync(A3, 0, (size_t)512 * 512 * 4, stream);
  k_ata_sk<<<dim3(8, 8, 8), 256, 0, stream>>>(A2m, perm2, A3, 1024, 512, 128);
  k_deg<<<512 / 4, 256, 0, stream>>>(A3, 512, dv3);
  k_xw<<<dim3(256), dim3(128, 2), 0, stream>>>(t, down_w + (size_t)2 * H * H, dv3, t2, 512, H);
  gcn(A3, nullptr, t2, dv3, down_b + 2 * H, h3, 512, 1);

  // ---- up path (skip fused: no memcpy/scatter) ----
  k_skip<<<1024 / 8, 256, 0, stream>>>(h2, h3, inv2, t, 1024);
  k_xw<<<dim3(512), dim3(128, 2), 0, stream>>>(t, up_w, dv2, t2, 1024, H);
  gcn(A2m, nullptr, t2, dv2, up_b, hu, 1024, 1);

  k_skip<<<2048 / 8, 256, 0, stream>>>(h1, hu, inv1, t, 2048);
  k_xw<<<dim3(1024), dim3(128, 2), 0, stream>>>(t, up_w + (size_t)H * H, dv1, t2, 2048, H);
  gcn(nullptr, A1b, t2, dv1, up_b + H, hu, 2048, 1);

  k_skip<<<4096 / 8, 256, 0, stream>>>(h0, hu, inv0, t, 4096);
  k_xw<<<dim3(2048), dim3(128, 2), 0, stream>>>(t, up_w + (size_t)2 * H * H, dv0, t2, 4096, H);
  k_spmm_fin<<<1024, 256, 0, stream>>>(rowptr, colidx, t2, dv0, up_b + 2 * H, hu, 4096, 0);

  // ---- pool + head ----
  hipMemsetAsync(g, 0, NG * H * 4, stream);
  k_segsum<<<4096 / 32, 128, 0, stream>>>(hu, batch, g, 4096);
  k_head<<<1, 256, 0, stream>>>(g, lins_w, lins_b, bn_g, bn_b, out_w, out_b, (float*)d_out);
}

// Round 6
// 654.293 us; speedup vs baseline: 6.4710x; 1.0941x over previous
//
#include <hip/hip_runtime.h>
#include <math.h>

#define H 128
#define NG 8

typedef __attribute__((ext_vector_type(8))) short bf16x8;
typedef __attribute__((ext_vector_type(8))) unsigned short ushort8;
typedef __attribute__((ext_vector_type(4))) float f32x4;

static __device__ __forceinline__ float b2f(unsigned short u) {
  union { unsigned int i; float f; } v;
  v.i = ((unsigned int)u) << 16;
  return v.f;
}
static __device__ __forceinline__ unsigned short f2b(float f) {
  return (unsigned short)(__float_as_uint(f) >> 16);  // exact for small ints
}

// ---------------- CSR build from edge list ----------------
__global__ void k_hist(const int* __restrict__ ei, int E, int* __restrict__ cnt) {
  int e = blockIdx.x * 256 + threadIdx.x;
  if (e >= E) return;
  atomicAdd(&cnt[ei[E + e]], 1);
}

__global__ __launch_bounds__(1024) void k_scan(const int* __restrict__ cnt,
                                               int* __restrict__ rowptr, int n) {
  __shared__ int sums[1024];
  int tid = threadIdx.x;
  int base = tid * 4;
  int v0 = 0, v1 = 0, v2 = 0, v3 = 0;
  if (base < n) { v0 = cnt[base]; v1 = cnt[base + 1]; v2 = cnt[base + 2]; v3 = cnt[base + 3]; }
  int s = v0 + v1 + v2 + v3;
  sums[tid] = s;
  __syncthreads();
  for (int off = 1; off < 1024; off <<= 1) {
    int t = (tid >= off) ? sums[tid - off] : 0;
    __syncthreads();
    sums[tid] += t;
    __syncthreads();
  }
  int excl = sums[tid] - s;
  if (base < n) {
    rowptr[base] = excl;
    rowptr[base + 1] = excl + v0;
    rowptr[base + 2] = excl + v0 + v1;
    rowptr[base + 3] = excl + v0 + v1 + v2;
  }
  if (tid == 1023) rowptr[n] = sums[1023];
}

__global__ void k_fill(const int* __restrict__ ei, int E, const int* __restrict__ rowptr,
                       int* __restrict__ cursor, int* __restrict__ colidx) {
  int e = blockIdx.x * 256 + threadIdx.x;
  if (e >= E) return;
  int r = ei[E + e], c = ei[e];
  int p = atomicAdd(&cursor[r], 1);
  colidx[rowptr[r] + p] = c;
}

__global__ void k_dvcnt(const int* __restrict__ cnt, float* __restrict__ dv, int n) {
  int i = blockIdx.x * 256 + threadIdx.x;
  if (i < n) dv[i] = rsqrtf((float)cnt[i] + 2.0f);
}

// d[i] = rsqrt(rowsum(A)+2) for dense fp32 A
__global__ void k_deg(const float* __restrict__ A, int n, float* __restrict__ dv) {
  int row = blockIdx.x * (blockDim.x >> 6) + (threadIdx.x >> 6);
  int lane = threadIdx.x & 63;
  if (row >= n) return;
  float s = 0.f;
  const float* arow = A + (size_t)row * n;
  for (int j = lane; j < n; j += 64) s += arow[j];
#pragma unroll
  for (int o = 32; o > 0; o >>= 1) s += __shfl_down(s, o);
  if (lane == 0) dv[row] = rsqrtf(s + 2.0f);
}

// Y[r,c] = dv[r] * sum_k X'[r,k] W[k,c]
// MODE 0: X' = X ; MODE 1 (pool): X'[r,k] = X[perm[r],k]*score[perm[r]]
// MODE 2 (skip): X'[r,k] = X[r,k] + (inv[r]>=0 ? prev[inv[r],k] : 0)
template <int MODE>
__global__ void k_xw(const float* __restrict__ X, const float* __restrict__ W,
                     const float* __restrict__ dv,
                     const int* __restrict__ idx, const float* __restrict__ aux,
                     float* __restrict__ Y, int n, int F) {
  int col = threadIdx.x;
  int row = blockIdx.x * blockDim.y + threadIdx.y;
  if (row >= n) return;
  float acc = 0.f;
  if (MODE == 0) {
    const float* xr = X + (size_t)row * F;
    for (int k = 0; k < F; ++k) acc += xr[k] * W[k * H + col];
  } else if (MODE == 1) {
    int p = idx[row];
    float sc = aux[p];
    const float* xr = X + (size_t)p * F;
    for (int k = 0; k < F; ++k) acc += (xr[k] * sc) * W[k * H + col];
  } else {
    int iv = idx[row];
    const float* xr = X + (size_t)row * F;
    if (iv >= 0) {
      const float* pr = aux + (size_t)iv * H;
      for (int k = 0; k < F; ++k) acc += (xr[k] + pr[k]) * W[k * H + col];
    } else {
      for (int k = 0; k < F; ++k) acc += xr[k] * W[k * H + col];
    }
  }
  Y[(size_t)row * H + col] = dv[row] * acc;
}

// sparse GCN epilogue
__global__ void k_spmm_fin(const int* __restrict__ rowptr, const int* __restrict__ colidx,
                           const float* __restrict__ Y, const float* __restrict__ dv,
                           const float* __restrict__ bias, float* __restrict__ Out,
                           int n, int relu) {
  int row = blockIdx.x * 4 + (threadIdx.x >> 6);
  int lane = threadIdx.x & 63;
  if (row >= n) return;
  int s = rowptr[row], e = rowptr[row + 1];
  float a0 = 0.f, a1 = 0.f;
  int i = s;
  for (; i + 1 < e; i += 2) {
    int c0 = colidx[i], c1 = colidx[i + 1];
    a0 += Y[(size_t)c0 * H + lane] + Y[(size_t)c1 * H + lane];
    a1 += Y[(size_t)c0 * H + 64 + lane] + Y[(size_t)c1 * H + 64 + lane];
  }
  if (i < e) {
    int c = colidx[i];
    a0 += Y[(size_t)c * H + lane];
    a1 += Y[(size_t)c * H + 64 + lane];
  }
  float d = dv[row];
  float v0 = d * (a0 + 2.0f * Y[(size_t)row * H + lane]) + bias[lane];
  float v1 = d * (a1 + 2.0f * Y[(size_t)row * H + 64 + lane]) + bias[64 + lane];
  if (relu) { v0 = fmaxf(v0, 0.f); v1 = fmaxf(v1, 0.f); }
  Out[(size_t)row * H + lane] = v0;
  Out[(size_t)row * H + 64 + lane] = v1;
}

// level-0 ATA, row-wise: one block per pooled row i.
// acc[inv[j]] = sum_k S[p,k]*S[k,j] via CSR walk (S = A + I, dup entries = multiplicity).
// Writes bf16 row (diag zeroed) + dv1 (rowsum) directly.
__global__ __launch_bounds__(256) void k_ata_rows(const int* __restrict__ rowptr,
                                                  const int* __restrict__ colidx,
                                                  const int* __restrict__ perm,
                                                  const int* __restrict__ inv,
                                                  unsigned short* __restrict__ Ab,
                                                  float* __restrict__ dv, int kdim) {
  __shared__ int acc[2048];
  __shared__ int wsum[4];
  int i = blockIdx.x;
  int tid = threadIdx.x;
  for (int j = tid; j < kdim; j += 256) acc[j] = 0;
  __syncthreads();
  int p = perm[i];
  int s = rowptr[p], e = rowptr[p + 1];
  int deg = e - s;                       // k-nodes: colidx[s..e) plus p itself
  int wave = tid >> 6, lane = tid & 63;
  for (int q = wave; q <= deg; q += 4) {
    int kn = (q < deg) ? colidx[s + q] : p;
    int s2 = rowptr[kn], e2 = rowptr[kn + 1];
    for (int idx = s2 + lane; idx <= e2; idx += 64) {  // idx==e2 slot = self entry
      int j = (idx < e2) ? colidx[idx] : kn;
      int ii = inv[j];
      if (ii >= 0) atomicAdd(&acc[ii], 1);
    }
  }
  __syncthreads();
  int rs = 0;
  {
    int j0 = tid * 8;
    ushort8 v;
#pragma unroll
    for (int q = 0; q < 8; ++q) {
      int j = j0 + q;
      int c = (j == i) ? 0 : acc[j];
      rs += c;
      v[q] = f2b((float)c);
    }
    *(ushort8*)&Ab[(size_t)i * kdim + j0] = v;
  }
#pragma unroll
  for (int o = 32; o > 0; o >>= 1) rs += __shfl_down(rs, o);
  if (lane == 0) wsum[wave] = rs;
  __syncthreads();
  if (tid == 0) dv[i] = rsqrtf((float)(wsum[0] + wsum[1] + wsum[2] + wsum[3]) + 2.0f);
}

// gather permuted S-rows into bf16 P (with +I), exact
__global__ void k_gather(const unsigned short* __restrict__ Ab, const int* __restrict__ perm,
                         unsigned short* __restrict__ P, int n, int k) {
  int row = blockIdx.x;
  int p = perm[row];
  const unsigned short* src = Ab + (size_t)p * n;
  unsigned short* dst = P + (size_t)row * n;
  for (int c = threadIdx.x * 8; c < n; c += 256 * 8) {
    *(ushort8*)&dst[c] = *(const ushort8*)&src[c];
  }
  __syncthreads();
  if (threadIdx.x == 0) dst[p] = f2b(b2f(src[p]) + 1.0f);
}

// C = P @ P^T via bf16 MFMA (exact small ints). Diagonal zeroed.
__global__ __launch_bounds__(256) void k_ata_mfma(const unsigned short* __restrict__ P,
                                                  float* __restrict__ C, int n, int k) {
  __shared__ __align__(16) unsigned short As[64][64];
  __shared__ __align__(16) unsigned short Bs[64][64];
  int tid = threadIdx.x;
  int w = tid >> 6, ln = tid & 63;
  int l15 = ln & 15, l4 = ln >> 4;
  int br = blockIdx.y, bc = blockIdx.x;
  f32x4 acc[4] = {};
  for (int k0 = 0; k0 < n; k0 += 64) {
#pragma unroll
    for (int it = 0; it < 2; ++it) {
      int e = tid + it * 256;
      int row = e >> 3, ch = e & 7;
      int sch = (ch ^ (row & 7)) * 8;
      *(ushort8*)&As[row][sch] = *(const ushort8*)&P[(size_t)(br * 64 + row) * n + k0 + ch * 8];
      *(ushort8*)&Bs[row][sch] = *(const ushort8*)&P[(size_t)(bc * 64 + row) * n + k0 + ch * 8];
    }
    __syncthreads();
#pragma unroll
    for (int s = 0; s < 2; ++s) {
      int arow = w * 16 + l15;
      bf16x8 af = *(const bf16x8*)&As[arow][((s * 4 + l4) ^ (arow & 7)) * 8];
#pragma unroll
      for (int f = 0; f < 4; ++f) {
        int brow = f * 16 + l15;
        bf16x8 bfr = *(const bf16x8*)&Bs[brow][((s * 4 + l4) ^ (brow & 7)) * 8];
        acc[f] = __builtin_amdgcn_mfma_f32_16x16x32_bf16(af, bfr, acc[f], 0, 0, 0);
      }
    }
    __syncthreads();
  }
#pragma unroll
  for (int f = 0; f < 4; ++f) {
#pragma unroll
    for (int r = 0; r < 4; ++r) {
      int gi = br * 64 + w * 16 + l4 * 4 + r;
      int gj = bc * 64 + f * 16 + l15;
      C[(size_t)gi * k + gj] = (gi == gj) ? 0.0f : acc[f][r];
    }
  }
}

// dense fp32 ATA split-K (level 2 only)
__global__ __launch_bounds__(256) void k_ata_sk(const float* __restrict__ A,
                                                const int* __restrict__ perm,
                                                float* __restrict__ C, int n, int k, int CK) {
  int bc = blockIdx.x, br = blockIdx.y;
  if (br > bc) return;
  __shared__ float As[64][36];
  __shared__ float Bs[64][36];
  __shared__ int pr[64], pc[64];
  int tid = threadIdx.x;
  if (tid < 64) pr[tid] = perm[br * 64 + tid];
  else if (tid < 128) pc[tid - 64] = perm[bc * 64 + (tid - 64)];
  __syncthreads();
  int ty = tid >> 4;
  int tx = tid & 15;
  float acc[4][4] = {};
  int k0s = blockIdx.z * CK;
  for (int k0 = k0s; k0 < k0s + CK; k0 += 32) {
#pragma unroll
    for (int it = 0, e = tid; it < 8; ++it, e += 256) {
      int ii = e >> 5, kk = e & 31;
      int gk = k0 + kk;
      int p = pr[ii];
      As[ii][kk] = A[(size_t)p * n + gk] + ((p == gk) ? 1.0f : 0.0f);
      p = pc[ii];
      Bs[ii][kk] = A[(size_t)p * n + gk] + ((p == gk) ? 1.0f : 0.0f);
    }
    __syncthreads();
#pragma unroll
    for (int kk = 0; kk < 32; kk += 4) {
      float4 a4[4], b4[4];
#pragma unroll
      for (int i = 0; i < 4; ++i) a4[i] = *(const float4*)&As[ty + 16 * i][kk];
#pragma unroll
      for (int j = 0; j < 4; ++j) b4[j] = *(const float4*)&Bs[tx + 16 * j][kk];
#pragma unroll
      for (int i = 0; i < 4; ++i) {
        float av[4] = {a4[i].x, a4[i].y, a4[i].z, a4[i].w};
#pragma unroll
        for (int j = 0; j < 4; ++j) {
          float bv[4] = {b4[j].x, b4[j].y, b4[j].z, b4[j].w};
#pragma unroll
          for (int s = 0; s < 4; ++s) acc[i][j] = fmaf(av[s], bv[s], acc[i][j]);
        }
      }
    }
    __syncthreads();
  }
  bool diag = (br == bc);
#pragma unroll
  for (int i = 0; i < 4; ++i) {
    int gi = br * 64 + ty + 16 * i;
#pragma unroll
    for (int j = 0; j < 4; ++j) {
      int gj = bc * 64 + tx + 16 * j;
      if (gi == gj) continue;
      float v = acc[i][j];
      atomicAdd(&C[(size_t)gi * k + gj], v);
      if (!diag) atomicAdd(&C[(size_t)gj * k + gi], v);
    }
  }
}

// fp32 dense GCN partial (split-K, private partials)
__global__ __launch_bounds__(256) void k_gcn_part(const float* __restrict__ A,
                                                  const float* __restrict__ Y,
                                                  float* __restrict__ Part,
                                                  int n, int KC) {
  __shared__ float As[64][36];
  __shared__ float Ys[32][132];
  int tid = threadIdx.x;
  int r0 = (tid >> 5) << 3;
  int c0 = (tid & 31) << 2;
  size_t rowBase = (size_t)blockIdx.x * 64;
  int k0s = blockIdx.y * KC;
  float* out = Part + (size_t)blockIdx.y * n * H;
  float acc[8][4] = {};
  for (int k0 = k0s; k0 < k0s + KC; k0 += 32) {
#pragma unroll
    for (int it = 0, e = tid; it < 8; ++it, e += 256) {
      int ii = e >> 5, kk = e & 31;
      As[ii][kk] = A[(rowBase + ii) * (size_t)n + k0 + kk];
    }
#pragma unroll
    for (int it = 0, e = tid; it < 4; ++it, e += 256) {
      int kk = e >> 5, cc4 = e & 31;
      *(float4*)&Ys[kk][cc4 << 2] = *(const float4*)&Y[(size_t)(k0 + kk) * H + (cc4 << 2)];
    }
    __syncthreads();
#pragma unroll
    for (int kk = 0; kk < 32; kk += 4) {
      float4 a4[8], y4[4];
#pragma unroll
      for (int i = 0; i < 8; ++i) a4[i] = *(const float4*)&As[r0 + i][kk];
#pragma unroll
      for (int s = 0; s < 4; ++s) y4[s] = *(const float4*)&Ys[kk + s][c0];
#pragma unroll
      for (int i = 0; i < 8; ++i) {
        float av[4] = {a4[i].x, a4[i].y, a4[i].z, a4[i].w};
#pragma unroll
        for (int s = 0; s < 4; ++s) {
          float yv[4] = {y4[s].x, y4[s].y, y4[s].z, y4[s].w};
#pragma unroll
          for (int j = 0; j < 4; ++j) acc[i][j] = fmaf(av[s], yv[j], acc[i][j]);
        }
      }
    }
    __syncthreads();
  }
#pragma unroll
  for (int i = 0; i < 8; ++i) {
    size_t row = rowBase + r0 + i;
    *(float4*)&out[row * H + c0] = make_float4(acc[i][0], acc[i][1], acc[i][2], acc[i][3]);
  }
}

// bf16-A variant
__global__ __launch_bounds__(256) void k_gcn_part_b16(const unsigned short* __restrict__ A,
                                                      const float* __restrict__ Y,
                                                      float* __restrict__ Part,
                                                      int n, int KC) {
  __shared__ float As[64][36];
  __shared__ float Ys[32][132];
  int tid = threadIdx.x;
  int r0 = (tid >> 5) << 3;
  int c0 = (tid & 31) << 2;
  size_t rowBase = (size_t)blockIdx.x * 64;
  int k0s = blockIdx.y * KC;
  float* out = Part + (size_t)blockIdx.y * n * H;
  float acc[8][4] = {};
  for (int k0 = k0s; k0 < k0s + KC; k0 += 32) {
    {
      int row = tid >> 2, ch = (tid & 3) * 8;
      ushort8 v = *(const ushort8*)&A[(rowBase + row) * (size_t)n + k0 + ch];
#pragma unroll
      for (int q = 0; q < 8; ++q) As[row][ch + q] = b2f(v[q]);
    }
#pragma unroll
    for (int it = 0, e = tid; it < 4; ++it, e += 256) {
      int kk = e >> 5, cc4 = e & 31;
      *(float4*)&Ys[kk][cc4 << 2] = *(const float4*)&Y[(size_t)(k0 + kk) * H + (cc4 << 2)];
    }
    __syncthreads();
#pragma unroll
    for (int kk = 0; kk < 32; kk += 4) {
      float4 a4[8], y4[4];
#pragma unroll
      for (int i = 0; i < 8; ++i) a4[i] = *(const float4*)&As[r0 + i][kk];
#pragma unroll
      for (int s = 0; s < 4; ++s) y4[s] = *(const float4*)&Ys[kk + s][c0];
#pragma unroll
      for (int i = 0; i < 8; ++i) {
        float av[4] = {a4[i].x, a4[i].y, a4[i].z, a4[i].w};
#pragma unroll
        for (int s = 0; s < 4; ++s) {
          float yv[4] = {y4[s].x, y4[s].y, y4[s].z, y4[s].w};
#pragma unroll
          for (int j = 0; j < 4; ++j) acc[i][j] = fmaf(av[s], yv[j], acc[i][j]);
        }
      }
    }
    __syncthreads();
  }
#pragma unroll
  for (int i = 0; i < 8; ++i) {
    size_t row = rowBase + r0 + i;
    *(float4*)&out[row * H + c0] = make_float4(acc[i][0], acc[i][1], acc[i][2], acc[i][3]);
  }
}

// Out = act(dv .* (sum_c Part[c] + 2Y) + bias)
__global__ void k_gcn_fin(const float* __restrict__ Part, const float* __restrict__ Y,
                          const float* __restrict__ dv, const float* __restrict__ bias,
                          float* __restrict__ Out, int n, int nch, int relu) {
  int i4 = blockIdx.x * 256 + threadIdx.x;
  if (i4 * 4 >= n * H) return;
  int row = i4 >> 5, c4 = (i4 & 31) * 4;
  size_t stride = (size_t)n * H;
  float4 s = *(const float4*)&Part[i4 * 4];
  for (int c = 1; c < nch; ++c) {
    float4 p = *(const float4*)&Part[c * stride + i4 * 4];
    s.x += p.x; s.y += p.y; s.z += p.z; s.w += p.w;
  }
  float4 y = *(const float4*)&Y[i4 * 4];
  float d = dv[row];
  float4 v;
  v.x = d * (s.x + 2.0f * y.x) + bias[c4];
  v.y = d * (s.y + 2.0f * y.y) + bias[c4 + 1];
  v.z = d * (s.z + 2.0f * y.z) + bias[c4 + 2];
  v.w = d * (s.w + 2.0f * y.w) + bias[c4 + 3];
  if (relu) {
    v.x = fmaxf(v.x, 0.f); v.y = fmaxf(v.y, 0.f);
    v.z = fmaxf(v.z, 0.f); v.w = fmaxf(v.w, 0.f);
  }
  *(float4*)&Out[i4 * 4] = v;
}

// score = tanh((h@w)/||w||)
__global__ void k_score(const float* __restrict__ h, const float* __restrict__ w,
                        float* __restrict__ score, int n) {
  __shared__ float wn;
  int tid = threadIdx.x;
  if (tid < 64) {
    float s = w[tid] * w[tid] + w[tid + 64] * w[tid + 64];
#pragma unroll
    for (int o = 32; o > 0; o >>= 1) s += __shfl_down(s, o);
    if (tid == 0) wn = sqrtf(s);
  }
  __syncthreads();
  int row = blockIdx.x * 4 + (tid >> 6);
  int lane = tid & 63;
  if (row >= n) return;
  float s = h[(size_t)row * H + lane] * w[lane] + h[(size_t)row * H + lane + 64] * w[lane + 64];
#pragma unroll
  for (int o = 32; o > 0; o >>= 1) s += __shfl_down(s, o);
  if (lane == 0) score[row] = tanhf(s / wn);
}

// ---- hybrid bitonic top-k ----
static __device__ __forceinline__ void ce_(unsigned long long& x, unsigned long long& y, bool asc) {
  if ((x < y) != asc) { unsigned long long t = x; x = y; y = t; }
}
static __device__ __forceinline__ unsigned long long pick_(unsigned long long a,
                                                           unsigned long long b,
                                                           bool lower, bool asc) {
  unsigned long long lo = (a < b) ? a : b;
  unsigned long long hi = (a < b) ? b : a;
  return (lower == asc) ? lo : hi;
}

template <int LOGN>
__global__ __launch_bounds__(1024) void k_topk(const float* __restrict__ score,
                                               int* __restrict__ perm,
                                               int* __restrict__ inv) {
  const int n = 1 << LOGN;
  __shared__ unsigned long long lds[1 << LOGN];
  int t = threadIdx.x;
  int e0 = t * 4;
  unsigned long long key[4];
#pragma unroll
  for (int j = 0; j < 4; ++j) {
    unsigned u = __float_as_uint(score[e0 + j]);
    u = (u & 0x80000000u) ? ~u : (u | 0x80000000u);
    u = ~u;
    key[j] = (((unsigned long long)u) << 32) | (unsigned)(e0 + j);
  }
  ce_(key[0], key[1], true);
  ce_(key[2], key[3], false);
  for (int size = 4; size <= n; size <<= 1) {
    bool asc = ((e0 & size) == 0);
    for (int stride = size >> 1; stride >= 256; stride >>= 1) {
#pragma unroll
      for (int j = 0; j < 4; ++j) lds[e0 + j] = key[j];
      __syncthreads();
      bool lower = ((e0 & stride) == 0);
#pragma unroll
      for (int j = 0; j < 4; ++j)
        key[j] = pick_(key[j], lds[(e0 + j) ^ stride], lower, asc);
      __syncthreads();
    }
    int s0 = ((size >> 1) < 256) ? (size >> 1) : 128;
    for (int stride = s0; stride >= 4; stride >>= 1) {
      int m = stride >> 2;
      bool lower = ((t & m) == 0);
#pragma unroll
      for (int j = 0; j < 4; ++j) {
        unsigned long long o = __shfl_xor(key[j], m, 64);
        key[j] = pick_(key[j], o, lower, asc);
      }
    }
    ce_(key[0], key[2], asc);
    ce_(key[1], key[3], asc);
    ce_(key[0], key[1], asc);
    ce_(key[2], key[3], asc);
  }
  int kk = n >> 1;
#pragma unroll
  for (int j = 0; j < 4; ++j) {
    int e = e0 + j;
    int idx = (int)(key[j] & 0xffffffffu);
    if (e < kk) perm[e] = idx;
    if (inv) inv[idx] = (e < kk) ? e : -1;
  }
}

__global__ void k_segsum(const float* __restrict__ h, const int* __restrict__ batch,
                         float* __restrict__ g, int n) {
  int c = threadIdx.x;
  int r0 = blockIdx.x * 32;
  int rend = min(r0 + 32, n);
  float acc = 0.f;
  int cur = batch[r0];
  for (int r = r0; r < rend; ++r) {
    int b = batch[r];
    if (b != cur) { atomicAdd(&g[cur * H + c], acc); acc = 0.f; cur = b; }
    acc += h[(size_t)r * H + c];
  }
  atomicAdd(&g[cur * H + c], acc);
}

__global__ __launch_bounds__(256) void k_head(const float* __restrict__ g,
    const float* __restrict__ lins_w, const float* __restrict__ lins_b,
    const float* __restrict__ bn_g, const float* __restrict__ bn_b,
    const float* __restrict__ out_w, const float* __restrict__ out_b,
    float* __restrict__ out) {
  __shared__ float a[NG * H], b[NG * H];
  int tid = threadIdx.x;
  const float inv = 1.0f / sqrtf(1.0f + 1e-5f);
  for (int i = tid; i < NG * H; i += 256) a[i] = g[i];
  __syncthreads();
  for (int L = 0; L < 3; ++L) {
    for (int i = tid; i < NG * H; i += 256) {
      int c = i & 127;
      b[i] = a[i] * (bn_g[L * H + c] * inv) + bn_b[L * H + c];
    }
    __syncthreads();
    for (int i = tid; i < NG * H; i += 256) {
      int r = i >> 7, c = i & 127;
      float s = lins_b[L * H + c];
      for (int k2 = 0; k2 < H; ++k2) s += b[r * H + k2] * lins_w[(size_t)L * H * H + k2 * H + c];
      a[i] = tanhf(s);
    }
    __syncthreads();
  }
  for (int i = tid; i < NG * H; i += 256) {
    int c = i & 127;
    b[i] = a[i] * (bn_g[3 * H + c] * inv) + bn_b[3 * H + c];
  }
  __syncthreads();
  for (int i = tid; i < NG * 32; i += 256) {
    int r = i >> 5, o = i & 31;
    float s = out_b[o];
    for (int k2 = 0; k2 < H; ++k2) s += b[r * H + k2] * out_w[k2 * 32 + o];
    out[i] = s;
  }
}

extern "C" void kernel_launch(void* const* d_in, const int* in_sizes, int n_in,
                              void* d_out, int out_size, void* d_ws, size_t ws_size,
                              hipStream_t stream) {
  const float* x       = (const float*)d_in[0];
  const int*   ei      = (const int*)d_in[1];
  const int*   batch   = (const int*)d_in[2];
  const float* conv0_w = (const float*)d_in[3];
  const float* conv0_b = (const float*)d_in[4];
  const float* down_w  = (const float*)d_in[5];
  const float* down_b  = (const float*)d_in[6];
  const float* pool_w  = (const float*)d_in[7];
  const float* up_w    = (const float*)d_in[8];
  const float* up_b    = (const float*)d_in[9];
  const float* lins_w  = (const float*)d_in[10];
  const float* lins_b  = (const float*)d_in[11];
  const float* bn_g    = (const float*)d_in[12];
  const float* bn_b    = (const float*)d_in[13];
  const float* out_w   = (const float*)d_in[14];
  const float* out_b   = (const float*)d_in[15];
  int E = in_sizes[1] / 2;

  char* p = (char*)d_ws;
  auto alloc = [&](size_t bytes) {
    char* r = p;
    p += (bytes + 255) & ~(size_t)255;
    return r;
  };
  unsigned short* A1b  = (unsigned short*)alloc((size_t)2048 * 2048 * 2);
  unsigned short* P    = (unsigned short*)alloc((size_t)1024 * 2048 * 2);
  float*          A2m  = (float*)alloc((size_t)1024 * 1024 * 4);
  float*          A3   = (float*)alloc((size_t)512 * 512 * 4);
  float*          part = (float*)alloc((size_t)8 * 2048 * H * 4);
  int* cnt    = (int*)alloc(4096 * 4);
  int* cursor = (int*)alloc(4096 * 4);
  int* rowptr = (int*)alloc(4100 * 4);
  int* colidx = (int*)alloc((size_t)E * 4);
  int* inv0   = (int*)alloc(4096 * 4);
  int* inv1   = (int*)alloc(2048 * 4);
  int* inv2   = (int*)alloc(1024 * 4);
  float* dv0  = (float*)alloc(4096 * 4);
  float* dv1  = (float*)alloc(2048 * 4);
  float* dv2  = (float*)alloc(1024 * 4);
  float* dv3  = (float*)alloc(512 * 4);
  int* perm0  = (int*)alloc(2048 * 4);
  int* perm1  = (int*)alloc(1024 * 4);
  int* perm2  = (int*)alloc(512 * 4);
  float* score = (float*)alloc(4096 * 4);
  float* h0 = (float*)alloc((size_t)4096 * H * 4);
  float* h1 = (float*)alloc((size_t)2048 * H * 4);
  float* h2 = (float*)alloc((size_t)1024 * H * 4);
  float* h3 = (float*)alloc((size_t)512 * H * 4);
  float* t2 = (float*)alloc((size_t)4096 * H * 4);
  float* hu = (float*)alloc((size_t)4096 * H * 4);
  float* g  = (float*)alloc(NG * H * 4);

  auto gcn = [&](const float* A, const unsigned short* Ab, const float* Y, const float* dvv,
                 const float* bias, float* Out, int nn, int relu) {
    const int nch = 8;
    int KC = nn / nch;
    if (Ab)
      k_gcn_part_b16<<<dim3(nn / 64, nch), 256, 0, stream>>>(Ab, Y, part, nn, KC);
    else
      k_gcn_part<<<dim3(nn / 64, nch), 256, 0, stream>>>(A, Y, part, nn, KC);
    k_gcn_fin<<<nn / 8, 256, 0, stream>>>(part, Y, dvv, bias, Out, nn, nch, relu);
  };

  // ---- CSR build ----
  hipMemsetAsync(cnt, 0, 4096 * 4, stream);
  hipMemsetAsync(cursor, 0, 4096 * 4, stream);
  k_hist<<<(E + 255) / 256, 256, 0, stream>>>(ei, E, cnt);
  k_scan<<<1, 1024, 0, stream>>>(cnt, rowptr, 4096);
  k_fill<<<(E + 255) / 256, 256, 0, stream>>>(ei, E, rowptr, cursor, colidx);
  k_dvcnt<<<4096 / 256, 256, 0, stream>>>(cnt, dv0, 4096);

  // ---- conv0 (sparse) ----
  k_xw<0><<<dim3(2048), dim3(128, 2), 0, stream>>>(x, conv0_w, dv0, nullptr, nullptr, t2, 4096, 64);
  k_spmm_fin<<<1024, 256, 0, stream>>>(rowptr, colidx, t2, dv0, conv0_b, h0, 4096, 1);

  // ---- level 0 pooling (4096 -> 2048): row-wise sparse ATA -> bf16 + dv1 ----
  k_score<<<1024, 256, 0, stream>>>(h0, pool_w, score, 4096);
  k_topk<12><<<1, 1024, 0, stream>>>(score, perm0, inv0);
  k_ata_rows<<<2048, 256, 0, stream>>>(rowptr, colidx, perm0, inv0, A1b, dv1, 2048);
  k_xw<1><<<dim3(1024), dim3(128, 2), 0, stream>>>(h0, down_w, dv1, perm0, score, t2, 2048, 128);
  gcn(nullptr, A1b, t2, dv1, down_b, h1, 2048, 1);

  // ---- level 1 pooling (2048 -> 1024): bf16 MFMA ATA ----
  k_score<<<512, 256, 0, stream>>>(h1, pool_w + H, score, 2048);
  k_topk<11><<<1, 512, 0, stream>>>(score, perm1, inv1);
  k_gather<<<1024, 256, 0, stream>>>(A1b, perm1, P, 2048, 1024);
  k_ata_mfma<<<dim3(16, 16), 256, 0, stream>>>(P, A2m, 2048, 1024);
  k_deg<<<1024 / 4, 256, 0, stream>>>(A2m, 1024, dv2);
  k_xw<1><<<dim3(512), dim3(128, 2), 0, stream>>>(h1, down_w + (size_t)H * H, dv2, perm1, score, t2, 1024, 128);
  gcn(A2m, nullptr, t2, dv2, down_b + H, h2, 1024, 1);

  // ---- level 2 pooling (1024 -> 512): fp32 split-K ATA ----
  k_score<<<256, 256, 0, stream>>>(h2, pool_w + 2 * H, score, 1024);
  k_topk<10><<<1, 256, 0, stream>>>(score, perm2, inv2);
  hipMemsetAsync(A3, 0, (size_t)512 * 512 * 4, stream);
  k_ata_sk<<<dim3(8, 8, 8), 256, 0, stream>>>(A2m, perm2, A3, 1024, 512, 128);
  k_deg<<<512 / 4, 256, 0, stream>>>(A3, 512, dv3);
  k_xw<1><<<dim3(256), dim3(128, 2), 0, stream>>>(h2, down_w + (size_t)2 * H * H, dv3, perm2, score, t2, 512, 128);
  gcn(A3, nullptr, t2, dv3, down_b + 2 * H, h3, 512, 1);

  // ---- up path (skip fused into xw) ----
  k_xw<2><<<dim3(512), dim3(128, 2), 0, stream>>>(h2, up_w, dv2, inv2, h3, t2, 1024, 128);
  gcn(A2m, nullptr, t2, dv2, up_b, hu, 1024, 1);

  k_xw<2><<<dim3(1024), dim3(128, 2), 0, stream>>>(h1, up_w + (size_t)H * H, dv1, inv1, hu, t2, 2048, 128);
  gcn(nullptr, A1b, t2, dv1, up_b + H, hu, 2048, 1);

  k_xw<2><<<dim3(2048), dim3(128, 2), 0, stream>>>(h0, up_w + (size_t)2 * H * H, dv0, inv0, hu, t2, 4096, 128);
  k_spmm_fin<<<1024, 256, 0, stream>>>(rowptr, colidx, t2, dv0, up_b + 2 * H, hu, 4096, 0);

  // ---- pool + head ----
  hipMemsetAsync(g, 0, NG * H * 4, stream);
  k_segsum<<<4096 / 32, 128, 0, stream>>>(hu, batch, g, 4096);
  k_head<<<1, 256, 0, stream>>>(g, lins_w, lins_b, bn_g, bn_b, out_w, out_b, (float*)d_out);
}

// Round 7
// 537.197 us; speedup vs baseline: 7.8815x; 1.2180x over previous
//
#include <hip/hip_runtime.h>
#include <math.h>

#define H 128
#define NG 8

typedef __attribute__((ext_vector_type(8))) short bf16x8;
typedef __attribute__((ext_vector_type(8))) unsigned short ushort8;
typedef __attribute__((ext_vector_type(4))) float f32x4;

static __device__ __forceinline__ float b2f(unsigned short u) {
  union { unsigned int i; float f; } v;
  v.i = ((unsigned int)u) << 16;
  return v.f;
}
static __device__ __forceinline__ unsigned short f2b(float f) {
  return (unsigned short)(__float_as_uint(f) >> 16);  // exact for small ints
}

// ---------------- CSR build from edge list ----------------
__global__ void k_hist(const int* __restrict__ ei, int E, int* __restrict__ cnt) {
  int e = blockIdx.x * 256 + threadIdx.x;
  if (e >= E) return;
  atomicAdd(&cnt[ei[E + e]], 1);
}

__global__ __launch_bounds__(1024) void k_scan(const int* __restrict__ cnt,
                                               int* __restrict__ rowptr, int n) {
  __shared__ int sums[1024];
  int tid = threadIdx.x;
  int base = tid * 4;
  int v0 = 0, v1 = 0, v2 = 0, v3 = 0;
  if (base < n) { v0 = cnt[base]; v1 = cnt[base + 1]; v2 = cnt[base + 2]; v3 = cnt[base + 3]; }
  int s = v0 + v1 + v2 + v3;
  sums[tid] = s;
  __syncthreads();
  for (int off = 1; off < 1024; off <<= 1) {
    int t = (tid >= off) ? sums[tid - off] : 0;
    __syncthreads();
    sums[tid] += t;
    __syncthreads();
  }
  int excl = sums[tid] - s;
  if (base < n) {
    rowptr[base] = excl;
    rowptr[base + 1] = excl + v0;
    rowptr[base + 2] = excl + v0 + v1;
    rowptr[base + 3] = excl + v0 + v1 + v2;
  }
  if (tid == 1023) rowptr[n] = sums[1023];
}

__global__ void k_fill(const int* __restrict__ ei, int E, const int* __restrict__ rowptr,
                       int* __restrict__ cursor, int* __restrict__ colidx) {
  int e = blockIdx.x * 256 + threadIdx.x;
  if (e >= E) return;
  int r = ei[E + e], c = ei[e];
  int p = atomicAdd(&cursor[r], 1);
  colidx[rowptr[r] + p] = c;
}

__global__ void k_dvcnt(const int* __restrict__ cnt, float* __restrict__ dv, int n) {
  int i = blockIdx.x * 256 + threadIdx.x;
  if (i < n) dv[i] = rsqrtf((float)cnt[i] + 2.0f);
}

// d[i] = rsqrt(rowsum(A)+2) for dense fp32 A
__global__ void k_deg(const float* __restrict__ A, int n, float* __restrict__ dv) {
  int row = blockIdx.x * (blockDim.x >> 6) + (threadIdx.x >> 6);
  int lane = threadIdx.x & 63;
  if (row >= n) return;
  float s = 0.f;
  const float* arow = A + (size_t)row * n;
  for (int j = lane; j < n; j += 64) s += arow[j];
#pragma unroll
  for (int o = 32; o > 0; o >>= 1) s += __shfl_down(s, o);
  if (lane == 0) dv[row] = rsqrtf(s + 2.0f);
}

// Y[r,c] = dv[r] * sum_k X'[r,k] W[k,c]  -- tiled GEMM, 64 rows x 128 cols / block
// MODE 0: X' = X ; MODE 1 (pool): X'[r,k] = X[perm[r],k]*score[perm[r]]
// MODE 2 (skip): X'[r,k] = X[r,k] + (inv[r]>=0 ? prev[inv[r],k] : 0)
template <int MODE>
__global__ __launch_bounds__(256) void k_xw(const float* __restrict__ X,
                                            const float* __restrict__ W,
                                            const float* __restrict__ dv,
                                            const int* __restrict__ idx,
                                            const float* __restrict__ aux,
                                            float* __restrict__ Y, int n, int F) {
  __shared__ float Xs[64][36];
  __shared__ float Ws[32][132];
  __shared__ int ridx[64];
  __shared__ float rscl[64];
  int tid = threadIdx.x;
  int rowBase = blockIdx.x * 64;
  if (MODE == 1) {
    if (tid < 64) {
      int pp = idx[rowBase + tid];
      ridx[tid] = pp;
      rscl[tid] = aux[pp];
    }
  } else if (MODE == 2) {
    if (tid < 64) ridx[tid] = idx[rowBase + tid];
  }
  if (MODE != 0) __syncthreads();
  int r0 = (tid >> 5) << 3;
  int c0 = (tid & 31) << 2;
  float acc[8][4] = {};
  for (int k0 = 0; k0 < F; k0 += 32) {
#pragma unroll
    for (int it = 0, e = tid; it < 8; ++it, e += 256) {
      int ii = e >> 5, kk = e & 31;
      int gk = k0 + kk;
      float v;
      if (MODE == 0) {
        v = X[(size_t)(rowBase + ii) * F + gk];
      } else if (MODE == 1) {
        v = X[(size_t)ridx[ii] * F + gk] * rscl[ii];
      } else {
        v = X[(size_t)(rowBase + ii) * F + gk];
        int iv = ridx[ii];
        if (iv >= 0) v += aux[(size_t)iv * H + gk];
      }
      Xs[ii][kk] = v;
    }
#pragma unroll
    for (int it = 0, e = tid; it < 4; ++it, e += 256) {
      int kk = e >> 5, cc4 = e & 31;
      *(float4*)&Ws[kk][cc4 << 2] = *(const float4*)&W[(size_t)(k0 + kk) * H + (cc4 << 2)];
    }
    __syncthreads();
#pragma unroll
    for (int kk = 0; kk < 32; kk += 4) {
      float4 a4[8], w4[4];
#pragma unroll
      for (int i = 0; i < 8; ++i) a4[i] = *(const float4*)&Xs[r0 + i][kk];
#pragma unroll
      for (int s = 0; s < 4; ++s) w4[s] = *(const float4*)&Ws[kk + s][c0];
#pragma unroll
      for (int i = 0; i < 8; ++i) {
        float av[4] = {a4[i].x, a4[i].y, a4[i].z, a4[i].w};
#pragma unroll
        for (int s = 0; s < 4; ++s) {
          float wv[4] = {w4[s].x, w4[s].y, w4[s].z, w4[s].w};
#pragma unroll
          for (int j = 0; j < 4; ++j) acc[i][j] = fmaf(av[s], wv[j], acc[i][j]);
        }
      }
    }
    __syncthreads();
  }
#pragma unroll
  for (int i = 0; i < 8; ++i) {
    int row = rowBase + r0 + i;
    float d = dv[row];
    *(float4*)&Y[(size_t)row * H + c0] =
        make_float4(d * acc[i][0], d * acc[i][1], d * acc[i][2], d * acc[i][3]);
  }
}

// sparse GCN epilogue
__global__ void k_spmm_fin(const int* __restrict__ rowptr, const int* __restrict__ colidx,
                           const float* __restrict__ Y, const float* __restrict__ dv,
                           const float* __restrict__ bias, float* __restrict__ Out,
                           int n, int relu) {
  int row = blockIdx.x * 4 + (threadIdx.x >> 6);
  int lane = threadIdx.x & 63;
  if (row >= n) return;
  int s = rowptr[row], e = rowptr[row + 1];
  float a0 = 0.f, a1 = 0.f;
  int i = s;
  for (; i + 1 < e; i += 2) {
    int c0 = colidx[i], c1 = colidx[i + 1];
    a0 += Y[(size_t)c0 * H + lane] + Y[(size_t)c1 * H + lane];
    a1 += Y[(size_t)c0 * H + 64 + lane] + Y[(size_t)c1 * H + 64 + lane];
  }
  if (i < e) {
    int c = colidx[i];
    a0 += Y[(size_t)c * H + lane];
    a1 += Y[(size_t)c * H + 64 + lane];
  }
  float d = dv[row];
  float v0 = d * (a0 + 2.0f * Y[(size_t)row * H + lane]) + bias[lane];
  float v1 = d * (a1 + 2.0f * Y[(size_t)row * H + 64 + lane]) + bias[64 + lane];
  if (relu) { v0 = fmaxf(v0, 0.f); v1 = fmaxf(v1, 0.f); }
  Out[(size_t)row * H + lane] = v0;
  Out[(size_t)row * H + 64 + lane] = v1;
}

// level-0 ATA, row-wise (LDS int accumulators) -> bf16 row + dv fused
__global__ __launch_bounds__(256) void k_ata_rows(const int* __restrict__ rowptr,
                                                  const int* __restrict__ colidx,
                                                  const int* __restrict__ perm,
                                                  const int* __restrict__ inv,
                                                  unsigned short* __restrict__ Ab,
                                                  float* __restrict__ dv, int kdim) {
  __shared__ int acc[2048];
  __shared__ int wsum[4];
  int i = blockIdx.x;
  int tid = threadIdx.x;
  for (int j = tid; j < kdim; j += 256) acc[j] = 0;
  __syncthreads();
  int p = perm[i];
  int s = rowptr[p], e = rowptr[p + 1];
  int deg = e - s;
  int wave = tid >> 6, lane = tid & 63;
  for (int q = wave; q <= deg; q += 4) {
    int kn = (q < deg) ? colidx[s + q] : p;
    int s2 = rowptr[kn], e2 = rowptr[kn + 1];
    for (int idx = s2 + lane; idx <= e2; idx += 64) {
      int j = (idx < e2) ? colidx[idx] : kn;
      int ii = inv[j];
      if (ii >= 0) atomicAdd(&acc[ii], 1);
    }
  }
  __syncthreads();
  int rs = 0;
  {
    int j0 = tid * 8;
    ushort8 v;
#pragma unroll
    for (int q = 0; q < 8; ++q) {
      int j = j0 + q;
      int c = (j == i) ? 0 : acc[j];
      rs += c;
      v[q] = f2b((float)c);
    }
    *(ushort8*)&Ab[(size_t)i * kdim + j0] = v;
  }
#pragma unroll
  for (int o = 32; o > 0; o >>= 1) rs += __shfl_down(rs, o);
  if (lane == 0) wsum[wave] = rs;
  __syncthreads();
  if (tid == 0) dv[i] = rsqrtf((float)(wsum[0] + wsum[1] + wsum[2] + wsum[3]) + 2.0f);
}

// gather permuted S-rows into bf16 P (with +I), exact
__global__ void k_gather(const unsigned short* __restrict__ Ab, const int* __restrict__ perm,
                         unsigned short* __restrict__ P, int n, int k) {
  int row = blockIdx.x;
  int p = perm[row];
  const unsigned short* src = Ab + (size_t)p * n;
  unsigned short* dst = P + (size_t)row * n;
  for (int c = threadIdx.x * 8; c < n; c += 256 * 8) {
    *(ushort8*)&dst[c] = *(const ushort8*)&src[c];
  }
  __syncthreads();
  if (threadIdx.x == 0) dst[p] = f2b(b2f(src[p]) + 1.0f);
}

// C = P @ P^T via bf16 MFMA (exact small ints). Diagonal zeroed.
__global__ __launch_bounds__(256) void k_ata_mfma(const unsigned short* __restrict__ P,
                                                  float* __restrict__ C, int n, int k) {
  __shared__ __align__(16) unsigned short As[64][64];
  __shared__ __align__(16) unsigned short Bs[64][64];
  int tid = threadIdx.x;
  int w = tid >> 6, ln = tid & 63;
  int l15 = ln & 15, l4 = ln >> 4;
  int br = blockIdx.y, bc = blockIdx.x;
  f32x4 acc[4] = {};
  for (int k0 = 0; k0 < n; k0 += 64) {
#pragma unroll
    for (int it = 0; it < 2; ++it) {
      int e = tid + it * 256;
      int row = e >> 3, ch = e & 7;
      int sch = (ch ^ (row & 7)) * 8;
      *(ushort8*)&As[row][sch] = *(const ushort8*)&P[(size_t)(br * 64 + row) * n + k0 + ch * 8];
      *(ushort8*)&Bs[row][sch] = *(const ushort8*)&P[(size_t)(bc * 64 + row) * n + k0 + ch * 8];
    }
    __syncthreads();
#pragma unroll
    for (int s = 0; s < 2; ++s) {
      int arow = w * 16 + l15;
      bf16x8 af = *(const bf16x8*)&As[arow][((s * 4 + l4) ^ (arow & 7)) * 8];
#pragma unroll
      for (int f = 0; f < 4; ++f) {
        int brow = f * 16 + l15;
        bf16x8 bfr = *(const bf16x8*)&Bs[brow][((s * 4 + l4) ^ (brow & 7)) * 8];
        acc[f] = __builtin_amdgcn_mfma_f32_16x16x32_bf16(af, bfr, acc[f], 0, 0, 0);
      }
    }
    __syncthreads();
  }
#pragma unroll
  for (int f = 0; f < 4; ++f) {
#pragma unroll
    for (int r = 0; r < 4; ++r) {
      int gi = br * 64 + w * 16 + l4 * 4 + r;
      int gj = bc * 64 + f * 16 + l15;
      C[(size_t)gi * k + gj] = (gi == gj) ? 0.0f : acc[f][r];
    }
  }
}

// dense fp32 ATA split-K (level 2 only)
__global__ __launch_bounds__(256) void k_ata_sk(const float* __restrict__ A,
                                                const int* __restrict__ perm,
                                                float* __restrict__ C, int n, int k, int CK) {
  int bc = blockIdx.x, br = blockIdx.y;
  if (br > bc) return;
  __shared__ float As[64][36];
  __shared__ float Bs[64][36];
  __shared__ int pr[64], pc[64];
  int tid = threadIdx.x;
  if (tid < 64) pr[tid] = perm[br * 64 + tid];
  else if (tid < 128) pc[tid - 64] = perm[bc * 64 + (tid - 64)];
  __syncthreads();
  int ty = tid >> 4;
  int tx = tid & 15;
  float acc[4][4] = {};
  int k0s = blockIdx.z * CK;
  for (int k0 = k0s; k0 < k0s + CK; k0 += 32) {
#pragma unroll
    for (int it = 0, e = tid; it < 8; ++it, e += 256) {
      int ii = e >> 5, kk = e & 31;
      int gk = k0 + kk;
      int p = pr[ii];
      As[ii][kk] = A[(size_t)p * n + gk] + ((p == gk) ? 1.0f : 0.0f);
      p = pc[ii];
      Bs[ii][kk] = A[(size_t)p * n + gk] + ((p == gk) ? 1.0f : 0.0f);
    }
    __syncthreads();
#pragma unroll
    for (int kk = 0; kk < 32; kk += 4) {
      float4 a4[4], b4[4];
#pragma unroll
      for (int i = 0; i < 4; ++i) a4[i] = *(const float4*)&As[ty + 16 * i][kk];
#pragma unroll
      for (int j = 0; j < 4; ++j) b4[j] = *(const float4*)&Bs[tx + 16 * j][kk];
#pragma unroll
      for (int i = 0; i < 4; ++i) {
        float av[4] = {a4[i].x, a4[i].y, a4[i].z, a4[i].w};
#pragma unroll
        for (int j = 0; j < 4; ++j) {
          float bv[4] = {b4[j].x, b4[j].y, b4[j].z, b4[j].w};
#pragma unroll
          for (int s = 0; s < 4; ++s) acc[i][j] = fmaf(av[s], bv[s], acc[i][j]);
        }
      }
    }
    __syncthreads();
  }
  bool diag = (br == bc);
#pragma unroll
  for (int i = 0; i < 4; ++i) {
    int gi = br * 64 + ty + 16 * i;
#pragma unroll
    for (int j = 0; j < 4; ++j) {
      int gj = bc * 64 + tx + 16 * j;
      if (gi == gj) continue;
      float v = acc[i][j];
      atomicAdd(&C[(size_t)gi * k + gj], v);
      if (!diag) atomicAdd(&C[(size_t)gj * k + gi], v);
    }
  }
}

// fp32 dense GCN partial (split-K, private partials)
__global__ __launch_bounds__(256) void k_gcn_part(const float* __restrict__ A,
                                                  const float* __restrict__ Y,
                                                  float* __restrict__ Part,
                                                  int n, int KC) {
  __shared__ float As[64][36];
  __shared__ float Ys[32][132];
  int tid = threadIdx.x;
  int r0 = (tid >> 5) << 3;
  int c0 = (tid & 31) << 2;
  size_t rowBase = (size_t)blockIdx.x * 64;
  int k0s = blockIdx.y * KC;
  float* out = Part + (size_t)blockIdx.y * n * H;
  float acc[8][4] = {};
  for (int k0 = k0s; k0 < k0s + KC; k0 += 32) {
#pragma unroll
    for (int it = 0, e = tid; it < 8; ++it, e += 256) {
      int ii = e >> 5, kk = e & 31;
      As[ii][kk] = A[(rowBase + ii) * (size_t)n + k0 + kk];
    }
#pragma unroll
    for (int it = 0, e = tid; it < 4; ++it, e += 256) {
      int kk = e >> 5, cc4 = e & 31;
      *(float4*)&Ys[kk][cc4 << 2] = *(const float4*)&Y[(size_t)(k0 + kk) * H + (cc4 << 2)];
    }
    __syncthreads();
#pragma unroll
    for (int kk = 0; kk < 32; kk += 4) {
      float4 a4[8], y4[4];
#pragma unroll
      for (int i = 0; i < 8; ++i) a4[i] = *(const float4*)&As[r0 + i][kk];
#pragma unroll
      for (int s = 0; s < 4; ++s) y4[s] = *(const float4*)&Ys[kk + s][c0];
#pragma unroll
      for (int i = 0; i < 8; ++i) {
        float av[4] = {a4[i].x, a4[i].y, a4[i].z, a4[i].w};
#pragma unroll
        for (int s = 0; s < 4; ++s) {
          float yv[4] = {y4[s].x, y4[s].y, y4[s].z, y4[s].w};
#pragma unroll
          for (int j = 0; j < 4; ++j) acc[i][j] = fmaf(av[s], yv[j], acc[i][j]);
        }
      }
    }
    __syncthreads();
  }
#pragma unroll
  for (int i = 0; i < 8; ++i) {
    size_t row = rowBase + r0 + i;
    *(float4*)&out[row * H + c0] = make_float4(acc[i][0], acc[i][1], acc[i][2], acc[i][3]);
  }
}

// bf16-A variant
__global__ __launch_bounds__(256) void k_gcn_part_b16(const unsigned short* __restrict__ A,
                                                      const float* __restrict__ Y,
                                                      float* __restrict__ Part,
                                                      int n, int KC) {
  __shared__ float As[64][36];
  __shared__ float Ys[32][132];
  int tid = threadIdx.x;
  int r0 = (tid >> 5) << 3;
  int c0 = (tid & 31) << 2;
  size_t rowBase = (size_t)blockIdx.x * 64;
  int k0s = blockIdx.y * KC;
  float* out = Part + (size_t)blockIdx.y * n * H;
  float acc[8][4] = {};
  for (int k0 = k0s; k0 < k0s + KC; k0 += 32) {
    {
      int row = tid >> 2, ch = (tid & 3) * 8;
      ushort8 v = *(const ushort8*)&A[(rowBase + row) * (size_t)n + k0 + ch];
#pragma unroll
      for (int q = 0; q < 8; ++q) As[row][ch + q] = b2f(v[q]);
    }
#pragma unroll
    for (int it = 0, e = tid; it < 4; ++it, e += 256) {
      int kk = e >> 5, cc4 = e & 31;
      *(float4*)&Ys[kk][cc4 << 2] = *(const float4*)&Y[(size_t)(k0 + kk) * H + (cc4 << 2)];
    }
    __syncthreads();
#pragma unroll
    for (int kk = 0; kk < 32; kk += 4) {
      float4 a4[8], y4[4];
#pragma unroll
      for (int i = 0; i < 8; ++i) a4[i] = *(const float4*)&As[r0 + i][kk];
#pragma unroll
      for (int s = 0; s < 4; ++s) y4[s] = *(const float4*)&Ys[kk + s][c0];
#pragma unroll
      for (int i = 0; i < 8; ++i) {
        float av[4] = {a4[i].x, a4[i].y, a4[i].z, a4[i].w};
#pragma unroll
        for (int s = 0; s < 4; ++s) {
          float yv[4] = {y4[s].x, y4[s].y, y4[s].z, y4[s].w};
#pragma unroll
          for (int j = 0; j < 4; ++j) acc[i][j] = fmaf(av[s], yv[j], acc[i][j]);
        }
      }
    }
    __syncthreads();
  }
#pragma unroll
  for (int i = 0; i < 8; ++i) {
    size_t row = rowBase + r0 + i;
    *(float4*)&out[row * H + c0] = make_float4(acc[i][0], acc[i][1], acc[i][2], acc[i][3]);
  }
}

// Out = act(dv .* (sum_c Part[c] + 2Y) + bias)
__global__ void k_gcn_fin(const float* __restrict__ Part, const float* __restrict__ Y,
                          const float* __restrict__ dv, const float* __restrict__ bias,
                          float* __restrict__ Out, int n, int nch, int relu) {
  int i4 = blockIdx.x * 256 + threadIdx.x;
  if (i4 * 4 >= n * H) return;
  int row = i4 >> 5, c4 = (i4 & 31) * 4;
  size_t stride = (size_t)n * H;
  float4 s = *(const float4*)&Part[i4 * 4];
  for (int c = 1; c < nch; ++c) {
    float4 p = *(const float4*)&Part[c * stride + i4 * 4];
    s.x += p.x; s.y += p.y; s.z += p.z; s.w += p.w;
  }
  float4 y = *(const float4*)&Y[i4 * 4];
  float d = dv[row];
  float4 v;
  v.x = d * (s.x + 2.0f * y.x) + bias[c4];
  v.y = d * (s.y + 2.0f * y.y) + bias[c4 + 1];
  v.z = d * (s.z + 2.0f * y.z) + bias[c4 + 2];
  v.w = d * (s.w + 2.0f * y.w) + bias[c4 + 3];
  if (relu) {
    v.x = fmaxf(v.x, 0.f); v.y = fmaxf(v.y, 0.f);
    v.z = fmaxf(v.z, 0.f); v.w = fmaxf(v.w, 0.f);
  }
  *(float4*)&Out[i4 * 4] = v;
}

// score = tanh((h@w)/||w||)
__global__ void k_score(const float* __restrict__ h, const float* __restrict__ w,
                        float* __restrict__ score, int n) {
  __shared__ float wn;
  int tid = threadIdx.x;
  if (tid < 64) {
    float s = w[tid] * w[tid] + w[tid + 64] * w[tid + 64];
#pragma unroll
    for (int o = 32; o > 0; o >>= 1) s += __shfl_down(s, o);
    if (tid == 0) wn = sqrtf(s);
  }
  __syncthreads();
  int row = blockIdx.x * 4 + (tid >> 6);
  int lane = tid & 63;
  if (row >= n) return;
  float s = h[(size_t)row * H + lane] * w[lane] + h[(size_t)row * H + lane + 64] * w[lane + 64];
#pragma unroll
  for (int o = 32; o > 0; o >>= 1) s += __shfl_down(s, o);
  if (lane == 0) score[row] = tanhf(s / wn);
}

// ---- hybrid bitonic top-k ----
static __device__ __forceinline__ void ce_(unsigned long long& x, unsigned long long& y, bool asc) {
  if ((x < y) != asc) { unsigned long long t = x; x = y; y = t; }
}
static __device__ __forceinline__ unsigned long long pick_(unsigned long long a,
                                                           unsigned long long b,
                                                           bool lower, bool asc) {
  unsigned long long lo = (a < b) ? a : b;
  unsigned long long hi = (a < b) ? b : a;
  return (lower == asc) ? lo : hi;
}

template <int LOGN>
__global__ __launch_bounds__(1024) void k_topk(const float* __restrict__ score,
                                               int* __restrict__ perm,
                                               int* __restrict__ inv) {
  const int n = 1 << LOGN;
  __shared__ unsigned long long lds[1 << LOGN];
  int t = threadIdx.x;
  int e0 = t * 4;
  unsigned long long key[4];
#pragma unroll
  for (int j = 0; j < 4; ++j) {
    unsigned u = __float_as_uint(score[e0 + j]);
    u = (u & 0x80000000u) ? ~u : (u | 0x80000000u);
    u = ~u;
    key[j] = (((unsigned long long)u) << 32) | (unsigned)(e0 + j);
  }
  ce_(key[0], key[1], true);
  ce_(key[2], key[3], false);
  for (int size = 4; size <= n; size <<= 1) {
    bool asc = ((e0 & size) == 0);
    for (int stride = size >> 1; stride >= 256; stride >>= 1) {
#pragma unroll
      for (int j = 0; j < 4; ++j) lds[e0 + j] = key[j];
      __syncthreads();
      bool lower = ((e0 & stride) == 0);
#pragma unroll
      for (int j = 0; j < 4; ++j)
        key[j] = pick_(key[j], lds[(e0 + j) ^ stride], lower, asc);
      __syncthreads();
    }
    int s0 = ((size >> 1) < 256) ? (size >> 1) : 128;
    for (int stride = s0; stride >= 4; stride >>= 1) {
      int m = stride >> 2;
      bool lower = ((t & m) == 0);
#pragma unroll
      for (int j = 0; j < 4; ++j) {
        unsigned long long o = __shfl_xor(key[j], m, 64);
        key[j] = pick_(key[j], o, lower, asc);
      }
    }
    ce_(key[0], key[2], asc);
    ce_(key[1], key[3], asc);
    ce_(key[0], key[1], asc);
    ce_(key[2], key[3], asc);
  }
  int kk = n >> 1;
#pragma unroll
  for (int j = 0; j < 4; ++j) {
    int e = e0 + j;
    int idx = (int)(key[j] & 0xffffffffu);
    if (e < kk) perm[e] = idx;
    if (inv) inv[idx] = (e < kk) ? e : -1;
  }
}

__global__ void k_segsum(const float* __restrict__ h, const int* __restrict__ batch,
                         float* __restrict__ g, int n) {
  int c = threadIdx.x;
  int r0 = blockIdx.x * 32;
  int rend = min(r0 + 32, n);
  float acc = 0.f;
  int cur = batch[r0];
  for (int r = r0; r < rend; ++r) {
    int b = batch[r];
    if (b != cur) { atomicAdd(&g[cur * H + c], acc); acc = 0.f; cur = b; }
    acc += h[(size_t)r * H + c];
  }
  atomicAdd(&g[cur * H + c], acc);
}

__global__ __launch_bounds__(256) void k_head(const float* __restrict__ g,
    const float* __restrict__ lins_w, const float* __restrict__ lins_b,
    const float* __restrict__ bn_g, const float* __restrict__ bn_b,
    const float* __restrict__ out_w, const float* __restrict__ out_b,
    float* __restrict__ out) {
  __shared__ float a[NG * H], b[NG * H];
  int tid = threadIdx.x;
  const float inv = 1.0f / sqrtf(1.0f + 1e-5f);
  for (int i = tid; i < NG * H; i += 256) a[i] = g[i];
  __syncthreads();
  for (int L = 0; L < 3; ++L) {
    for (int i = tid; i < NG * H; i += 256) {
      int c = i & 127;
      b[i] = a[i] * (bn_g[L * H + c] * inv) + bn_b[L * H + c];
    }
    __syncthreads();
    for (int i = tid; i < NG * H; i += 256) {
      int r = i >> 7, c = i & 127;
      float s = lins_b[L * H + c];
      for (int k2 = 0; k2 < H; ++k2) s += b[r * H + k2] * lins_w[(size_t)L * H * H + k2 * H + c];
      a[i] = tanhf(s);
    }
    __syncthreads();
  }
  for (int i = tid; i < NG * H; i += 256) {
    int c = i & 127;
    b[i] = a[i] * (bn_g[3 * H + c] * inv) + bn_b[3 * H + c];
  }
  __syncthreads();
  for (int i = tid; i < NG * 32; i += 256) {
    int r = i >> 5, o = i & 31;
    float s = out_b[o];
    for (int k2 = 0; k2 < H; ++k2) s += b[r * H + k2] * out_w[k2 * 32 + o];
    out[i] = s;
  }
}

extern "C" void kernel_launch(void* const* d_in, const int* in_sizes, int n_in,
                              void* d_out, int out_size, void* d_ws, size_t ws_size,
                              hipStream_t stream) {
  const float* x       = (const float*)d_in[0];
  const int*   ei      = (const int*)d_in[1];
  const int*   batch   = (const int*)d_in[2];
  const float* conv0_w = (const float*)d_in[3];
  const float* conv0_b = (const float*)d_in[4];
  const float* down_w  = (const float*)d_in[5];
  const float* down_b  = (const float*)d_in[6];
  const float* pool_w  = (const float*)d_in[7];
  const float* up_w    = (const float*)d_in[8];
  const float* up_b    = (const float*)d_in[9];
  const float* lins_w  = (const float*)d_in[10];
  const float* lins_b  = (const float*)d_in[11];
  const float* bn_g    = (const float*)d_in[12];
  const float* bn_b    = (const float*)d_in[13];
  const float* out_w   = (const float*)d_in[14];
  const float* out_b   = (const float*)d_in[15];
  int E = in_sizes[1] / 2;

  char* p = (char*)d_ws;
  auto alloc = [&](size_t bytes) {
    char* r = p;
    p += (bytes + 255) & ~(size_t)255;
    return r;
  };
  unsigned short* A1b  = (unsigned short*)alloc((size_t)2048 * 2048 * 2);
  unsigned short* P    = (unsigned short*)alloc((size_t)1024 * 2048 * 2);
  float*          A2m  = (float*)alloc((size_t)1024 * 1024 * 4);
  float*          A3   = (float*)alloc((size_t)512 * 512 * 4);
  float*          part = (float*)alloc((size_t)8 * 2048 * H * 4);
  int* cnt    = (int*)alloc(4096 * 4);
  int* cursor = (int*)alloc(4096 * 4);
  int* rowptr = (int*)alloc(4100 * 4);
  int* colidx = (int*)alloc((size_t)E * 4);
  int* inv0   = (int*)alloc(4096 * 4);
  int* inv1   = (int*)alloc(2048 * 4);
  int* inv2   = (int*)alloc(1024 * 4);
  float* dv0  = (float*)alloc(4096 * 4);
  float* dv1  = (float*)alloc(2048 * 4);
  float* dv2  = (float*)alloc(1024 * 4);
  float* dv3  = (float*)alloc(512 * 4);
  int* perm0  = (int*)alloc(2048 * 4);
  int* perm1  = (int*)alloc(1024 * 4);
  int* perm2  = (int*)alloc(512 * 4);
  float* score = (float*)alloc(4096 * 4);
  float* h0 = (float*)alloc((size_t)4096 * H * 4);
  float* h1 = (float*)alloc((size_t)2048 * H * 4);
  float* h2 = (float*)alloc((size_t)1024 * H * 4);
  float* h3 = (float*)alloc((size_t)512 * H * 4);
  float* t2 = (float*)alloc((size_t)4096 * H * 4);
  float* hu = (float*)alloc((size_t)4096 * H * 4);
  float* g  = (float*)alloc(NG * H * 4);

  auto gcn = [&](const float* A, const unsigned short* Ab, const float* Y, const float* dvv,
                 const float* bias, float* Out, int nn, int relu) {
    const int nch = 8;
    int KC = nn / nch;
    if (Ab)
      k_gcn_part_b16<<<dim3(nn / 64, nch), 256, 0, stream>>>(Ab, Y, part, nn, KC);
    else
      k_gcn_part<<<dim3(nn / 64, nch), 256, 0, stream>>>(A, Y, part, nn, KC);
    k_gcn_fin<<<nn / 8, 256, 0, stream>>>(part, Y, dvv, bias, Out, nn, nch, relu);
  };

  // ---- CSR build ----
  hipMemsetAsync(cnt, 0, 4096 * 4, stream);
  hipMemsetAsync(cursor, 0, 4096 * 4, stream);
  k_hist<<<(E + 255) / 256, 256, 0, stream>>>(ei, E, cnt);
  k_scan<<<1, 1024, 0, stream>>>(cnt, rowptr, 4096);
  k_fill<<<(E + 255) / 256, 256, 0, stream>>>(ei, E, rowptr, cursor, colidx);
  k_dvcnt<<<4096 / 256, 256, 0, stream>>>(cnt, dv0, 4096);

  // ---- conv0 (sparse) ----
  k_xw<0><<<4096 / 64, 256, 0, stream>>>(x, conv0_w, dv0, nullptr, nullptr, t2, 4096, 64);
  k_spmm_fin<<<1024, 256, 0, stream>>>(rowptr, colidx, t2, dv0, conv0_b, h0, 4096, 1);

  // ---- level 0 pooling (4096 -> 2048): row-wise sparse ATA -> bf16 + dv1 ----
  k_score<<<1024, 256, 0, stream>>>(h0, pool_w, score, 4096);
  k_topk<12><<<1, 1024, 0, stream>>>(score, perm0, inv0);
  k_ata_rows<<<2048, 256, 0, stream>>>(rowptr, colidx, perm0, inv0, A1b, dv1, 2048);
  k_xw<1><<<2048 / 64, 256, 0, stream>>>(h0, down_w, dv1, perm0, score, t2, 2048, 128);
  gcn(nullptr, A1b, t2, dv1, down_b, h1, 2048, 1);

  // ---- level 1 pooling (2048 -> 1024): bf16 MFMA ATA ----
  k_score<<<512, 256, 0, stream>>>(h1, pool_w + H, score, 2048);
  k_topk<11><<<1, 512, 0, stream>>>(score, perm1, inv1);
  k_gather<<<1024, 256, 0, stream>>>(A1b, perm1, P, 2048, 1024);
  k_ata_mfma<<<dim3(16, 16), 256, 0, stream>>>(P, A2m, 2048, 1024);
  k_deg<<<1024 / 4, 256, 0, stream>>>(A2m, 1024, dv2);
  k_xw<1><<<1024 / 64, 256, 0, stream>>>(h1, down_w + (size_t)H * H, dv2, perm1, score, t2, 1024, 128);
  gcn(A2m, nullptr, t2, dv2, down_b + H, h2, 1024, 1);

  // ---- level 2 pooling (1024 -> 512): fp32 split-K ATA ----
  k_score<<<256, 256, 0, stream>>>(h2, pool_w + 2 * H, score, 1024);
  k_topk<10><<<1, 256, 0, stream>>>(score, perm2, inv2);
  hipMemsetAsync(A3, 0, (size_t)512 * 512 * 4, stream);
  k_ata_sk<<<dim3(8, 8, 8), 256, 0, stream>>>(A2m, perm2, A3, 1024, 512, 128);
  k_deg<<<512 / 4, 256, 0, stream>>>(A3, 512, dv3);
  k_xw<1><<<512 / 64, 256, 0, stream>>>(h2, down_w + (size_t)2 * H * H, dv3, perm2, score, t2, 512, 128);
  gcn(A3, nullptr, t2, dv3, down_b + 2 * H, h3, 512, 1);

  // ---- up path (skip fused into xw) ----
  k_xw<2><<<1024 / 64, 256, 0, stream>>>(h2, up_w, dv2, inv2, h3, t2, 1024, 128);
  gcn(A2m, nullptr, t2, dv2, up_b, hu, 1024, 1);

  k_xw<2><<<2048 / 64, 256, 0, stream>>>(h1, up_w + (size_t)H * H, dv1, inv1, hu, t2, 2048, 128);
  gcn(nullptr, A1b, t2, dv1, up_b + H, hu, 2048, 1);

  k_xw<2><<<4096 / 64, 256, 0, stream>>>(h0, up_w + (size_t)2 * H * H, dv0, inv0, hu, t2, 4096, 128);
  k_spmm_fin<<<1024, 256, 0, stream>>>(rowptr, colidx, t2, dv0, up_b + 2 * H, hu, 4096, 0);

  // ---- pool + head ----
  hipMemsetAsync(g, 0, NG * H * 4, stream);
  k_segsum<<<4096 / 32, 128, 0, stream>>>(hu, batch, g, 4096);
  k_head<<<1, 256, 0, stream>>>(g, lins_w, lins_b, bn_g, bn_b, out_w, out_b, (float*)d_out);
}

// Round 8
// 529.705 us; speedup vs baseline: 7.9930x; 1.0141x over previous
//
#include <hip/hip_runtime.h>
#include <math.h>

#define H 128
#define NG 8

typedef __attribute__((ext_vector_type(8))) short bf16x8;
typedef __attribute__((ext_vector_type(8))) unsigned short ushort8;
typedef __attribute__((ext_vector_type(4))) float f32x4;

static __device__ __forceinline__ float b2f(unsigned short u) {
  union { unsigned int i; float f; } v;
  v.i = ((unsigned int)u) << 16;
  return v.f;
}
static __device__ __forceinline__ unsigned short f2b(float f) {
  return (unsigned short)(__float_as_uint(f) >> 16);  // truncation; exact for small ints
}

// ---------------- CSR build from edge list ----------------
__global__ void k_hist(const int* __restrict__ ei, int E, int* __restrict__ cnt) {
  int e = blockIdx.x * 256 + threadIdx.x;
  if (e >= E) return;
  atomicAdd(&cnt[ei[E + e]], 1);
}

__global__ __launch_bounds__(1024) void k_scan(const int* __restrict__ cnt,
                                               int* __restrict__ rowptr, int n) {
  __shared__ int sums[1024];
  int tid = threadIdx.x;
  int base = tid * 4;
  int v0 = 0, v1 = 0, v2 = 0, v3 = 0;
  if (base < n) { v0 = cnt[base]; v1 = cnt[base + 1]; v2 = cnt[base + 2]; v3 = cnt[base + 3]; }
  int s = v0 + v1 + v2 + v3;
  sums[tid] = s;
  __syncthreads();
  for (int off = 1; off < 1024; off <<= 1) {
    int t = (tid >= off) ? sums[tid - off] : 0;
    __syncthreads();
    sums[tid] += t;
    __syncthreads();
  }
  int excl = sums[tid] - s;
  if (base < n) {
    rowptr[base] = excl;
    rowptr[base + 1] = excl + v0;
    rowptr[base + 2] = excl + v0 + v1;
    rowptr[base + 3] = excl + v0 + v1 + v2;
  }
  if (tid == 1023) rowptr[n] = sums[1023];
}

__global__ void k_fill(const int* __restrict__ ei, int E, const int* __restrict__ rowptr,
                       int* __restrict__ cursor, int* __restrict__ colidx) {
  int e = blockIdx.x * 256 + threadIdx.x;
  if (e >= E) return;
  int r = ei[E + e], c = ei[e];
  int p = atomicAdd(&cursor[r], 1);
  colidx[rowptr[r] + p] = c;
}

__global__ void k_dvcnt(const int* __restrict__ cnt, float* __restrict__ dv, int n) {
  int i = blockIdx.x * 256 + threadIdx.x;
  if (i < n) dv[i] = rsqrtf((float)cnt[i] + 2.0f);
}

// d[i] = rsqrt(rowsum(A)+2) for dense fp32 A
__global__ void k_deg(const float* __restrict__ A, int n, float* __restrict__ dv) {
  int row = blockIdx.x * (blockDim.x >> 6) + (threadIdx.x >> 6);
  int lane = threadIdx.x & 63;
  if (row >= n) return;
  float s = 0.f;
  const float* arow = A + (size_t)row * n;
  for (int j = lane; j < n; j += 64) s += arow[j];
#pragma unroll
  for (int o = 32; o > 0; o >>= 1) s += __shfl_down(s, o);
  if (lane == 0) dv[row] = rsqrtf(s + 2.0f);
}

// Y[r,c] = dv[r] * sum_k X'[r,k] W[k,c]  -- tiled GEMM, 64x128 per block
// MODE 0: X'=X ; MODE 1 (pool): X'[r,k]=X[perm[r],k]*score[perm[r]]
// MODE 2 (skip): X'[r,k]=X[r,k]+(inv[r]>=0?prev[inv[r],k]:0)
template <int MODE>
__global__ __launch_bounds__(256) void k_xw(const float* __restrict__ X,
                                            const float* __restrict__ W,
                                            const float* __restrict__ dv,
                                            const int* __restrict__ idx,
                                            const float* __restrict__ aux,
                                            float* __restrict__ Y, int n, int F) {
  __shared__ float Xs[64][36];
  __shared__ float Ws[32][132];
  __shared__ int ridx[64];
  __shared__ float rscl[64];
  int tid = threadIdx.x;
  int rowBase = blockIdx.x * 64;
  if (MODE == 1) {
    if (tid < 64) {
      int pp = idx[rowBase + tid];
      ridx[tid] = pp;
      rscl[tid] = aux[pp];
    }
  } else if (MODE == 2) {
    if (tid < 64) ridx[tid] = idx[rowBase + tid];
  }
  if (MODE != 0) __syncthreads();
  int r0 = (tid >> 5) << 3;
  int c0 = (tid & 31) << 2;
  float acc[8][4] = {};
  for (int k0 = 0; k0 < F; k0 += 32) {
#pragma unroll
    for (int it = 0, e = tid; it < 8; ++it, e += 256) {
      int ii = e >> 5, kk = e & 31;
      int gk = k0 + kk;
      float v;
      if (MODE == 0) {
        v = X[(size_t)(rowBase + ii) * F + gk];
      } else if (MODE == 1) {
        v = X[(size_t)ridx[ii] * F + gk] * rscl[ii];
      } else {
        v = X[(size_t)(rowBase + ii) * F + gk];
        int iv = ridx[ii];
        if (iv >= 0) v += aux[(size_t)iv * H + gk];
      }
      Xs[ii][kk] = v;
    }
#pragma unroll
    for (int it = 0, e = tid; it < 4; ++it, e += 256) {
      int kk = e >> 5, cc4 = e & 31;
      *(float4*)&Ws[kk][cc4 << 2] = *(const float4*)&W[(size_t)(k0 + kk) * H + (cc4 << 2)];
    }
    __syncthreads();
#pragma unroll
    for (int kk = 0; kk < 32; kk += 4) {
      float4 a4[8], w4[4];
#pragma unroll
      for (int i = 0; i < 8; ++i) a4[i] = *(const float4*)&Xs[r0 + i][kk];
#pragma unroll
      for (int s = 0; s < 4; ++s) w4[s] = *(const float4*)&Ws[kk + s][c0];
#pragma unroll
      for (int i = 0; i < 8; ++i) {
        float av[4] = {a4[i].x, a4[i].y, a4[i].z, a4[i].w};
#pragma unroll
        for (int s = 0; s < 4; ++s) {
          float wv[4] = {w4[s].x, w4[s].y, w4[s].z, w4[s].w};
#pragma unroll
          for (int j = 0; j < 4; ++j) acc[i][j] = fmaf(av[s], wv[j], acc[i][j]);
        }
      }
    }
    __syncthreads();
  }
#pragma unroll
  for (int i = 0; i < 8; ++i) {
    int row = rowBase + r0 + i;
    float d = dv[row];
    *(float4*)&Y[(size_t)row * H + c0] =
        make_float4(d * acc[i][0], d * acc[i][1], d * acc[i][2], d * acc[i][3]);
  }
}

// sparse GCN epilogue
__global__ void k_spmm_fin(const int* __restrict__ rowptr, const int* __restrict__ colidx,
                           const float* __restrict__ Y, const float* __restrict__ dv,
                           const float* __restrict__ bias, float* __restrict__ Out,
                           int n, int relu) {
  int row = blockIdx.x * 4 + (threadIdx.x >> 6);
  int lane = threadIdx.x & 63;
  if (row >= n) return;
  int s = rowptr[row], e = rowptr[row + 1];
  float a0 = 0.f, a1 = 0.f;
  int i = s;
  for (; i + 1 < e; i += 2) {
    int c0 = colidx[i], c1 = colidx[i + 1];
    a0 += Y[(size_t)c0 * H + lane] + Y[(size_t)c1 * H + lane];
    a1 += Y[(size_t)c0 * H + 64 + lane] + Y[(size_t)c1 * H + 64 + lane];
  }
  if (i < e) {
    int c = colidx[i];
    a0 += Y[(size_t)c * H + lane];
    a1 += Y[(size_t)c * H + 64 + lane];
  }
  float d = dv[row];
  float v0 = d * (a0 + 2.0f * Y[(size_t)row * H + lane]) + bias[lane];
  float v1 = d * (a1 + 2.0f * Y[(size_t)row * H + 64 + lane]) + bias[64 + lane];
  if (relu) { v0 = fmaxf(v0, 0.f); v1 = fmaxf(v1, 0.f); }
  Out[(size_t)row * H + lane] = v0;
  Out[(size_t)row * H + 64 + lane] = v1;
}

// level-0 ATA, row-wise (LDS int accumulators) -> bf16 row + dv fused
__global__ __launch_bounds__(256) void k_ata_rows(const int* __restrict__ rowptr,
                                                  const int* __restrict__ colidx,
                                                  const int* __restrict__ perm,
                                                  const int* __restrict__ inv,
                                                  unsigned short* __restrict__ Ab,
                                                  float* __restrict__ dv, int kdim) {
  __shared__ int acc[2048];
  __shared__ int wsum[4];
  int i = blockIdx.x;
  int tid = threadIdx.x;
  for (int j = tid; j < kdim; j += 256) acc[j] = 0;
  __syncthreads();
  int p = perm[i];
  int s = rowptr[p], e = rowptr[p + 1];
  int deg = e - s;
  int wave = tid >> 6, lane = tid & 63;
  for (int q = wave; q <= deg; q += 4) {
    int kn = (q < deg) ? colidx[s + q] : p;
    int s2 = rowptr[kn], e2 = rowptr[kn + 1];
    for (int idx = s2 + lane; idx <= e2; idx += 64) {
      int j = (idx < e2) ? colidx[idx] : kn;
      int ii = inv[j];
      if (ii >= 0) atomicAdd(&acc[ii], 1);
    }
  }
  __syncthreads();
  int rs = 0;
  {
    int j0 = tid * 8;
    ushort8 v;
#pragma unroll
    for (int q = 0; q < 8; ++q) {
      int j = j0 + q;
      int c = (j == i) ? 0 : acc[j];
      rs += c;
      v[q] = f2b((float)c);
    }
    *(ushort8*)&Ab[(size_t)i * kdim + j0] = v;
  }
#pragma unroll
  for (int o = 32; o > 0; o >>= 1) rs += __shfl_down(rs, o);
  if (lane == 0) wsum[wave] = rs;
  __syncthreads();
  if (tid == 0) dv[i] = rsqrtf((float)(wsum[0] + wsum[1] + wsum[2] + wsum[3]) + 2.0f);
}

// gather permuted S-rows into bf16 P (with +I), exact
__global__ void k_gather(const unsigned short* __restrict__ Ab, const int* __restrict__ perm,
                         unsigned short* __restrict__ P, int n, int k) {
  int row = blockIdx.x;
  int p = perm[row];
  const unsigned short* src = Ab + (size_t)p * n;
  unsigned short* dst = P + (size_t)row * n;
  for (int c = threadIdx.x * 8; c < n; c += 256 * 8) {
    *(ushort8*)&dst[c] = *(const ushort8*)&src[c];
  }
  __syncthreads();
  if (threadIdx.x == 0) dst[p] = f2b(b2f(src[p]) + 1.0f);
}

// C = P @ P^T via bf16 MFMA (exact small ints). Diagonal zeroed.
__global__ __launch_bounds__(256) void k_ata_mfma(const unsigned short* __restrict__ P,
                                                  float* __restrict__ C, int n, int k) {
  __shared__ __align__(16) unsigned short As[64][64];
  __shared__ __align__(16) unsigned short Bs[64][64];
  int tid = threadIdx.x;
  int w = tid >> 6, ln = tid & 63;
  int l15 = ln & 15, l4 = ln >> 4;
  int br = blockIdx.y, bc = blockIdx.x;
  f32x4 acc[4] = {};
  for (int k0 = 0; k0 < n; k0 += 64) {
#pragma unroll
    for (int it = 0; it < 2; ++it) {
      int e = tid + it * 256;
      int row = e >> 3, ch = e & 7;
      int sch = (ch ^ (row & 7)) * 8;
      *(ushort8*)&As[row][sch] = *(const ushort8*)&P[(size_t)(br * 64 + row) * n + k0 + ch * 8];
      *(ushort8*)&Bs[row][sch] = *(const ushort8*)&P[(size_t)(bc * 64 + row) * n + k0 + ch * 8];
    }
    __syncthreads();
#pragma unroll
    for (int s = 0; s < 2; ++s) {
      int arow = w * 16 + l15;
      bf16x8 af = *(const bf16x8*)&As[arow][((s * 4 + l4) ^ (arow & 7)) * 8];
#pragma unroll
      for (int f = 0; f < 4; ++f) {
        int brow = f * 16 + l15;
        bf16x8 bfr = *(const bf16x8*)&Bs[brow][((s * 4 + l4) ^ (brow & 7)) * 8];
        acc[f] = __builtin_amdgcn_mfma_f32_16x16x32_bf16(af, bfr, acc[f], 0, 0, 0);
      }
    }
    __syncthreads();
  }
#pragma unroll
  for (int f = 0; f < 4; ++f) {
#pragma unroll
    for (int r = 0; r < 4; ++r) {
      int gi = br * 64 + w * 16 + l4 * 4 + r;
      int gj = bc * 64 + f * 16 + l15;
      C[(size_t)gi * k + gj] = (gi == gj) ? 0.0f : acc[f][r];
    }
  }
}

// Y [n][128] fp32 -> YT [128][2n] bf16: YT[c][k]=hi(Y[k][c]), YT[c][n+k]=lo residual
__global__ void k_cvt_split(const float* __restrict__ Y, unsigned short* __restrict__ YT, int n) {
  int c = blockIdx.x;  // 0..127
  for (int k0 = threadIdx.x * 8; k0 < n; k0 += 256 * 8) {
    ushort8 hi, lo;
#pragma unroll
    for (int q = 0; q < 8; ++q) {
      float v = Y[(size_t)(k0 + q) * H + c];
      unsigned short h = f2b(v);
      hi[q] = h;
      lo[q] = f2b(v - b2f(h));
    }
    *(ushort8*)&YT[(size_t)c * (2 * n) + k0] = hi;
    *(ushort8*)&YT[(size_t)c * (2 * n) + n + k0] = lo;
  }
}

// Partial A@Y via bf16 MFMA over virtual K=2n (hi|lo limbs of Y).
// A bf16 exact (n x n, row-major); YT [128][2n]. Split-K: blockIdx.y chunk -> private partial.
__global__ __launch_bounds__(256) void k_gcn_mfma(const unsigned short* __restrict__ A,
                                                  const unsigned short* __restrict__ YT,
                                                  float* __restrict__ Part, int n, int VK) {
  __shared__ __align__(16) unsigned short As[64][64];
  __shared__ __align__(16) unsigned short Bs[128][64];
  int tid = threadIdx.x;
  int w = tid >> 6, ln = tid & 63;
  int l15 = ln & 15, l4 = ln >> 4;
  int rowBase = blockIdx.x * 64;
  float* out = Part + (size_t)blockIdx.y * n * H;
  f32x4 acc[8] = {};
  int vk0s = blockIdx.y * VK;
  for (int vk0 = vk0s; vk0 < vk0s + VK; vk0 += 64) {
    int ka = vk0 & (n - 1);  // physical A column (hi/lo halves share A)
#pragma unroll
    for (int it = 0; it < 2; ++it) {
      int e = tid + it * 256;
      int row = e >> 3, ch = e & 7;
      int sch = (ch ^ (row & 7)) * 8;
      *(ushort8*)&As[row][sch] = *(const ushort8*)&A[(size_t)(rowBase + row) * n + ka + ch * 8];
    }
#pragma unroll
    for (int it = 0; it < 4; ++it) {
      int e = tid + it * 256;
      int row = e >> 3, ch = e & 7;
      int sch = (ch ^ (row & 7)) * 8;
      *(ushort8*)&Bs[row][sch] = *(const ushort8*)&YT[(size_t)row * (2 * n) + vk0 + ch * 8];
    }
    __syncthreads();
#pragma unroll
    for (int s = 0; s < 2; ++s) {
      int arow = w * 16 + l15;
      bf16x8 af = *(const bf16x8*)&As[arow][((s * 4 + l4) ^ (arow & 7)) * 8];
#pragma unroll
      for (int f = 0; f < 8; ++f) {
        int brow = f * 16 + l15;
        bf16x8 bfr = *(const bf16x8*)&Bs[brow][((s * 4 + l4) ^ (brow & 7)) * 8];
        acc[f] = __builtin_amdgcn_mfma_f32_16x16x32_bf16(af, bfr, acc[f], 0, 0, 0);
      }
    }
    __syncthreads();
  }
#pragma unroll
  for (int f = 0; f < 8; ++f) {
#pragma unroll
    for (int r = 0; r < 4; ++r) {
      int row = rowBase + w * 16 + l4 * 4 + r;
      out[(size_t)row * H + f * 16 + l15] = acc[f][r];
    }
  }
}

// dense fp32 ATA split-K (level 2 only)
__global__ __launch_bounds__(256) void k_ata_sk(const float* __restrict__ A,
                                                const int* __restrict__ perm,
                                                float* __restrict__ C, int n, int k, int CK) {
  int bc = blockIdx.x, br = blockIdx.y;
  if (br > bc) return;
  __shared__ float As[64][36];
  __shared__ float Bs[64][36];
  __shared__ int pr[64], pc[64];
  int tid = threadIdx.x;
  if (tid < 64) pr[tid] = perm[br * 64 + tid];
  else if (tid < 128) pc[tid - 64] = perm[bc * 64 + (tid - 64)];
  __syncthreads();
  int ty = tid >> 4;
  int tx = tid & 15;
  float acc[4][4] = {};
  int k0s = blockIdx.z * CK;
  for (int k0 = k0s; k0 < k0s + CK; k0 += 32) {
#pragma unroll
    for (int it = 0, e = tid; it < 8; ++it, e += 256) {
      int ii = e >> 5, kk = e & 31;
      int gk = k0 + kk;
      int p = pr[ii];
      As[ii][kk] = A[(size_t)p * n + gk] + ((p == gk) ? 1.0f : 0.0f);
      p = pc[ii];
      Bs[ii][kk] = A[(size_t)p * n + gk] + ((p == gk) ? 1.0f : 0.0f);
    }
    __syncthreads();
#pragma unroll
    for (int kk = 0; kk < 32; kk += 4) {
      float4 a4[4], b4[4];
#pragma unroll
      for (int i = 0; i < 4; ++i) a4[i] = *(const float4*)&As[ty + 16 * i][kk];
#pragma unroll
      for (int j = 0; j < 4; ++j) b4[j] = *(const float4*)&Bs[tx + 16 * j][kk];
#pragma unroll
      for (int i = 0; i < 4; ++i) {
        float av[4] = {a4[i].x, a4[i].y, a4[i].z, a4[i].w};
#pragma unroll
        for (int j = 0; j < 4; ++j) {
          float bv[4] = {b4[j].x, b4[j].y, b4[j].z, b4[j].w};
#pragma unroll
          for (int s = 0; s < 4; ++s) acc[i][j] = fmaf(av[s], bv[s], acc[i][j]);
        }
      }
    }
    __syncthreads();
  }
  bool diag = (br == bc);
#pragma unroll
  for (int i = 0; i < 4; ++i) {
    int gi = br * 64 + ty + 16 * i;
#pragma unroll
    for (int j = 0; j < 4; ++j) {
      int gj = bc * 64 + tx + 16 * j;
      if (gi == gj) continue;
      float v = acc[i][j];
      atomicAdd(&C[(size_t)gi * k + gj], v);
      if (!diag) atomicAdd(&C[(size_t)gj * k + gi], v);
    }
  }
}

// fp32 dense GCN partial (split-K, private partials) -- n<=1024 levels
__global__ __launch_bounds__(256) void k_gcn_part(const float* __restrict__ A,
                                                  const float* __restrict__ Y,
                                                  float* __restrict__ Part,
                                                  int n, int KC) {
  __shared__ float As[64][36];
  __shared__ float Ys[32][132];
  int tid = threadIdx.x;
  int r0 = (tid >> 5) << 3;
  int c0 = (tid & 31) << 2;
  size_t rowBase = (size_t)blockIdx.x * 64;
  int k0s = blockIdx.y * KC;
  float* out = Part + (size_t)blockIdx.y * n * H;
  float acc[8][4] = {};
  for (int k0 = k0s; k0 < k0s + KC; k0 += 32) {
#pragma unroll
    for (int it = 0, e = tid; it < 8; ++it, e += 256) {
      int ii = e >> 5, kk = e & 31;
      As[ii][kk] = A[(rowBase + ii) * (size_t)n + k0 + kk];
    }
#pragma unroll
    for (int it = 0, e = tid; it < 4; ++it, e += 256) {
      int kk = e >> 5, cc4 = e & 31;
      *(float4*)&Ys[kk][cc4 << 2] = *(const float4*)&Y[(size_t)(k0 + kk) * H + (cc4 << 2)];
    }
    __syncthreads();
#pragma unroll
    for (int kk = 0; kk < 32; kk += 4) {
      float4 a4[8], y4[4];
#pragma unroll
      for (int i = 0; i < 8; ++i) a4[i] = *(const float4*)&As[r0 + i][kk];
#pragma unroll
      for (int s = 0; s < 4; ++s) y4[s] = *(const float4*)&Ys[kk + s][c0];
#pragma unroll
      for (int i = 0; i < 8; ++i) {
        float av[4] = {a4[i].x, a4[i].y, a4[i].z, a4[i].w};
#pragma unroll
        for (int s = 0; s < 4; ++s) {
          float yv[4] = {y4[s].x, y4[s].y, y4[s].z, y4[s].w};
#pragma unroll
          for (int j = 0; j < 4; ++j) acc[i][j] = fmaf(av[s], yv[j], acc[i][j]);
        }
      }
    }
    __syncthreads();
  }
#pragma unroll
  for (int i = 0; i < 8; ++i) {
    size_t row = rowBase + r0 + i;
    *(float4*)&out[row * H + c0] = make_float4(acc[i][0], acc[i][1], acc[i][2], acc[i][3]);
  }
}

// Out = act(dv .* (sum_c Part[c] + 2Y) + bias)
__global__ void k_gcn_fin(const float* __restrict__ Part, const float* __restrict__ Y,
                          const float* __restrict__ dv, const float* __restrict__ bias,
                          float* __restrict__ Out, int n, int nch, int relu) {
  int i4 = blockIdx.x * 256 + threadIdx.x;
  if (i4 * 4 >= n * H) return;
  int row = i4 >> 5, c4 = (i4 & 31) * 4;
  size_t stride = (size_t)n * H;
  float4 s = *(const float4*)&Part[i4 * 4];
  for (int c = 1; c < nch; ++c) {
    float4 p = *(const float4*)&Part[c * stride + i4 * 4];
    s.x += p.x; s.y += p.y; s.z += p.z; s.w += p.w;
  }
  float4 y = *(const float4*)&Y[i4 * 4];
  float d = dv[row];
  float4 v;
  v.x = d * (s.x + 2.0f * y.x) + bias[c4];
  v.y = d * (s.y + 2.0f * y.y) + bias[c4 + 1];
  v.z = d * (s.z + 2.0f * y.z) + bias[c4 + 2];
  v.w = d * (s.w + 2.0f * y.w) + bias[c4 + 3];
  if (relu) {
    v.x = fmaxf(v.x, 0.f); v.y = fmaxf(v.y, 0.f);
    v.z = fmaxf(v.z, 0.f); v.w = fmaxf(v.w, 0.f);
  }
  *(float4*)&Out[i4 * 4] = v;
}

// score = tanh((h@w)/||w||)
__global__ void k_score(const float* __restrict__ h, const float* __restrict__ w,
                        float* __restrict__ score, int n) {
  __shared__ float wn;
  int tid = threadIdx.x;
  if (tid < 64) {
    float s = w[tid] * w[tid] + w[tid + 64] * w[tid + 64];
#pragma unroll
    for (int o = 32; o > 0; o >>= 1) s += __shfl_down(s, o);
    if (tid == 0) wn = sqrtf(s);
  }
  __syncthreads();
  int row = blockIdx.x * 4 + (tid >> 6);
  int lane = tid & 63;
  if (row >= n) return;
  float s = h[(size_t)row * H + lane] * w[lane] + h[(size_t)row * H + lane + 64] * w[lane + 64];
#pragma unroll
  for (int o = 32; o > 0; o >>= 1) s += __shfl_down(s, o);
  if (lane == 0) score[row] = tanhf(s / wn);
}

// ---- hybrid bitonic top-k ----
static __device__ __forceinline__ void ce_(unsigned long long& x, unsigned long long& y, bool asc) {
  if ((x < y) != asc) { unsigned long long t = x; x = y; y = t; }
}
static __device__ __forceinline__ unsigned long long pick_(unsigned long long a,
                                                           unsigned long long b,
                                                           bool lower, bool asc) {
  unsigned long long lo = (a < b) ? a : b;
  unsigned long long hi = (a < b) ? b : a;
  return (lower == asc) ? lo : hi;
}

template <int LOGN>
__global__ __launch_bounds__(1024) void k_topk(const float* __restrict__ score,
                                               int* __restrict__ perm,
                                               int* __restrict__ inv) {
  const int n = 1 << LOGN;
  __shared__ unsigned long long lds[1 << LOGN];
  int t = threadIdx.x;
  int e0 = t * 4;
  unsigned long long key[4];
#pragma unroll
  for (int j = 0; j < 4; ++j) {
    unsigned u = __float_as_uint(score[e0 + j]);
    u = (u & 0x80000000u) ? ~u : (u | 0x80000000u);
    u = ~u;
    key[j] = (((unsigned long long)u) << 32) | (unsigned)(e0 + j);
  }
  ce_(key[0], key[1], true);
  ce_(key[2], key[3], false);
  for (int size = 4; size <= n; size <<= 1) {
    bool asc = ((e0 & size) == 0);
    for (int stride = size >> 1; stride >= 256; stride >>= 1) {
#pragma unroll
      for (int j = 0; j < 4; ++j) lds[e0 + j] = key[j];
      __syncthreads();
      bool lower = ((e0 & stride) == 0);
#pragma unroll
      for (int j = 0; j < 4; ++j)
        key[j] = pick_(key[j], lds[(e0 + j) ^ stride], lower, asc);
      __syncthreads();
    }
    int s0 = ((size >> 1) < 256) ? (size >> 1) : 128;
    for (int stride = s0; stride >= 4; stride >>= 1) {
      int m = stride >> 2;
      bool lower = ((t & m) == 0);
#pragma unroll
      for (int j = 0; j < 4; ++j) {
        unsigned long long o = __shfl_xor(key[j], m, 64);
        key[j] = pick_(key[j], o, lower, asc);
      }
    }
    ce_(key[0], key[2], asc);
    ce_(key[1], key[3], asc);
    ce_(key[0], key[1], asc);
    ce_(key[2], key[3], asc);
  }
  int kk = n >> 1;
#pragma unroll
  for (int j = 0; j < 4; ++j) {
    int e = e0 + j;
    int idx = (int)(key[j] & 0xffffffffu);
    if (e < kk) perm[e] = idx;
    if (inv) inv[idx] = (e < kk) ? e : -1;
  }
}

__global__ void k_segsum(const float* __restrict__ h, const int* __restrict__ batch,
                         float* __restrict__ g, int n) {
  int c = threadIdx.x;
  int r0 = blockIdx.x * 32;
  int rend = min(r0 + 32, n);
  float acc = 0.f;
  int cur = batch[r0];
  for (int r = r0; r < rend; ++r) {
    int b = batch[r];
    if (b != cur) { atomicAdd(&g[cur * H + c], acc); acc = 0.f; cur = b; }
    acc += h[(size_t)r * H + c];
  }
  atomicAdd(&g[cur * H + c], acc);
}

__global__ __launch_bounds__(256) void k_head(const float* __restrict__ g,
    const float* __restrict__ lins_w, const float* __restrict__ lins_b,
    const float* __restrict__ bn_g, const float* __restrict__ bn_b,
    const float* __restrict__ out_w, const float* __restrict__ out_b,
    float* __restrict__ out) {
  __shared__ float a[NG * H], b[NG * H];
  int tid = threadIdx.x;
  const float inv = 1.0f / sqrtf(1.0f + 1e-5f);
  for (int i = tid; i < NG * H; i += 256) a[i] = g[i];
  __syncthreads();
  for (int L = 0; L < 3; ++L) {
    for (int i = tid; i < NG * H; i += 256) {
      int c = i & 127;
      b[i] = a[i] * (bn_g[L * H + c] * inv) + bn_b[L * H + c];
    }
    __syncthreads();
    for (int i = tid; i < NG * H; i += 256) {
      int r = i >> 7, c = i & 127;
      float s = lins_b[L * H + c];
      for (int k2 = 0; k2 < H; ++k2) s += b[r * H + k2] * lins_w[(size_t)L * H * H + k2 * H + c];
      a[i] = tanhf(s);
    }
    __syncthreads();
  }
  for (int i = tid; i < NG * H; i += 256) {
    int c = i & 127;
    b[i] = a[i] * (bn_g[3 * H + c] * inv) + bn_b[3 * H + c];
  }
  __syncthreads();
  for (int i = tid; i < NG * 32; i += 256) {
    int r = i >> 5, o = i & 31;
    float s = out_b[o];
    for (int k2 = 0; k2 < H; ++k2) s += b[r * H + k2] * out_w[k2 * 32 + o];
    out[i] = s;
  }
}

extern "C" void kernel_launch(void* const* d_in, const int* in_sizes, int n_in,
                              void* d_out, int out_size, void* d_ws, size_t ws_size,
                              hipStream_t stream) {
  const float* x       = (const float*)d_in[0];
  const int*   ei      = (const int*)d_in[1];
  const int*   batch   = (const int*)d_in[2];
  const float* conv0_w = (const float*)d_in[3];
  const float* conv0_b = (const float*)d_in[4];
  const float* down_w  = (const float*)d_in[5];
  const float* down_b  = (const float*)d_in[6];
  const float* pool_w  = (const float*)d_in[7];
  const float* up_w    = (const float*)d_in[8];
  const float* up_b    = (const float*)d_in[9];
  const float* lins_w  = (const float*)d_in[10];
  const float* lins_b  = (const float*)d_in[11];
  const float* bn_g    = (const float*)d_in[12];
  const float* bn_b    = (const float*)d_in[13];
  const float* out_w   = (const float*)d_in[14];
  const float* out_b   = (const float*)d_in[15];
  int E = in_sizes[1] / 2;

  char* p = (char*)d_ws;
  auto alloc = [&](size_t bytes) {
    char* r = p;
    p += (bytes + 255) & ~(size_t)255;
    return r;
  };
  unsigned short* A1b  = (unsigned short*)alloc((size_t)2048 * 2048 * 2);
  unsigned short* P    = (unsigned short*)alloc((size_t)1024 * 2048 * 2);
  unsigned short* YT   = (unsigned short*)alloc((size_t)128 * 4096 * 2);
  float*          A2m  = (float*)alloc((size_t)1024 * 1024 * 4);
  float*          A3   = (float*)alloc((size_t)512 * 512 * 4);
  float*          part = (float*)alloc((size_t)8 * 2048 * H * 4);
  int* cnt    = (int*)alloc(4096 * 4);
  int* cursor = (int*)alloc(4096 * 4);
  int* rowptr = (int*)alloc(4100 * 4);
  int* colidx = (int*)alloc((size_t)E * 4);
  int* inv0   = (int*)alloc(4096 * 4);
  int* inv1   = (int*)alloc(2048 * 4);
  int* inv2   = (int*)alloc(1024 * 4);
  float* dv0  = (float*)alloc(4096 * 4);
  float* dv1  = (float*)alloc(2048 * 4);
  float* dv2  = (float*)alloc(1024 * 4);
  float* dv3  = (float*)alloc(512 * 4);
  int* perm0  = (int*)alloc(2048 * 4);
  int* perm1  = (int*)alloc(1024 * 4);
  int* perm2  = (int*)alloc(512 * 4);
  float* score = (float*)alloc(4096 * 4);
  float* h0 = (float*)alloc((size_t)4096 * H * 4);
  float* h1 = (float*)alloc((size_t)2048 * H * 4);
  float* h2 = (float*)alloc((size_t)1024 * H * 4);
  float* h3 = (float*)alloc((size_t)512 * H * 4);
  float* t2 = (float*)alloc((size_t)4096 * H * 4);
  float* hu = (float*)alloc((size_t)4096 * H * 4);
  float* g  = (float*)alloc(NG * H * 4);

  // dense gcn, fp32 VALU path (n<=1024)
  auto gcn = [&](const float* A, const float* Y, const float* dvv,
                 const float* bias, float* Out, int nn, int relu) {
    const int nch = 8;
    int KC = nn / nch;
    k_gcn_part<<<dim3(nn / 64, nch), 256, 0, stream>>>(A, Y, part, nn, KC);
    k_gcn_fin<<<nn / 8, 256, 0, stream>>>(part, Y, dvv, bias, Out, nn, nch, relu);
  };
  // dense gcn, bf16 MFMA path with hi/lo Y split (n=2048, A=A1b exact bf16)
  auto gcn_mfma = [&](const unsigned short* Ab, const float* Y, const float* dvv,
                      const float* bias, float* Out, int nn, int relu) {
    k_cvt_split<<<128, 256, 0, stream>>>(Y, YT, nn);
    k_gcn_mfma<<<dim3(nn / 64, 4), 256, 0, stream>>>(Ab, YT, part, nn, (2 * nn) / 4);
    k_gcn_fin<<<nn / 8, 256, 0, stream>>>(part, Y, dvv, bias, Out, nn, 4, relu);
  };

  // ---- CSR build ----
  hipMemsetAsync(cnt, 0, 4096 * 4, stream);
  hipMemsetAsync(cursor, 0, 4096 * 4, stream);
  k_hist<<<(E + 255) / 256, 256, 0, stream>>>(ei, E, cnt);
  k_scan<<<1, 1024, 0, stream>>>(cnt, rowptr, 4096);
  k_fill<<<(E + 255) / 256, 256, 0, stream>>>(ei, E, rowptr, cursor, colidx);
  k_dvcnt<<<4096 / 256, 256, 0, stream>>>(cnt, dv0, 4096);

  // ---- conv0 (sparse) ----
  k_xw<0><<<4096 / 64, 256, 0, stream>>>(x, conv0_w, dv0, nullptr, nullptr, t2, 4096, 64);
  k_spmm_fin<<<1024, 256, 0, stream>>>(rowptr, colidx, t2, dv0, conv0_b, h0, 4096, 1);

  // ---- level 0 pooling (4096 -> 2048): row-wise sparse ATA -> bf16 + dv1 ----
  k_score<<<1024, 256, 0, stream>>>(h0, pool_w, score, 4096);
  k_topk<12><<<1, 1024, 0, stream>>>(score, perm0, inv0);
  k_ata_rows<<<2048, 256, 0, stream>>>(rowptr, colidx, perm0, inv0, A1b, dv1, 2048);
  k_xw<1><<<2048 / 64, 256, 0, stream>>>(h0, down_w, dv1, perm0, score, t2, 2048, 128);
  gcn_mfma(A1b, t2, dv1, down_b, h1, 2048, 1);

  // ---- level 1 pooling (2048 -> 1024): bf16 MFMA ATA ----
  k_score<<<512, 256, 0, stream>>>(h1, pool_w + H, score, 2048);
  k_topk<11><<<1, 512, 0, stream>>>(score, perm1, inv1);
  k_gather<<<1024, 256, 0, stream>>>(A1b, perm1, P, 2048, 1024);
  k_ata_mfma<<<dim3(16, 16), 256, 0, stream>>>(P, A2m, 2048, 1024);
  k_deg<<<1024 / 4, 256, 0, stream>>>(A2m, 1024, dv2);
  k_xw<1><<<1024 / 64, 256, 0, stream>>>(h1, down_w + (size_t)H * H, dv2, perm1, score, t2, 1024, 128);
  gcn(A2m, t2, dv2, down_b + H, h2, 1024, 1);

  // ---- level 2 pooling (1024 -> 512): fp32 split-K ATA ----
  k_score<<<256, 256, 0, stream>>>(h2, pool_w + 2 * H, score, 1024);
  k_topk<10><<<1, 256, 0, stream>>>(score, perm2, inv2);
  hipMemsetAsync(A3, 0, (size_t)512 * 512 * 4, stream);
  k_ata_sk<<<dim3(8, 8, 8), 256, 0, stream>>>(A2m, perm2, A3, 1024, 512, 128);
  k_deg<<<512 / 4, 256, 0, stream>>>(A3, 512, dv3);
  k_xw<1><<<512 / 64, 256, 0, stream>>>(h2, down_w + (size_t)2 * H * H, dv3, perm2, score, t2, 512, 128);
  gcn(A3, t2, dv3, down_b + 2 * H, h3, 512, 1);

  // ---- up path (skip fused into xw) ----
  k_xw<2><<<1024 / 64, 256, 0, stream>>>(h2, up_w, dv2, inv2, h3, t2, 1024, 128);
  gcn(A2m, t2, dv2, up_b, hu, 1024, 1);

  k_xw<2><<<2048 / 64, 256, 0, stream>>>(h1, up_w + (size_t)H * H, dv1, inv1, hu, t2, 2048, 128);
  gcn_mfma(A1b, t2, dv1, up_b + H, hu, 2048, 1);

  k_xw<2><<<4096 / 64, 256, 0, stream>>>(h0, up_w + (size_t)2 * H * H, dv0, inv0, hu, t2, 4096, 128);
  k_spmm_fin<<<1024, 256, 0, stream>>>(rowptr, colidx, t2, dv0, up_b + 2 * H, hu, 4096, 0);

  // ---- pool + head ----
  hipMemsetAsync(g, 0, NG * H * 4, stream);
  k_segsum<<<4096 / 32, 128, 0, stream>>>(hu, batch, g, 4096);
  k_head<<<1, 256, 0, stream>>>(g, lins_w, lins_b, bn_g, bn_b, out_w, out_b, (float*)d_out);
}

// Round 9
// 523.981 us; speedup vs baseline: 8.0803x; 1.0109x over previous
//
#include <hip/hip_runtime.h>
#include <math.h>

#define H 128
#define NG 8

typedef __attribute__((ext_vector_type(8))) short bf16x8;
typedef __attribute__((ext_vector_type(8))) unsigned short ushort8;
typedef __attribute__((ext_vector_type(4))) float f32x4;

static __device__ __forceinline__ float b2f(unsigned short u) {
  union { unsigned int i; float f; } v;
  v.i = ((unsigned int)u) << 16;
  return v.f;
}
static __device__ __forceinline__ unsigned short f2b(float f) {
  return (unsigned short)(__float_as_uint(f) >> 16);  // truncation; exact for small ints
}

// ---------------- CSR build ----------------
__global__ void k_hist(const int* __restrict__ ei, int E, int* __restrict__ cnt) {
  int e = blockIdx.x * 256 + threadIdx.x;
  if (e >= E) return;
  atomicAdd(&cnt[ei[E + e]], 1);
}

// scan + dv0 = rsqrt(cnt+2) fused
__global__ __launch_bounds__(1024) void k_scan(const int* __restrict__ cnt,
                                               int* __restrict__ rowptr,
                                               float* __restrict__ dv, int n) {
  __shared__ int sums[1024];
  int tid = threadIdx.x;
  int base = tid * 4;
  int v0 = 0, v1 = 0, v2 = 0, v3 = 0;
  if (base < n) { v0 = cnt[base]; v1 = cnt[base + 1]; v2 = cnt[base + 2]; v3 = cnt[base + 3]; }
  int s = v0 + v1 + v2 + v3;
  sums[tid] = s;
  __syncthreads();
  for (int off = 1; off < 1024; off <<= 1) {
    int t = (tid >= off) ? sums[tid - off] : 0;
    __syncthreads();
    sums[tid] += t;
    __syncthreads();
  }
  int excl = sums[tid] - s;
  if (base < n) {
    rowptr[base] = excl;
    rowptr[base + 1] = excl + v0;
    rowptr[base + 2] = excl + v0 + v1;
    rowptr[base + 3] = excl + v0 + v1 + v2;
    dv[base] = rsqrtf((float)v0 + 2.0f);
    dv[base + 1] = rsqrtf((float)v1 + 2.0f);
    dv[base + 2] = rsqrtf((float)v2 + 2.0f);
    dv[base + 3] = rsqrtf((float)v3 + 2.0f);
  }
  if (tid == 1023) rowptr[n] = sums[1023];
}

__global__ void k_fill(const int* __restrict__ ei, int E, const int* __restrict__ rowptr,
                       int* __restrict__ cursor, int* __restrict__ colidx) {
  int e = blockIdx.x * 256 + threadIdx.x;
  if (e >= E) return;
  int r = ei[E + e], c = ei[e];
  int p = atomicAdd(&cursor[r], 1);
  colidx[rowptr[r] + p] = c;
}

// d[i] = rsqrt(rowsum(A)+2), dense fp32 (level-2 only)
__global__ void k_deg(const float* __restrict__ A, int n, float* __restrict__ dv) {
  int row = blockIdx.x * (blockDim.x >> 6) + (threadIdx.x >> 6);
  int lane = threadIdx.x & 63;
  if (row >= n) return;
  float s = 0.f;
  const float* arow = A + (size_t)row * n;
  for (int j = lane; j < n; j += 64) s += arow[j];
#pragma unroll
  for (int o = 32; o > 0; o >>= 1) s += __shfl_down(s, o);
  if (lane == 0) dv[row] = rsqrtf(s + 2.0f);
}

// Y[r,c] = d(r) * sum_k X'[r,k] W[k,c]; RS: dv[] holds rowsum -> d=rsqrt(rs+2)
// MODE 0: X'=X ; 1 (pool): X[perm[r]]*score ; 2 (skip): X[r]+prev[inv[r]]
template <int MODE, int RS>
__global__ __launch_bounds__(256) void k_xw(const float* __restrict__ X,
                                            const float* __restrict__ W,
                                            const float* __restrict__ dv,
                                            const int* __restrict__ idx,
                                            const float* __restrict__ aux,
                                            float* __restrict__ Y, int n, int F) {
  __shared__ float Xs[64][36];
  __shared__ float Ws[32][132];
  __shared__ int ridx[64];
  __shared__ float rscl[64];
  int tid = threadIdx.x;
  int rowBase = blockIdx.x * 64;
  if (MODE == 1) {
    if (tid < 64) {
      int pp = idx[rowBase + tid];
      ridx[tid] = pp;
      rscl[tid] = aux[pp];
    }
  } else if (MODE == 2) {
    if (tid < 64) ridx[tid] = idx[rowBase + tid];
  }
  if (MODE != 0) __syncthreads();
  int r0 = (tid >> 5) << 3;
  int c0 = (tid & 31) << 2;
  float acc[8][4] = {};
  for (int k0 = 0; k0 < F; k0 += 32) {
#pragma unroll
    for (int it = 0, e = tid; it < 8; ++it, e += 256) {
      int ii = e >> 5, kk = e & 31;
      int gk = k0 + kk;
      float v;
      if (MODE == 0) {
        v = X[(size_t)(rowBase + ii) * F + gk];
      } else if (MODE == 1) {
        v = X[(size_t)ridx[ii] * F + gk] * rscl[ii];
      } else {
        v = X[(size_t)(rowBase + ii) * F + gk];
        int iv = ridx[ii];
        if (iv >= 0) v += aux[(size_t)iv * H + gk];
      }
      Xs[ii][kk] = v;
    }
#pragma unroll
    for (int it = 0, e = tid; it < 4; ++it, e += 256) {
      int kk = e >> 5, cc4 = e & 31;
      *(float4*)&Ws[kk][cc4 << 2] = *(const float4*)&W[(size_t)(k0 + kk) * H + (cc4 << 2)];
    }
    __syncthreads();
#pragma unroll
    for (int kk = 0; kk < 32; kk += 4) {
      float4 a4[8], w4[4];
#pragma unroll
      for (int i = 0; i < 8; ++i) a4[i] = *(const float4*)&Xs[r0 + i][kk];
#pragma unroll
      for (int s = 0; s < 4; ++s) w4[s] = *(const float4*)&Ws[kk + s][c0];
#pragma unroll
      for (int i = 0; i < 8; ++i) {
        float av[4] = {a4[i].x, a4[i].y, a4[i].z, a4[i].w};
#pragma unroll
        for (int s = 0; s < 4; ++s) {
          float wv[4] = {w4[s].x, w4[s].y, w4[s].z, w4[s].w};
#pragma unroll
          for (int j = 0; j < 4; ++j) acc[i][j] = fmaf(av[s], wv[j], acc[i][j]);
        }
      }
    }
    __syncthreads();
  }
#pragma unroll
  for (int i = 0; i < 8; ++i) {
    int row = rowBase + r0 + i;
    float d = RS ? rsqrtf(dv[row] + 2.0f) : dv[row];
    *(float4*)&Y[(size_t)row * H + c0] =
        make_float4(d * acc[i][0], d * acc[i][1], d * acc[i][2], d * acc[i][3]);
  }
}

// sparse GCN epilogue; lane covers cols 2*lane, 2*lane+1 (float2 loads)
__global__ void k_spmm_fin(const int* __restrict__ rowptr, const int* __restrict__ colidx,
                           const float* __restrict__ Y, const float* __restrict__ dv,
                           const float* __restrict__ bias, float* __restrict__ Out,
                           int n, int relu) {
  int row = blockIdx.x * 4 + (threadIdx.x >> 6);
  int lane = threadIdx.x & 63;
  if (row >= n) return;
  int s = rowptr[row], e = rowptr[row + 1];
  int c2 = lane * 2;
  float a0 = 0.f, a1 = 0.f;
  int i = s;
  for (; i + 1 < e; i += 2) {
    int cA = colidx[i], cB = colidx[i + 1];
    float2 yA = *(const float2*)&Y[(size_t)cA * H + c2];
    float2 yB = *(const float2*)&Y[(size_t)cB * H + c2];
    a0 += yA.x + yB.x;
    a1 += yA.y + yB.y;
  }
  if (i < e) {
    int c = colidx[i];
    float2 y = *(const float2*)&Y[(size_t)c * H + c2];
    a0 += y.x;
    a1 += y.y;
  }
  float d = dv[row];
  float2 yr = *(const float2*)&Y[(size_t)row * H + c2];
  float v0 = d * (a0 + 2.0f * yr.x) + bias[c2];
  float v1 = d * (a1 + 2.0f * yr.y) + bias[c2 + 1];
  if (relu) { v0 = fmaxf(v0, 0.f); v1 = fmaxf(v1, 0.f); }
  float2 o = make_float2(v0, v1);
  *(float2*)&Out[(size_t)row * H + c2] = o;
}

// level-0 ATA, row-wise (LDS int accumulators) -> bf16 row + dv fused
__global__ __launch_bounds__(256) void k_ata_rows(const int* __restrict__ rowptr,
                                                  const int* __restrict__ colidx,
                                                  const int* __restrict__ perm,
                                                  const int* __restrict__ inv,
                                                  unsigned short* __restrict__ Ab,
                                                  float* __restrict__ dv, int kdim) {
  __shared__ int acc[2048];
  __shared__ int wsum[4];
  int i = blockIdx.x;
  int tid = threadIdx.x;
  for (int j = tid; j < kdim; j += 256) acc[j] = 0;
  __syncthreads();
  int p = perm[i];
  int s = rowptr[p], e = rowptr[p + 1];
  int deg = e - s;
  int wave = tid >> 6, lane = tid & 63;
  for (int q = wave; q <= deg; q += 4) {
    int kn = (q < deg) ? colidx[s + q] : p;
    int s2 = rowptr[kn], e2 = rowptr[kn + 1];
    for (int idx = s2 + lane; idx <= e2; idx += 64) {
      int j = (idx < e2) ? colidx[idx] : kn;
      int ii = inv[j];
      if (ii >= 0) atomicAdd(&acc[ii], 1);
    }
  }
  __syncthreads();
  int rs = 0;
  {
    int j0 = tid * 8;
    ushort8 v;
#pragma unroll
    for (int q = 0; q < 8; ++q) {
      int j = j0 + q;
      int c = (j == i) ? 0 : acc[j];
      rs += c;
      v[q] = f2b((float)c);
    }
    *(ushort8*)&Ab[(size_t)i * kdim + j0] = v;
  }
#pragma unroll
  for (int o = 32; o > 0; o >>= 1) rs += __shfl_down(rs, o);
  if (lane == 0) wsum[wave] = rs;
  __syncthreads();
  if (tid == 0) dv[i] = rsqrtf((float)(wsum[0] + wsum[1] + wsum[2] + wsum[3]) + 2.0f);
}

// level-1 ATA: C = S_sub @ S_sub^T via bf16 MFMA, gather + (+I) + rowsum fused.
// rowsum pre-zeroed; exact integer sums.
__global__ __launch_bounds__(256) void k_ata_mfma_g(const unsigned short* __restrict__ Ab,
                                                    const int* __restrict__ perm,
                                                    float* __restrict__ C,
                                                    float* __restrict__ rowsum,
                                                    int n, int k) {
  __shared__ __align__(16) unsigned short As[64][64];
  __shared__ __align__(16) unsigned short Bs[64][64];
  __shared__ int pr[64], pc[64];
  int tid = threadIdx.x;
  int w = tid >> 6, ln = tid & 63;
  int l15 = ln & 15, l4 = ln >> 4;
  int br = blockIdx.y, bc = blockIdx.x;
  if (tid < 64) pr[tid] = perm[br * 64 + tid];
  else if (tid < 128) pc[tid - 64] = perm[bc * 64 + (tid - 64)];
  __syncthreads();
  f32x4 acc[4] = {};
  for (int k0 = 0; k0 < n; k0 += 64) {
#pragma unroll
    for (int it = 0; it < 2; ++it) {
      int e = tid + it * 256;
      int row = e >> 3, ch = e & 7;
      int sch = (ch ^ (row & 7)) * 8;
      int base = k0 + ch * 8;
      {
        int p = pr[row];
        ushort8 v = *(const ushort8*)&Ab[(size_t)p * n + base];
#pragma unroll
        for (int q = 0; q < 8; ++q)
          if (base + q == p) v[q] = f2b(b2f(v[q]) + 1.0f);
        *(ushort8*)&As[row][sch] = v;
      }
      {
        int p = pc[row];
        ushort8 v = *(const ushort8*)&Ab[(size_t)p * n + base];
#pragma unroll
        for (int q = 0; q < 8; ++q)
          if (base + q == p) v[q] = f2b(b2f(v[q]) + 1.0f);
        *(ushort8*)&Bs[row][sch] = v;
      }
    }
    __syncthreads();
#pragma unroll
    for (int s = 0; s < 2; ++s) {
      int arow = w * 16 + l15;
      bf16x8 af = *(const bf16x8*)&As[arow][((s * 4 + l4) ^ (arow & 7)) * 8];
#pragma unroll
      for (int f = 0; f < 4; ++f) {
        int brow = f * 16 + l15;
        bf16x8 bfr = *(const bf16x8*)&Bs[brow][((s * 4 + l4) ^ (brow & 7)) * 8];
        acc[f] = __builtin_amdgcn_mfma_f32_16x16x32_bf16(af, bfr, acc[f], 0, 0, 0);
      }
    }
    __syncthreads();
  }
#pragma unroll
  for (int r = 0; r < 4; ++r) {
    int gi = br * 64 + w * 16 + l4 * 4 + r;
    float part = 0.f;
#pragma unroll
    for (int f = 0; f < 4; ++f) {
      int gj = bc * 64 + f * 16 + l15;
      float v = (gi == gj) ? 0.0f : acc[f][r];
      C[(size_t)gi * k + gj] = v;
      part += v;
    }
#pragma unroll
    for (int m = 8; m >= 1; m >>= 1) part += __shfl_xor(part, m, 64);
    if (l15 == 0) atomicAdd(&rowsum[gi], part);
  }
}

// Y [n][128] fp32 -> YT [128][2n] bf16 hi|lo limbs
__global__ void k_cvt_split(const float* __restrict__ Y, unsigned short* __restrict__ YT, int n) {
  int c = blockIdx.x;
  for (int k0 = threadIdx.x * 8; k0 < n; k0 += 256 * 8) {
    ushort8 hi, lo;
#pragma unroll
    for (int q = 0; q < 8; ++q) {
      float v = Y[(size_t)(k0 + q) * H + c];
      unsigned short h = f2b(v);
      hi[q] = h;
      lo[q] = f2b(v - b2f(h));
    }
    *(ushort8*)&YT[(size_t)c * (2 * n) + k0] = hi;
    *(ushort8*)&YT[(size_t)c * (2 * n) + n + k0] = lo;
  }
}

// Partial A@Y via bf16 MFMA over virtual K=2n (hi|lo limbs). Split-K private partials.
__global__ __launch_bounds__(256) void k_gcn_mfma(const unsigned short* __restrict__ A,
                                                  const unsigned short* __restrict__ YT,
                                                  float* __restrict__ Part, int n, int VK) {
  __shared__ __align__(16) unsigned short As[64][64];
  __shared__ __align__(16) unsigned short Bs[128][64];
  int tid = threadIdx.x;
  int w = tid >> 6, ln = tid & 63;
  int l15 = ln & 15, l4 = ln >> 4;
  int rowBase = blockIdx.x * 64;
  float* out = Part + (size_t)blockIdx.y * n * H;
  f32x4 acc[8] = {};
  int vk0s = blockIdx.y * VK;
  for (int vk0 = vk0s; vk0 < vk0s + VK; vk0 += 64) {
    int ka = vk0 & (n - 1);
#pragma unroll
    for (int it = 0; it < 2; ++it) {
      int e = tid + it * 256;
      int row = e >> 3, ch = e & 7;
      int sch = (ch ^ (row & 7)) * 8;
      *(ushort8*)&As[row][sch] = *(const ushort8*)&A[(size_t)(rowBase + row) * n + ka + ch * 8];
    }
#pragma unroll
    for (int it = 0; it < 4; ++it) {
      int e = tid + it * 256;
      int row = e >> 3, ch = e & 7;
      int sch = (ch ^ (row & 7)) * 8;
      *(ushort8*)&Bs[row][sch] = *(const ushort8*)&YT[(size_t)row * (2 * n) + vk0 + ch * 8];
    }
    __syncthreads();
#pragma unroll
    for (int s = 0; s < 2; ++s) {
      int arow = w * 16 + l15;
      bf16x8 af = *(const bf16x8*)&As[arow][((s * 4 + l4) ^ (arow & 7)) * 8];
#pragma unroll
      for (int f = 0; f < 8; ++f) {
        int brow = f * 16 + l15;
        bf16x8 bfr = *(const bf16x8*)&Bs[brow][((s * 4 + l4) ^ (brow & 7)) * 8];
        acc[f] = __builtin_amdgcn_mfma_f32_16x16x32_bf16(af, bfr, acc[f], 0, 0, 0);
      }
    }
    __syncthreads();
  }
#pragma unroll
  for (int f = 0; f < 8; ++f) {
#pragma unroll
    for (int r = 0; r < 4; ++r) {
      int row = rowBase + w * 16 + l4 * 4 + r;
      out[(size_t)row * H + f * 16 + l15] = acc[f][r];
    }
  }
}

// dense fp32 ATA split-K (level 2 only)
__global__ __launch_bounds__(256) void k_ata_sk(const float* __restrict__ A,
                                                const int* __restrict__ perm,
                                                float* __restrict__ C, int n, int k, int CK) {
  int bc = blockIdx.x, br = blockIdx.y;
  if (br > bc) return;
  __shared__ float As[64][36];
  __shared__ float Bs[64][36];
  __shared__ int pr[64], pc[64];
  int tid = threadIdx.x;
  if (tid < 64) pr[tid] = perm[br * 64 + tid];
  else if (tid < 128) pc[tid - 64] = perm[bc * 64 + (tid - 64)];
  __syncthreads();
  int ty = tid >> 4;
  int tx = tid & 15;
  float acc[4][4] = {};
  int k0s = blockIdx.z * CK;
  for (int k0 = k0s; k0 < k0s + CK; k0 += 32) {
#pragma unroll
    for (int it = 0, e = tid; it < 8; ++it, e += 256) {
      int ii = e >> 5, kk = e & 31;
      int gk = k0 + kk;
      int p = pr[ii];
      As[ii][kk] = A[(size_t)p * n + gk] + ((p == gk) ? 1.0f : 0.0f);
      p = pc[ii];
      Bs[ii][kk] = A[(size_t)p * n + gk] + ((p == gk) ? 1.0f : 0.0f);
    }
    __syncthreads();
#pragma unroll
    for (int kk = 0; kk < 32; kk += 4) {
      float4 a4[4], b4[4];
#pragma unroll
      for (int i = 0; i < 4; ++i) a4[i] = *(const float4*)&As[ty + 16 * i][kk];
#pragma unroll
      for (int j = 0; j < 4; ++j) b4[j] = *(const float4*)&Bs[tx + 16 * j][kk];
#pragma unroll
      for (int i = 0; i < 4; ++i) {
        float av[4] = {a4[i].x, a4[i].y, a4[i].z, a4[i].w};
#pragma unroll
        for (int j = 0; j < 4; ++j) {
          float bv[4] = {b4[j].x, b4[j].y, b4[j].z, b4[j].w};
#pragma unroll
          for (int s = 0; s < 4; ++s) acc[i][j] = fmaf(av[s], bv[s], acc[i][j]);
        }
      }
    }
    __syncthreads();
  }
  bool diag = (br == bc);
#pragma unroll
  for (int i = 0; i < 4; ++i) {
    int gi = br * 64 + ty + 16 * i;
#pragma unroll
    for (int j = 0; j < 4; ++j) {
      int gj = bc * 64 + tx + 16 * j;
      if (gi == gj) continue;
      float v = acc[i][j];
      atomicAdd(&C[(size_t)gi * k + gj], v);
      if (!diag) atomicAdd(&C[(size_t)gj * k + gi], v);
    }
  }
}

// fp32 dense GCN partial (split-K, private partials)
__global__ __launch_bounds__(256) void k_gcn_part(const float* __restrict__ A,
                                                  const float* __restrict__ Y,
                                                  float* __restrict__ Part,
                                                  int n, int KC) {
  __shared__ float As[64][36];
  __shared__ float Ys[32][132];
  int tid = threadIdx.x;
  int r0 = (tid >> 5) << 3;
  int c0 = (tid & 31) << 2;
  size_t rowBase = (size_t)blockIdx.x * 64;
  int k0s = blockIdx.y * KC;
  float* out = Part + (size_t)blockIdx.y * n * H;
  float acc[8][4] = {};
  for (int k0 = k0s; k0 < k0s + KC; k0 += 32) {
#pragma unroll
    for (int it = 0, e = tid; it < 8; ++it, e += 256) {
      int ii = e >> 5, kk = e & 31;
      As[ii][kk] = A[(rowBase + ii) * (size_t)n + k0 + kk];
    }
#pragma unroll
    for (int it = 0, e = tid; it < 4; ++it, e += 256) {
      int kk = e >> 5, cc4 = e & 31;
      *(float4*)&Ys[kk][cc4 << 2] = *(const float4*)&Y[(size_t)(k0 + kk) * H + (cc4 << 2)];
    }
    __syncthreads();
#pragma unroll
    for (int kk = 0; kk < 32; kk += 4) {
      float4 a4[8], y4[4];
#pragma unroll
      for (int i = 0; i < 8; ++i) a4[i] = *(const float4*)&As[r0 + i][kk];
#pragma unroll
      for (int s = 0; s < 4; ++s) y4[s] = *(const float4*)&Ys[kk + s][c0];
#pragma unroll
      for (int i = 0; i < 8; ++i) {
        float av[4] = {a4[i].x, a4[i].y, a4[i].z, a4[i].w};
#pragma unroll
        for (int s = 0; s < 4; ++s) {
          float yv[4] = {y4[s].x, y4[s].y, y4[s].z, y4[s].w};
#pragma unroll
          for (int j = 0; j < 4; ++j) acc[i][j] = fmaf(av[s], yv[j], acc[i][j]);
        }
      }
    }
    __syncthreads();
  }
#pragma unroll
  for (int i = 0; i < 8; ++i) {
    size_t row = rowBase + r0 + i;
    *(float4*)&out[row * H + c0] = make_float4(acc[i][0], acc[i][1], acc[i][2], acc[i][3]);
  }
}

// Out = act(d .* (sum_c Part[c] + 2Y) + bias); RS: dv holds rowsum
template <int RS>
__global__ void k_gcn_fin(const float* __restrict__ Part, const float* __restrict__ Y,
                          const float* __restrict__ dv, const float* __restrict__ bias,
                          float* __restrict__ Out, int n, int nch, int relu) {
  int i4 = blockIdx.x * 256 + threadIdx.x;
  if (i4 * 4 >= n * H) return;
  int row = i4 >> 5, c4 = (i4 & 31) * 4;
  size_t stride = (size_t)n * H;
  float4 s = *(const float4*)&Part[i4 * 4];
  for (int c = 1; c < nch; ++c) {
    float4 p = *(const float4*)&Part[c * stride + i4 * 4];
    s.x += p.x; s.y += p.y; s.z += p.z; s.w += p.w;
  }
  float4 y = *(const float4*)&Y[i4 * 4];
  float d = RS ? rsqrtf(dv[row] + 2.0f) : dv[row];
  float4 v;
  v.x = d * (s.x + 2.0f * y.x) + bias[c4];
  v.y = d * (s.y + 2.0f * y.y) + bias[c4 + 1];
  v.z = d * (s.z + 2.0f * y.z) + bias[c4 + 2];
  v.w = d * (s.w + 2.0f * y.w) + bias[c4 + 3];
  if (relu) {
    v.x = fmaxf(v.x, 0.f); v.y = fmaxf(v.y, 0.f);
    v.z = fmaxf(v.z, 0.f); v.w = fmaxf(v.w, 0.f);
  }
  *(float4*)&Out[i4 * 4] = v;
}

// score = tanh((h@w)/||w||)
__global__ void k_score(const float* __restrict__ h, const float* __restrict__ w,
                        float* __restrict__ score, int n) {
  __shared__ float wn;
  int tid = threadIdx.x;
  if (tid < 64) {
    float s = w[tid] * w[tid] + w[tid + 64] * w[tid + 64];
#pragma unroll
    for (int o = 32; o > 0; o >>= 1) s += __shfl_down(s, o);
    if (tid == 0) wn = sqrtf(s);
  }
  __syncthreads();
  int row = blockIdx.x * 4 + (tid >> 6);
  int lane = tid & 63;
  if (row >= n) return;
  float s = h[(size_t)row * H + lane] * w[lane] + h[(size_t)row * H + lane + 64] * w[lane + 64];
#pragma unroll
  for (int o = 32; o > 0; o >>= 1) s += __shfl_down(s, o);
  if (lane == 0) score[row] = tanhf(s / wn);
}

// ---- hybrid bitonic top-k ----
static __device__ __forceinline__ void ce_(unsigned long long& x, unsigned long long& y, bool asc) {
  if ((x < y) != asc) { unsigned long long t = x; x = y; y = t; }
}
static __device__ __forceinline__ unsigned long long pick_(unsigned long long a,
                                                           unsigned long long b,
                                                           bool lower, bool asc) {
  unsigned long long lo = (a < b) ? a : b;
  unsigned long long hi = (a < b) ? b : a;
  return (lower == asc) ? lo : hi;
}

template <int LOGN>
__global__ __launch_bounds__(1024) void k_topk(const float* __restrict__ score,
                                               int* __restrict__ perm,
                                               int* __restrict__ inv) {
  const int n = 1 << LOGN;
  __shared__ unsigned long long lds[1 << LOGN];
  int t = threadIdx.x;
  int e0 = t * 4;
  unsigned long long key[4];
#pragma unroll
  for (int j = 0; j < 4; ++j) {
    unsigned u = __float_as_uint(score[e0 + j]);
    u = (u & 0x80000000u) ? ~u : (u | 0x80000000u);
    u = ~u;
    key[j] = (((unsigned long long)u) << 32) | (unsigned)(e0 + j);
  }
  ce_(key[0], key[1], true);
  ce_(key[2], key[3], false);
  for (int size = 4; size <= n; size <<= 1) {
    bool asc = ((e0 & size) == 0);
    for (int stride = size >> 1; stride >= 256; stride >>= 1) {
#pragma unroll
      for (int j = 0; j < 4; ++j) lds[e0 + j] = key[j];
      __syncthreads();
      bool lower = ((e0 & stride) == 0);
#pragma unroll
      for (int j = 0; j < 4; ++j)
        key[j] = pick_(key[j], lds[(e0 + j) ^ stride], lower, asc);
      __syncthreads();
    }
    int s0 = ((size >> 1) < 256) ? (size >> 1) : 128;
    for (int stride = s0; stride >= 4; stride >>= 1) {
      int m = stride >> 2;
      bool lower = ((t & m) == 0);
#pragma unroll
      for (int j = 0; j < 4; ++j) {
        unsigned long long o = __shfl_xor(key[j], m, 64);
        key[j] = pick_(key[j], o, lower, asc);
      }
    }
    ce_(key[0], key[2], asc);
    ce_(key[1], key[3], asc);
    ce_(key[0], key[1], asc);
    ce_(key[2], key[3], asc);
  }
  int kk = n >> 1;
#pragma unroll
  for (int j = 0; j < 4; ++j) {
    int e = e0 + j;
    int idx = (int)(key[j] & 0xffffffffu);
    if (e < kk) perm[e] = idx;
    if (inv) inv[idx] = (e < kk) ? e : -1;
  }
}

__global__ void k_segsum(const float* __restrict__ h, const int* __restrict__ batch,
                         float* __restrict__ g, int n) {
  int c = threadIdx.x;
  int r0 = blockIdx.x * 32;
  int rend = min(r0 + 32, n);
  float acc = 0.f;
  int cur = batch[r0];
  for (int r = r0; r < rend; ++r) {
    int b = batch[r];
    if (b != cur) { atomicAdd(&g[cur * H + c], acc); acc = 0.f; cur = b; }
    acc += h[(size_t)r * H + c];
  }
  atomicAdd(&g[cur * H + c], acc);
}

__global__ __launch_bounds__(256) void k_head(const float* __restrict__ g,
    const float* __restrict__ lins_w, const float* __restrict__ lins_b,
    const float* __restrict__ bn_g, const float* __restrict__ bn_b,
    const float* __restrict__ out_w, const float* __restrict__ out_b,
    float* __restrict__ out) {
  __shared__ float a[NG * H], b[NG * H];
  int tid = threadIdx.x;
  const float inv = 1.0f / sqrtf(1.0f + 1e-5f);
  for (int i = tid; i < NG * H; i += 256) a[i] = g[i];
  __syncthreads();
  for (int L = 0; L < 3; ++L) {
    for (int i = tid; i < NG * H; i += 256) {
      int c = i & 127;
      b[i] = a[i] * (bn_g[L * H + c] * inv) + bn_b[L * H + c];
    }
    __syncthreads();
    for (int i = tid; i < NG * H; i += 256) {
      int r = i >> 7, c = i & 127;
      float s = lins_b[L * H + c];
      for (int k2 = 0; k2 < H; ++k2) s += b[r * H + k2] * lins_w[(size_t)L * H * H + k2 * H + c];
      a[i] = tanhf(s);
    }
    __syncthreads();
  }
  for (int i = tid; i < NG * H; i += 256) {
    int c = i & 127;
    b[i] = a[i] * (bn_g[3 * H + c] * inv) + bn_b[3 * H + c];
  }
  __syncthreads();
  for (int i = tid; i < NG * 32; i += 256) {
    int r = i >> 5, o = i & 31;
    float s = out_b[o];
    for (int k2 = 0; k2 < H; ++k2) s += b[r * H + k2] * out_w[k2 * 32 + o];
    out[i] = s;
  }
}

extern "C" void kernel_launch(void* const* d_in, const int* in_sizes, int n_in,
                              void* d_out, int out_size, void* d_ws, size_t ws_size,
                              hipStream_t stream) {
  const float* x       = (const float*)d_in[0];
  const int*   ei      = (const int*)d_in[1];
  const int*   batch   = (const int*)d_in[2];
  const float* conv0_w = (const float*)d_in[3];
  const float* conv0_b = (const float*)d_in[4];
  const float* down_w  = (const float*)d_in[5];
  const float* down_b  = (const float*)d_in[6];
  const float* pool_w  = (const float*)d_in[7];
  const float* up_w    = (const float*)d_in[8];
  const float* up_b    = (const float*)d_in[9];
  const float* lins_w  = (const float*)d_in[10];
  const float* lins_b  = (const float*)d_in[11];
  const float* bn_g    = (const float*)d_in[12];
  const float* bn_b    = (const float*)d_in[13];
  const float* out_w   = (const float*)d_in[14];
  const float* out_b   = (const float*)d_in[15];
  int E = in_sizes[1] / 2;

  char* p = (char*)d_ws;
  auto alloc = [&](size_t bytes) {
    char* r = p;
    p += (bytes + 255) & ~(size_t)255;
    return r;
  };
  unsigned short* A1b  = (unsigned short*)alloc((size_t)2048 * 2048 * 2);
  unsigned short* YT   = (unsigned short*)alloc((size_t)128 * 4096 * 2);
  float*          A2m  = (float*)alloc((size_t)1024 * 1024 * 4);
  float*          A3   = (float*)alloc((size_t)512 * 512 * 4);
  float*          part = (float*)alloc((size_t)8 * 2048 * H * 4);
  int* cnt    = (int*)alloc(4096 * 4);
  int* cursor = (int*)alloc(4096 * 4);
  int* rowptr = (int*)alloc(4100 * 4);
  int* colidx = (int*)alloc((size_t)E * 4);
  int* inv0   = (int*)alloc(4096 * 4);
  int* inv1   = (int*)alloc(2048 * 4);
  int* inv2   = (int*)alloc(1024 * 4);
  float* dv0  = (float*)alloc(4096 * 4);
  float* dv1  = (float*)alloc(2048 * 4);
  float* dv2  = (float*)alloc(1024 * 4);   // rowsum form (RS)
  float* dv3  = (float*)alloc(512 * 4);
  int* perm0  = (int*)alloc(2048 * 4);
  int* perm1  = (int*)alloc(1024 * 4);
  int* perm2  = (int*)alloc(512 * 4);
  float* score = (float*)alloc(4096 * 4);
  float* h0 = (float*)alloc((size_t)4096 * H * 4);
  float* h1 = (float*)alloc((size_t)2048 * H * 4);
  float* h2 = (float*)alloc((size_t)1024 * H * 4);
  float* h3 = (float*)alloc((size_t)512 * H * 4);
  float* t2 = (float*)alloc((size_t)4096 * H * 4);
  float* hu = (float*)alloc((size_t)4096 * H * 4);
  float* g  = (float*)alloc(NG * H * 4);

  // fp32 gcn (n<=1024); rs selects rowsum-interpretation of dv
  auto gcn = [&](const float* A, const float* Y, const float* dvv, const float* bias,
                 float* Out, int nn, int relu, bool rs) {
    const int nch = 8;
    int KC = nn / nch;
    k_gcn_part<<<dim3(nn / 64, nch), 256, 0, stream>>>(A, Y, part, nn, KC);
    if (rs)
      k_gcn_fin<1><<<nn / 8, 256, 0, stream>>>(part, Y, dvv, bias, Out, nn, nch, relu);
    else
      k_gcn_fin<0><<<nn / 8, 256, 0, stream>>>(part, Y, dvv, bias, Out, nn, nch, relu);
  };
  // bf16 MFMA gcn with hi/lo Y split (n=2048, A=A1b exact bf16), split-K=8
  auto gcn_mfma = [&](const unsigned short* Ab, const float* Y, const float* dvv,
                      const float* bias, float* Out, int nn, int relu) {
    k_cvt_split<<<128, 256, 0, stream>>>(Y, YT, nn);
    k_gcn_mfma<<<dim3(nn / 64, 8), 256, 0, stream>>>(Ab, YT, part, nn, (2 * nn) / 8);
    k_gcn_fin<0><<<nn / 8, 256, 0, stream>>>(part, Y, dvv, bias, Out, nn, 8, relu);
  };

  // ---- CSR build (scan emits dv0) ----
  hipMemsetAsync(cnt, 0, 4096 * 4, stream);
  hipMemsetAsync(cursor, 0, 4096 * 4, stream);
  k_hist<<<(E + 255) / 256, 256, 0, stream>>>(ei, E, cnt);
  k_scan<<<1, 1024, 0, stream>>>(cnt, rowptr, dv0, 4096);
  k_fill<<<(E + 255) / 256, 256, 0, stream>>>(ei, E, rowptr, cursor, colidx);

  // ---- conv0 (sparse) ----
  k_xw<0, 0><<<4096 / 64, 256, 0, stream>>>(x, conv0_w, dv0, nullptr, nullptr, t2, 4096, 64);
  k_spmm_fin<<<1024, 256, 0, stream>>>(rowptr, colidx, t2, dv0, conv0_b, h0, 4096, 1);

  // ---- level 0 pooling (4096 -> 2048): row-wise sparse ATA -> bf16 + dv1 ----
  k_score<<<1024, 256, 0, stream>>>(h0, pool_w, score, 4096);
  k_topk<12><<<1, 1024, 0, stream>>>(score, perm0, inv0);
  k_ata_rows<<<2048, 256, 0, stream>>>(rowptr, colidx, perm0, inv0, A1b, dv1, 2048);
  k_xw<1, 0><<<2048 / 64, 256, 0, stream>>>(h0, down_w, dv1, perm0, score, t2, 2048, 128);
  gcn_mfma(A1b, t2, dv1, down_b, h1, 2048, 1);

  // ---- level 1 pooling (2048 -> 1024): fused gather+MFMA ATA + rowsum ----
  k_score<<<512, 256, 0, stream>>>(h1, pool_w + H, score, 2048);
  k_topk<11><<<1, 512, 0, stream>>>(score, perm1, inv1);
  hipMemsetAsync(dv2, 0, 1024 * 4, stream);
  k_ata_mfma_g<<<dim3(16, 16), 256, 0, stream>>>(A1b, perm1, A2m, dv2, 2048, 1024);
  k_xw<1, 1><<<1024 / 64, 256, 0, stream>>>(h1, down_w + (size_t)H * H, dv2, perm1, score, t2, 1024, 128);
  gcn(A2m, t2, dv2, down_b + H, h2, 1024, 1, true);

  // ---- level 2 pooling (1024 -> 512): fp32 split-K ATA ----
  k_score<<<256, 256, 0, stream>>>(h2, pool_w + 2 * H, score, 1024);
  k_topk<10><<<1, 256, 0, stream>>>(score, perm2, inv2);
  hipMemsetAsync(A3, 0, (size_t)512 * 512 * 4, stream);
  k_ata_sk<<<dim3(8, 8, 8), 256, 0, stream>>>(A2m, perm2, A3, 1024, 512, 128);
  k_deg<<<512 / 4, 256, 0, stream>>>(A3, 512, dv3);
  k_xw<1, 0><<<512 / 64, 256, 0, stream>>>(h2, down_w + (size_t)2 * H * H, dv3, perm2, score, t2, 512, 128);
  gcn(A3, t2, dv3, down_b + 2 * H, h3, 512, 1, false);

  // ---- up path (skip fused into xw) ----
  k_xw<2, 1><<<1024 / 64, 256, 0, stream>>>(h2, up_w, dv2, inv2, h3, t2, 1024, 128);
  gcn(A2m, t2, dv2, up_b, hu, 1024, 1, true);

  k_xw<2, 0><<<2048 / 64, 256, 0, stream>>>(h1, up_w + (size_t)H * H, dv1, inv1, hu, t2, 2048, 128);
  gcn_mfma(A1b, t2, dv1, up_b + H, hu, 2048, 1);

  k_xw<2, 0><<<4096 / 64, 256, 0, stream>>>(h0, up_w + (size_t)2 * H * H, dv0, inv0, hu, t2, 4096, 128);
  k_spmm_fin<<<1024, 256, 0, stream>>>(rowptr, colidx, t2, dv0, up_b + 2 * H, hu, 4096, 0);

  // ---- pool + head ----
  hipMemsetAsync(g, 0, NG * H * 4, stream);
  k_segsum<<<4096 / 32, 128, 0, stream>>>(hu, batch, g, 4096);
  k_head<<<1, 256, 0, stream>>>(g, lins_w, lins_b, bn_g, bn_b, out_w, out_b, (float*)d_out);
}

// Round 10
// 512.010 us; speedup vs baseline: 8.2692x; 1.0234x over previous
//
#include <hip/hip_runtime.h>
#include <math.h>

#define H 128
#define NG 8

typedef __attribute__((ext_vector_type(8))) short bf16x8;
typedef __attribute__((ext_vector_type(8))) unsigned short ushort8;
typedef __attribute__((ext_vector_type(4))) float f32x4;

static __device__ __forceinline__ float b2f(unsigned short u) {
  union { unsigned int i; float f; } v;
  v.i = ((unsigned int)u) << 16;
  return v.f;
}
static __device__ __forceinline__ unsigned short f2b(float f) {
  return (unsigned short)(__float_as_uint(f) >> 16);  // truncation; exact for small ints
}

// ---------------- CSR build ----------------
__global__ void k_hist(const int* __restrict__ ei, int E, int* __restrict__ cnt) {
  int e = blockIdx.x * 256 + threadIdx.x;
  if (e >= E) return;
  atomicAdd(&cnt[ei[E + e]], 1);
}

// scan + dv0 = rsqrt(cnt+2) fused
__global__ __launch_bounds__(1024) void k_scan(const int* __restrict__ cnt,
                                               int* __restrict__ rowptr,
                                               float* __restrict__ dv, int n) {
  __shared__ int sums[1024];
  int tid = threadIdx.x;
  int base = tid * 4;
  int v0 = 0, v1 = 0, v2 = 0, v3 = 0;
  if (base < n) { v0 = cnt[base]; v1 = cnt[base + 1]; v2 = cnt[base + 2]; v3 = cnt[base + 3]; }
  int s = v0 + v1 + v2 + v3;
  sums[tid] = s;
  __syncthreads();
  for (int off = 1; off < 1024; off <<= 1) {
    int t = (tid >= off) ? sums[tid - off] : 0;
    __syncthreads();
    sums[tid] += t;
    __syncthreads();
  }
  int excl = sums[tid] - s;
  if (base < n) {
    rowptr[base] = excl;
    rowptr[base + 1] = excl + v0;
    rowptr[base + 2] = excl + v0 + v1;
    rowptr[base + 3] = excl + v0 + v1 + v2;
    dv[base] = rsqrtf((float)v0 + 2.0f);
    dv[base + 1] = rsqrtf((float)v1 + 2.0f);
    dv[base + 2] = rsqrtf((float)v2 + 2.0f);
    dv[base + 3] = rsqrtf((float)v3 + 2.0f);
  }
  if (tid == 1023) rowptr[n] = sums[1023];
}

__global__ void k_fill(const int* __restrict__ ei, int E, const int* __restrict__ rowptr,
                       int* __restrict__ cursor, int* __restrict__ colidx) {
  int e = blockIdx.x * 256 + threadIdx.x;
  if (e >= E) return;
  int r = ei[E + e], c = ei[e];
  int p = atomicAdd(&cursor[r], 1);
  colidx[rowptr[r] + p] = c;
}

// d[i] = rsqrt(rowsum(A)+2), dense fp32 (level-2 only)
__global__ void k_deg(const float* __restrict__ A, int n, float* __restrict__ dv) {
  int row = blockIdx.x * (blockDim.x >> 6) + (threadIdx.x >> 6);
  int lane = threadIdx.x & 63;
  if (row >= n) return;
  float s = 0.f;
  const float* arow = A + (size_t)row * n;
  for (int j = lane; j < n; j += 64) s += arow[j];
#pragma unroll
  for (int o = 32; o > 0; o >>= 1) s += __shfl_down(s, o);
  if (lane == 0) dv[row] = rsqrtf(s + 2.0f);
}

// Y[r,c] = d(r) * sum_k X'[r,k] W[k,c]; RS: dv[] holds rowsum -> d=rsqrt(rs+2)
// MODE 0: X'=X ; 1 (pool): X[perm[r]]*score ; 2 (skip): X[r]+prev[inv[r]]
template <int MODE, int RS>
__global__ __launch_bounds__(256) void k_xw(const float* __restrict__ X,
                                            const float* __restrict__ W,
                                            const float* __restrict__ dv,
                                            const int* __restrict__ idx,
                                            const float* __restrict__ aux,
                                            float* __restrict__ Y, int n, int F) {
  __shared__ float Xs[64][36];
  __shared__ float Ws[32][132];
  __shared__ int ridx[64];
  __shared__ float rscl[64];
  int tid = threadIdx.x;
  int rowBase = blockIdx.x * 64;
  if (MODE == 1) {
    if (tid < 64) {
      int pp = idx[rowBase + tid];
      ridx[tid] = pp;
      rscl[tid] = aux[pp];
    }
  } else if (MODE == 2) {
    if (tid < 64) ridx[tid] = idx[rowBase + tid];
  }
  if (MODE != 0) __syncthreads();
  int r0 = (tid >> 5) << 3;
  int c0 = (tid & 31) << 2;
  float acc[8][4] = {};
  for (int k0 = 0; k0 < F; k0 += 32) {
#pragma unroll
    for (int it = 0, e = tid; it < 8; ++it, e += 256) {
      int ii = e >> 5, kk = e & 31;
      int gk = k0 + kk;
      float v;
      if (MODE == 0) {
        v = X[(size_t)(rowBase + ii) * F + gk];
      } else if (MODE == 1) {
        v = X[(size_t)ridx[ii] * F + gk] * rscl[ii];
      } else {
        v = X[(size_t)(rowBase + ii) * F + gk];
        int iv = ridx[ii];
        if (iv >= 0) v += aux[(size_t)iv * H + gk];
      }
      Xs[ii][kk] = v;
    }
#pragma unroll
    for (int it = 0, e = tid; it < 4; ++it, e += 256) {
      int kk = e >> 5, cc4 = e & 31;
      *(float4*)&Ws[kk][cc4 << 2] = *(const float4*)&W[(size_t)(k0 + kk) * H + (cc4 << 2)];
    }
    __syncthreads();
#pragma unroll
    for (int kk = 0; kk < 32; kk += 4) {
      float4 a4[8], w4[4];
#pragma unroll
      for (int i = 0; i < 8; ++i) a4[i] = *(const float4*)&Xs[r0 + i][kk];
#pragma unroll
      for (int s = 0; s < 4; ++s) w4[s] = *(const float4*)&Ws[kk + s][c0];
#pragma unroll
      for (int i = 0; i < 8; ++i) {
        float av[4] = {a4[i].x, a4[i].y, a4[i].z, a4[i].w};
#pragma unroll
        for (int s = 0; s < 4; ++s) {
          float wv[4] = {w4[s].x, w4[s].y, w4[s].z, w4[s].w};
#pragma unroll
          for (int j = 0; j < 4; ++j) acc[i][j] = fmaf(av[s], wv[j], acc[i][j]);
        }
      }
    }
    __syncthreads();
  }
#pragma unroll
  for (int i = 0; i < 8; ++i) {
    int row = rowBase + r0 + i;
    float d = RS ? rsqrtf(dv[row] + 2.0f) : dv[row];
    *(float4*)&Y[(size_t)row * H + c0] =
        make_float4(d * acc[i][0], d * acc[i][1], d * acc[i][2], d * acc[i][3]);
  }
}

// sparse GCN epilogue; lane covers cols 2*lane, 2*lane+1 (float2 loads)
__global__ void k_spmm_fin(const int* __restrict__ rowptr, const int* __restrict__ colidx,
                           const float* __restrict__ Y, const float* __restrict__ dv,
                           const float* __restrict__ bias, float* __restrict__ Out,
                           int n, int relu) {
  int row = blockIdx.x * 4 + (threadIdx.x >> 6);
  int lane = threadIdx.x & 63;
  if (row >= n) return;
  int s = rowptr[row], e = rowptr[row + 1];
  int c2 = lane * 2;
  float a0 = 0.f, a1 = 0.f;
  int i = s;
  for (; i + 1 < e; i += 2) {
    int cA = colidx[i], cB = colidx[i + 1];
    float2 yA = *(const float2*)&Y[(size_t)cA * H + c2];
    float2 yB = *(const float2*)&Y[(size_t)cB * H + c2];
    a0 += yA.x + yB.x;
    a1 += yA.y + yB.y;
  }
  if (i < e) {
    int c = colidx[i];
    float2 y = *(const float2*)&Y[(size_t)c * H + c2];
    a0 += y.x;
    a1 += y.y;
  }
  float d = dv[row];
  float2 yr = *(const float2*)&Y[(size_t)row * H + c2];
  float v0 = d * (a0 + 2.0f * yr.x) + bias[c2];
  float v1 = d * (a1 + 2.0f * yr.y) + bias[c2 + 1];
  if (relu) { v0 = fmaxf(v0, 0.f); v1 = fmaxf(v1, 0.f); }
  float2 o = make_float2(v0, v1);
  *(float2*)&Out[(size_t)row * H + c2] = o;
}

// level-0 ATA, row-wise (LDS int accumulators) -> bf16 row + dv fused
__global__ __launch_bounds__(256) void k_ata_rows(const int* __restrict__ rowptr,
                                                  const int* __restrict__ colidx,
                                                  const int* __restrict__ perm,
                                                  const int* __restrict__ inv,
                                                  unsigned short* __restrict__ Ab,
                                                  float* __restrict__ dv, int kdim) {
  __shared__ int acc[2048];
  __shared__ int wsum[4];
  int i = blockIdx.x;
  int tid = threadIdx.x;
  for (int j = tid; j < kdim; j += 256) acc[j] = 0;
  __syncthreads();
  int p = perm[i];
  int s = rowptr[p], e = rowptr[p + 1];
  int deg = e - s;
  int wave = tid >> 6, lane = tid & 63;
  for (int q = wave; q <= deg; q += 4) {
    int kn = (q < deg) ? colidx[s + q] : p;
    int s2 = rowptr[kn], e2 = rowptr[kn + 1];
    for (int idx = s2 + lane; idx <= e2; idx += 64) {
      int j = (idx < e2) ? colidx[idx] : kn;
      int ii = inv[j];
      if (ii >= 0) atomicAdd(&acc[ii], 1);
    }
  }
  __syncthreads();
  int rs = 0;
  {
    int j0 = tid * 8;
    ushort8 v;
#pragma unroll
    for (int q = 0; q < 8; ++q) {
      int j = j0 + q;
      int c = (j == i) ? 0 : acc[j];
      rs += c;
      v[q] = f2b((float)c);
    }
    *(ushort8*)&Ab[(size_t)i * kdim + j0] = v;
  }
#pragma unroll
  for (int o = 32; o > 0; o >>= 1) rs += __shfl_down(rs, o);
  if (lane == 0) wsum[wave] = rs;
  __syncthreads();
  if (tid == 0) dv[i] = rsqrtf((float)(wsum[0] + wsum[1] + wsum[2] + wsum[3]) + 2.0f);
}

// level-1 ATA partial: C_z = S_sub[:, kz] @ S_sub[:, kz]^T via bf16 MFMA (gather + +I fused).
// z-chunk writes a private partial (plain stores). Exact integer partial sums.
__global__ __launch_bounds__(256) void k_ata_mfma_g(const unsigned short* __restrict__ Ab,
                                                    const int* __restrict__ perm,
                                                    float* __restrict__ PartC,
                                                    int n, int k, int KC) {
  __shared__ __align__(16) unsigned short As[64][64];
  __shared__ __align__(16) unsigned short Bs[64][64];
  __shared__ int pr[64], pc[64];
  int tid = threadIdx.x;
  int w = tid >> 6, ln = tid & 63;
  int l15 = ln & 15, l4 = ln >> 4;
  int br = blockIdx.y, bc = blockIdx.x;
  if (tid < 64) pr[tid] = perm[br * 64 + tid];
  else if (tid < 128) pc[tid - 64] = perm[bc * 64 + (tid - 64)];
  __syncthreads();
  f32x4 acc[4] = {};
  int k0s = blockIdx.z * KC;
  for (int k0 = k0s; k0 < k0s + KC; k0 += 64) {
#pragma unroll
    for (int it = 0; it < 2; ++it) {
      int e = tid + it * 256;
      int row = e >> 3, ch = e & 7;
      int sch = (ch ^ (row & 7)) * 8;
      int base = k0 + ch * 8;
      {
        int p = pr[row];
        ushort8 v = *(const ushort8*)&Ab[(size_t)p * n + base];
#pragma unroll
        for (int q = 0; q < 8; ++q)
          if (base + q == p) v[q] = f2b(b2f(v[q]) + 1.0f);
        *(ushort8*)&As[row][sch] = v;
      }
      {
        int p = pc[row];
        ushort8 v = *(const ushort8*)&Ab[(size_t)p * n + base];
#pragma unroll
        for (int q = 0; q < 8; ++q)
          if (base + q == p) v[q] = f2b(b2f(v[q]) + 1.0f);
        *(ushort8*)&Bs[row][sch] = v;
      }
    }
    __syncthreads();
#pragma unroll
    for (int s = 0; s < 2; ++s) {
      int arow = w * 16 + l15;
      bf16x8 af = *(const bf16x8*)&As[arow][((s * 4 + l4) ^ (arow & 7)) * 8];
#pragma unroll
      for (int f = 0; f < 4; ++f) {
        int brow = f * 16 + l15;
        bf16x8 bfr = *(const bf16x8*)&Bs[brow][((s * 4 + l4) ^ (brow & 7)) * 8];
        acc[f] = __builtin_amdgcn_mfma_f32_16x16x32_bf16(af, bfr, acc[f], 0, 0, 0);
      }
    }
    __syncthreads();
  }
  float* out = PartC + (size_t)blockIdx.z * k * k;
#pragma unroll
  for (int f = 0; f < 4; ++f) {
#pragma unroll
    for (int r = 0; r < 4; ++r) {
      int gi = br * 64 + w * 16 + l4 * 4 + r;
      int gj = bc * 64 + f * 16 + l15;
      out[(size_t)gi * k + gj] = acc[f][r];
    }
  }
}

// sum 4 ATA partials, zero diag, write C, emit raw rowsum (exact ints)
__global__ __launch_bounds__(256) void k_ata_fin(const float* __restrict__ PartC,
                                                 float* __restrict__ C,
                                                 float* __restrict__ rowsum, int k) {
  __shared__ float wsum[4];
  int gi = blockIdx.x;
  int tid = threadIdx.x;
  int j4 = tid * 4;
  size_t stride = (size_t)k * k;
  size_t off = (size_t)gi * k + j4;
  float4 s = *(const float4*)&PartC[off];
#pragma unroll
  for (int z = 1; z < 4; ++z) {
    float4 p = *(const float4*)&PartC[z * stride + off];
    s.x += p.x; s.y += p.y; s.z += p.z; s.w += p.w;
  }
  if (gi >= j4 && gi < j4 + 4) ((float*)&s)[gi - j4] = 0.0f;
  *(float4*)&C[off] = s;
  float part = s.x + s.y + s.z + s.w;
  int lane = tid & 63, wave = tid >> 6;
#pragma unroll
  for (int o = 32; o > 0; o >>= 1) part += __shfl_down(part, o);
  if (lane == 0) wsum[wave] = part;
  __syncthreads();
  if (tid == 0) rowsum[gi] = wsum[0] + wsum[1] + wsum[2] + wsum[3];
}

// Y [n][128] fp32 -> YT [128][2n] bf16 hi|lo limbs
__global__ void k_cvt_split(const float* __restrict__ Y, unsigned short* __restrict__ YT, int n) {
  int c = blockIdx.x;
  for (int k0 = threadIdx.x * 8; k0 < n; k0 += 256 * 8) {
    ushort8 hi, lo;
#pragma unroll
    for (int q = 0; q < 8; ++q) {
      float v = Y[(size_t)(k0 + q) * H + c];
      unsigned short h = f2b(v);
      hi[q] = h;
      lo[q] = f2b(v - b2f(h));
    }
    *(ushort8*)&YT[(size_t)c * (2 * n) + k0] = hi;
    *(ushort8*)&YT[(size_t)c * (2 * n) + n + k0] = lo;
  }
}

// Partial A@Y via bf16 MFMA over virtual K=2n (hi|lo limbs). Split-K private partials.
__global__ __launch_bounds__(256) void k_gcn_mfma(const unsigned short* __restrict__ A,
                                                  const unsigned short* __restrict__ YT,
                                                  float* __restrict__ Part, int n, int VK) {
  __shared__ __align__(16) unsigned short As[64][64];
  __shared__ __align__(16) unsigned short Bs[128][64];
  int tid = threadIdx.x;
  int w = tid >> 6, ln = tid & 63;
  int l15 = ln & 15, l4 = ln >> 4;
  int rowBase = blockIdx.x * 64;
  float* out = Part + (size_t)blockIdx.y * n * H;
  f32x4 acc[8] = {};
  int vk0s = blockIdx.y * VK;
  for (int vk0 = vk0s; vk0 < vk0s + VK; vk0 += 64) {
    int ka = vk0 & (n - 1);
#pragma unroll
    for (int it = 0; it < 2; ++it) {
      int e = tid + it * 256;
      int row = e >> 3, ch = e & 7;
      int sch = (ch ^ (row & 7)) * 8;
      *(ushort8*)&As[row][sch] = *(const ushort8*)&A[(size_t)(rowBase + row) * n + ka + ch * 8];
    }
#pragma unroll
    for (int it = 0; it < 4; ++it) {
      int e = tid + it * 256;
      int row = e >> 3, ch = e & 7;
      int sch = (ch ^ (row & 7)) * 8;
      *(ushort8*)&Bs[row][sch] = *(const ushort8*)&YT[(size_t)row * (2 * n) + vk0 + ch * 8];
    }
    __syncthreads();
#pragma unroll
    for (int s = 0; s < 2; ++s) {
      int arow = w * 16 + l15;
      bf16x8 af = *(const bf16x8*)&As[arow][((s * 4 + l4) ^ (arow & 7)) * 8];
#pragma unroll
      for (int f = 0; f < 8; ++f) {
        int brow = f * 16 + l15;
        bf16x8 bfr = *(const bf16x8*)&Bs[brow][((s * 4 + l4) ^ (brow & 7)) * 8];
        acc[f] = __builtin_amdgcn_mfma_f32_16x16x32_bf16(af, bfr, acc[f], 0, 0, 0);
      }
    }
    __syncthreads();
  }
#pragma unroll
  for (int f = 0; f < 8; ++f) {
#pragma unroll
    for (int r = 0; r < 4; ++r) {
      int row = rowBase + w * 16 + l4 * 4 + r;
      out[(size_t)row * H + f * 16 + l15] = acc[f][r];
    }
  }
}

// dense fp32 ATA split-K (level 2 only)
__global__ __launch_bounds__(256) void k_ata_sk(const float* __restrict__ A,
                                                const int* __restrict__ perm,
                                                float* __restrict__ C, int n, int k, int CK) {
  int bc = blockIdx.x, br = blockIdx.y;
  if (br > bc) return;
  __shared__ float As[64][36];
  __shared__ float Bs[64][36];
  __shared__ int pr[64], pc[64];
  int tid = threadIdx.x;
  if (tid < 64) pr[tid] = perm[br * 64 + tid];
  else if (tid < 128) pc[tid - 64] = perm[bc * 64 + (tid - 64)];
  __syncthreads();
  int ty = tid >> 4;
  int tx = tid & 15;
  float acc[4][4] = {};
  int k0s = blockIdx.z * CK;
  for (int k0 = k0s; k0 < k0s + CK; k0 += 32) {
#pragma unroll
    for (int it = 0, e = tid; it < 8; ++it, e += 256) {
      int ii = e >> 5, kk = e & 31;
      int gk = k0 + kk;
      int p = pr[ii];
      As[ii][kk] = A[(size_t)p * n + gk] + ((p == gk) ? 1.0f : 0.0f);
      p = pc[ii];
      Bs[ii][kk] = A[(size_t)p * n + gk] + ((p == gk) ? 1.0f : 0.0f);
    }
    __syncthreads();
#pragma unroll
    for (int kk = 0; kk < 32; kk += 4) {
      float4 a4[4], b4[4];
#pragma unroll
      for (int i = 0; i < 4; ++i) a4[i] = *(const float4*)&As[ty + 16 * i][kk];
#pragma unroll
      for (int j = 0; j < 4; ++j) b4[j] = *(const float4*)&Bs[tx + 16 * j][kk];
#pragma unroll
      for (int i = 0; i < 4; ++i) {
        float av[4] = {a4[i].x, a4[i].y, a4[i].z, a4[i].w};
#pragma unroll
        for (int j = 0; j < 4; ++j) {
          float bv[4] = {b4[j].x, b4[j].y, b4[j].z, b4[j].w};
#pragma unroll
          for (int s = 0; s < 4; ++s) acc[i][j] = fmaf(av[s], bv[s], acc[i][j]);
        }
      }
    }
    __syncthreads();
  }
  bool diag = (br == bc);
#pragma unroll
  for (int i = 0; i < 4; ++i) {
    int gi = br * 64 + ty + 16 * i;
#pragma unroll
    for (int j = 0; j < 4; ++j) {
      int gj = bc * 64 + tx + 16 * j;
      if (gi == gj) continue;
      float v = acc[i][j];
      atomicAdd(&C[(size_t)gi * k + gj], v);
      if (!diag) atomicAdd(&C[(size_t)gj * k + gi], v);
    }
  }
}

// fp32 dense GCN partial (split-K, private partials)
__global__ __launch_bounds__(256) void k_gcn_part(const float* __restrict__ A,
                                                  const float* __restrict__ Y,
                                                  float* __restrict__ Part,
                                                  int n, int KC) {
  __shared__ float As[64][36];
  __shared__ float Ys[32][132];
  int tid = threadIdx.x;
  int r0 = (tid >> 5) << 3;
  int c0 = (tid & 31) << 2;
  size_t rowBase = (size_t)blockIdx.x * 64;
  int k0s = blockIdx.y * KC;
  float* out = Part + (size_t)blockIdx.y * n * H;
  float acc[8][4] = {};
  for (int k0 = k0s; k0 < k0s + KC; k0 += 32) {
#pragma unroll
    for (int it = 0, e = tid; it < 8; ++it, e += 256) {
      int ii = e >> 5, kk = e & 31;
      As[ii][kk] = A[(rowBase + ii) * (size_t)n + k0 + kk];
    }
#pragma unroll
    for (int it = 0, e = tid; it < 4; ++it, e += 256) {
      int kk = e >> 5, cc4 = e & 31;
      *(float4*)&Ys[kk][cc4 << 2] = *(const float4*)&Y[(size_t)(k0 + kk) * H + (cc4 << 2)];
    }
    __syncthreads();
#pragma unroll
    for (int kk = 0; kk < 32; kk += 4) {
      float4 a4[8], y4[4];
#pragma unroll
      for (int i = 0; i < 8; ++i) a4[i] = *(const float4*)&As[r0 + i][kk];
#pragma unroll
      for (int s = 0; s < 4; ++s) y4[s] = *(const float4*)&Ys[kk + s][c0];
#pragma unroll
      for (int i = 0; i < 8; ++i) {
        float av[4] = {a4[i].x, a4[i].y, a4[i].z, a4[i].w};
#pragma unroll
        for (int s = 0; s < 4; ++s) {
          float yv[4] = {y4[s].x, y4[s].y, y4[s].z, y4[s].w};
#pragma unroll
          for (int j = 0; j < 4; ++j) acc[i][j] = fmaf(av[s], yv[j], acc[i][j]);
        }
      }
    }
    __syncthreads();
  }
#pragma unroll
  for (int i = 0; i < 8; ++i) {
    size_t row = rowBase + r0 + i;
    *(float4*)&out[row * H + c0] = make_float4(acc[i][0], acc[i][1], acc[i][2], acc[i][3]);
  }
}

// Out = act(d .* (sum_c Part[c] + 2Y) + bias); RS: dv holds rowsum
template <int RS>
__global__ void k_gcn_fin(const float* __restrict__ Part, const float* __restrict__ Y,
                          const float* __restrict__ dv, const float* __restrict__ bias,
                          float* __restrict__ Out, int n, int nch, int relu) {
  int i4 = blockIdx.x * 256 + threadIdx.x;
  if (i4 * 4 >= n * H) return;
  int row = i4 >> 5, c4 = (i4 & 31) * 4;
  size_t stride = (size_t)n * H;
  float4 s = *(const float4*)&Part[i4 * 4];
  for (int c = 1; c < nch; ++c) {
    float4 p = *(const float4*)&Part[c * stride + i4 * 4];
    s.x += p.x; s.y += p.y; s.z += p.z; s.w += p.w;
  }
  float4 y = *(const float4*)&Y[i4 * 4];
  float d = RS ? rsqrtf(dv[row] + 2.0f) : dv[row];
  float4 v;
  v.x = d * (s.x + 2.0f * y.x) + bias[c4];
  v.y = d * (s.y + 2.0f * y.y) + bias[c4 + 1];
  v.z = d * (s.z + 2.0f * y.z) + bias[c4 + 2];
  v.w = d * (s.w + 2.0f * y.w) + bias[c4 + 3];
  if (relu) {
    v.x = fmaxf(v.x, 0.f); v.y = fmaxf(v.y, 0.f);
    v.z = fmaxf(v.z, 0.f); v.w = fmaxf(v.w, 0.f);
  }
  *(float4*)&Out[i4 * 4] = v;
}

// score = tanh((h@w)/||w||)
__global__ void k_score(const float* __restrict__ h, const float* __restrict__ w,
                        float* __restrict__ score, int n) {
  __shared__ float wn;
  int tid = threadIdx.x;
  if (tid < 64) {
    float s = w[tid] * w[tid] + w[tid + 64] * w[tid + 64];
#pragma unroll
    for (int o = 32; o > 0; o >>= 1) s += __shfl_down(s, o);
    if (tid == 0) wn = sqrtf(s);
  }
  __syncthreads();
  int row = blockIdx.x * 4 + (tid >> 6);
  int lane = tid & 63;
  if (row >= n) return;
  float s = h[(size_t)row * H + lane] * w[lane] + h[(size_t)row * H + lane + 64] * w[lane + 64];
#pragma unroll
  for (int o = 32; o > 0; o >>= 1) s += __shfl_down(s, o);
  if (lane == 0) score[row] = tanhf(s / wn);
}

// ---- hybrid bitonic top-k ----
static __device__ __forceinline__ void ce_(unsigned long long& x, unsigned long long& y, bool asc) {
  if ((x < y) != asc) { unsigned long long t = x; x = y; y = t; }
}
static __device__ __forceinline__ unsigned long long pick_(unsigned long long a,
                                                           unsigned long long b,
                                                           bool lower, bool asc) {
  unsigned long long lo = (a < b) ? a : b;
  unsigned long long hi = (a < b) ? b : a;
  return (lower == asc) ? lo : hi;
}

template <int LOGN>
__global__ __launch_bounds__(1024) void k_topk(const float* __restrict__ score,
                                               int* __restrict__ perm,
                                               int* __restrict__ inv) {
  const int n = 1 << LOGN;
  __shared__ unsigned long long lds[1 << LOGN];
  int t = threadIdx.x;
  int e0 = t * 4;
  unsigned long long key[4];
#pragma unroll
  for (int j = 0; j < 4; ++j) {
    unsigned u = __float_as_uint(score[e0 + j]);
    u = (u & 0x80000000u) ? ~u : (u | 0x80000000u);
    u = ~u;
    key[j] = (((unsigned long long)u) << 32) | (unsigned)(e0 + j);
  }
  ce_(key[0], key[1], true);
  ce_(key[2], key[3], false);
  for (int size = 4; size <= n; size <<= 1) {
    bool asc = ((e0 & size) == 0);
    for (int stride = size >> 1; stride >= 256; stride >>= 1) {
#pragma unroll
      for (int j = 0; j < 4; ++j) lds[e0 + j] = key[j];
      __syncthreads();
      bool lower = ((e0 & stride) == 0);
#pragma unroll
      for (int j = 0; j < 4; ++j)
        key[j] = pick_(key[j], lds[(e0 + j) ^ stride], lower, asc);
      __syncthreads();
    }
    int s0 = ((size >> 1) < 256) ? (size >> 1) : 128;
    for (int stride = s0; stride >= 4; stride >>= 1) {
      int m = stride >> 2;
      bool lower = ((t & m) == 0);
#pragma unroll
      for (int j = 0; j < 4; ++j) {
        unsigned long long o = __shfl_xor(key[j], m, 64);
        key[j] = pick_(key[j], o, lower, asc);
      }
    }
    ce_(key[0], key[2], asc);
    ce_(key[1], key[3], asc);
    ce_(key[0], key[1], asc);
    ce_(key[2], key[3], asc);
  }
  int kk = n >> 1;
#pragma unroll
  for (int j = 0; j < 4; ++j) {
    int e = e0 + j;
    int idx = (int)(key[j] & 0xffffffffu);
    if (e < kk) perm[e] = idx;
    if (inv) inv[idx] = (e < kk) ? e : -1;
  }
}

__global__ void k_segsum(const float* __restrict__ h, const int* __restrict__ batch,
                         float* __restrict__ g, int n) {
  int c = threadIdx.x;
  int r0 = blockIdx.x * 32;
  int rend = min(r0 + 32, n);
  float acc = 0.f;
  int cur = batch[r0];
  for (int r = r0; r < rend; ++r) {
    int b = batch[r];
    if (b != cur) { atomicAdd(&g[cur * H + c], acc); acc = 0.f; cur = b; }
    acc += h[(size_t)r * H + c];
  }
  atomicAdd(&g[cur * H + c], acc);
}

__global__ __launch_bounds__(256) void k_head(const float* __restrict__ g,
    const float* __restrict__ lins_w, const float* __restrict__ lins_b,
    const float* __restrict__ bn_g, const float* __restrict__ bn_b,
    const float* __restrict__ out_w, const float* __restrict__ out_b,
    float* __restrict__ out) {
  __shared__ float a[NG * H], b[NG * H];
  int tid = threadIdx.x;
  const float inv = 1.0f / sqrtf(1.0f + 1e-5f);
  for (int i = tid; i < NG * H; i += 256) a[i] = g[i];
  __syncthreads();
  for (int L = 0; L < 3; ++L) {
    for (int i = tid; i < NG * H; i += 256) {
      int c = i & 127;
      b[i] = a[i] * (bn_g[L * H + c] * inv) + bn_b[L * H + c];
    }
    __syncthreads();
    for (int i = tid; i < NG * H; i += 256) {
      int r = i >> 7, c = i & 127;
      float s = lins_b[L * H + c];
      for (int k2 = 0; k2 < H; ++k2) s += b[r * H + k2] * lins_w[(size_t)L * H * H + k2 * H + c];
      a[i] = tanhf(s);
    }
    __syncthreads();
  }
  for (int i = tid; i < NG * H; i += 256) {
    int c = i & 127;
    b[i] = a[i] * (bn_g[3 * H + c] * inv) + bn_b[3 * H + c];
  }
  __syncthreads();
  for (int i = tid; i < NG * 32; i += 256) {
    int r = i >> 5, o = i & 31;
    float s = out_b[o];
    for (int k2 = 0; k2 < H; ++k2) s += b[r * H + k2] * out_w[k2 * 32 + o];
    out[i] = s;
  }
}

extern "C" void kernel_launch(void* const* d_in, const int* in_sizes, int n_in,
                              void* d_out, int out_size, void* d_ws, size_t ws_size,
                              hipStream_t stream) {
  const float* x       = (const float*)d_in[0];
  const int*   ei      = (const int*)d_in[1];
  const int*   batch   = (const int*)d_in[2];
  const float* conv0_w = (const float*)d_in[3];
  const float* conv0_b = (const float*)d_in[4];
  const float* down_w  = (const float*)d_in[5];
  const float* down_b  = (const float*)d_in[6];
  const float* pool_w  = (const float*)d_in[7];
  const float* up_w    = (const float*)d_in[8];
  const float* up_b    = (const float*)d_in[9];
  const float* lins_w  = (const float*)d_in[10];
  const float* lins_b  = (const float*)d_in[11];
  const float* bn_g    = (const float*)d_in[12];
  const float* bn_b    = (const float*)d_in[13];
  const float* out_w   = (const float*)d_in[14];
  const float* out_b   = (const float*)d_in[15];
  int E = in_sizes[1] / 2;

  char* p = (char*)d_ws;
  auto alloc = [&](size_t bytes) {
    char* r = p;
    p += (bytes + 255) & ~(size_t)255;
    return r;
  };
  unsigned short* A1b  = (unsigned short*)alloc((size_t)2048 * 2048 * 2);
  unsigned short* YT   = (unsigned short*)alloc((size_t)128 * 4096 * 2);
  float*          A2m  = (float*)alloc((size_t)1024 * 1024 * 4);
  float*          A3   = (float*)alloc((size_t)512 * 512 * 4);
  float*          part = (float*)alloc((size_t)16 * 1024 * 1024 * 4);  // 64 MB: gcn partials / ata partials
  int* cnt    = (int*)alloc(4096 * 4);
  int* cursor = (int*)alloc(4096 * 4);
  int* rowptr = (int*)alloc(4100 * 4);
  int* colidx = (int*)alloc((size_t)E * 4);
  int* inv0   = (int*)alloc(4096 * 4);
  int* inv1   = (int*)alloc(2048 * 4);
  int* inv2   = (int*)alloc(1024 * 4);
  float* dv0  = (float*)alloc(4096 * 4);
  float* dv1  = (float*)alloc(2048 * 4);
  float* dv2  = (float*)alloc(1024 * 4);   // raw rowsum (RS consumers)
  float* dv3  = (float*)alloc(512 * 4);
  int* perm0  = (int*)alloc(2048 * 4);
  int* perm1  = (int*)alloc(1024 * 4);
  int* perm2  = (int*)alloc(512 * 4);
  float* score = (float*)alloc(4096 * 4);
  float* h0 = (float*)alloc((size_t)4096 * H * 4);
  float* h1 = (float*)alloc((size_t)2048 * H * 4);
  float* h2 = (float*)alloc((size_t)1024 * H * 4);
  float* h3 = (float*)alloc((size_t)512 * H * 4);
  float* t2 = (float*)alloc((size_t)4096 * H * 4);
  float* hu = (float*)alloc((size_t)4096 * H * 4);
  float* g  = (float*)alloc(NG * H * 4);

  // fp32 gcn (n<=1024); rs selects rowsum-interpretation of dv
  auto gcn = [&](const float* A, const float* Y, const float* dvv, const float* bias,
                 float* Out, int nn, int relu, bool rs) {
    const int nch = 8;
    int KC = nn / nch;
    k_gcn_part<<<dim3(nn / 64, nch), 256, 0, stream>>>(A, Y, part, nn, KC);
    if (rs)
      k_gcn_fin<1><<<nn / 8, 256, 0, stream>>>(part, Y, dvv, bias, Out, nn, nch, relu);
    else
      k_gcn_fin<0><<<nn / 8, 256, 0, stream>>>(part, Y, dvv, bias, Out, nn, nch, relu);
  };
  // bf16 MFMA gcn with hi/lo Y split (n=2048, A=A1b exact bf16), split-K=16
  auto gcn_mfma = [&](const unsigned short* Ab, const float* Y, const float* dvv,
                      const float* bias, float* Out, int nn, int relu) {
    k_cvt_split<<<128, 256, 0, stream>>>(Y, YT, nn);
    k_gcn_mfma<<<dim3(nn / 64, 16), 256, 0, stream>>>(Ab, YT, part, nn, (2 * nn) / 16);
    k_gcn_fin<0><<<nn / 8, 256, 0, stream>>>(part, Y, dvv, bias, Out, nn, 16, relu);
  };

  // ---- CSR build (scan emits dv0) ----
  hipMemsetAsync(cnt, 0, 4096 * 4, stream);
  hipMemsetAsync(cursor, 0, 4096 * 4, stream);
  k_hist<<<(E + 255) / 256, 256, 0, stream>>>(ei, E, cnt);
  k_scan<<<1, 1024, 0, stream>>>(cnt, rowptr, dv0, 4096);
  k_fill<<<(E + 255) / 256, 256, 0, stream>>>(ei, E, rowptr, cursor, colidx);

  // ---- conv0 (sparse) ----
  k_xw<0, 0><<<4096 / 64, 256, 0, stream>>>(x, conv0_w, dv0, nullptr, nullptr, t2, 4096, 64);
  k_spmm_fin<<<1024, 256, 0, stream>>>(rowptr, colidx, t2, dv0, conv0_b, h0, 4096, 1);

  // ---- level 0 pooling (4096 -> 2048): row-wise sparse ATA -> bf16 + dv1 ----
  k_score<<<1024, 256, 0, stream>>>(h0, pool_w, score, 4096);
  k_topk<12><<<1, 1024, 0, stream>>>(score, perm0, inv0);
  k_ata_rows<<<2048, 256, 0, stream>>>(rowptr, colidx, perm0, inv0, A1b, dv1, 2048);
  k_xw<1, 0><<<2048 / 64, 256, 0, stream>>>(h0, down_w, dv1, perm0, score, t2, 2048, 128);
  gcn_mfma(A1b, t2, dv1, down_b, h1, 2048, 1);

  // ---- level 1 pooling (2048 -> 1024): fused gather+MFMA ATA, split-K=4 + fin ----
  k_score<<<512, 256, 0, stream>>>(h1, pool_w + H, score, 2048);
  k_topk<11><<<1, 512, 0, stream>>>(score, perm1, inv1);
  k_ata_mfma_g<<<dim3(16, 16, 4), 256, 0, stream>>>(A1b, perm1, part, 2048, 1024, 512);
  k_ata_fin<<<1024, 256, 0, stream>>>(part, A2m, dv2, 1024);
  k_xw<1, 1><<<1024 / 64, 256, 0, stream>>>(h1, down_w + (size_t)H * H, dv2, perm1, score, t2, 1024, 128);
  gcn(A2m, t2, dv2, down_b + H, h2, 1024, 1, true);

  // ---- level 2 pooling (1024 -> 512): fp32 split-K ATA ----
  k_score<<<256, 256, 0, stream>>>(h2, pool_w + 2 * H, score, 1024);
  k_topk<10><<<1, 256, 0, stream>>>(score, perm2, inv2);
  hipMemsetAsync(A3, 0, (size_t)512 * 512 * 4, stream);
  k_ata_sk<<<dim3(8, 8, 8), 256, 0, stream>>>(A2m, perm2, A3, 1024, 512, 128);
  k_deg<<<512 / 4, 256, 0, stream>>>(A3, 512, dv3);
  k_xw<1, 0><<<512 / 64, 256, 0, stream>>>(h2, down_w + (size_t)2 * H * H, dv3, perm2, score, t2, 512, 128);
  gcn(A3, t2, dv3, down_b + 2 * H, h3, 512, 1, false);

  // ---- up path (skip fused into xw) ----
  k_xw<2, 1><<<1024 / 64, 256, 0, stream>>>(h2, up_w, dv2, inv2, h3, t2, 1024, 128);
  gcn(A2m, t2, dv2, up_b, hu, 1024, 1, true);

  k_xw<2, 0><<<2048 / 64, 256, 0, stream>>>(h1, up_w + (size_t)H * H, dv1, inv1, hu, t2, 2048, 128);
  gcn_mfma(A1b, t2, dv1, up_b + H, hu, 2048, 1);

  k_xw<2, 0><<<4096 / 64, 256, 0, stream>>>(h0, up_w + (size_t)2 * H * H, dv0, inv0, hu, t2, 4096, 128);
  k_spmm_fin<<<1024, 256, 0, stream>>>(rowptr, colidx, t2, dv0, up_b + 2 * H, hu, 4096, 0);

  // ---- pool + head ----
  hipMemsetAsync(g, 0, NG * H * 4, stream);
  k_segsum<<<4096 / 32, 128, 0, stream>>>(hu, batch, g, 4096);
  k_head<<<1, 256, 0, stream>>>(g, lins_w, lins_b, bn_g, bn_b, out_w, out_b, (float*)d_out);
}